// Round 13
// baseline (7118.534 us; speedup 1.0000x reference)
//
#include <hip/hip_runtime.h>
#include <float.h>
#include <math.h>

// ---------------------------------------------------------------------------
// SSFE_Net pipeline on MI355X. B=16, N=2048.
// R11: direct feature-knn fused (no D matrix) — regressed: 16 batches x 512KB
//      FT thrashed the 4MB per-XCD L2 (6.5GB HBM refetch).
// R12: XCD-pinned batch locality (T1): non-FPS blocks remapped in 8-wide
//      stripes alternating geo/feat; feat stripe position r == XCD == b%8,
//      so each XCD touches only 2 batches' FT (1MB, L2-resident). Geo (VALU)
//      and feat (L2) blocks interleave on every CU.
// ---------------------------------------------------------------------------

static constexpr int B_   = 16;
static constexpr int N_   = 2048;
static constexpr int NP1  = 512;
static constexpr int NP2  = 256;
static constexpr int KG   = 20;
static constexpr int NSAMP= 32;

// workspace offsets (in float elements)
static constexpr long OFF_FT   = 0;
static constexpr long OFF_SQ   = OFF_FT   + (long)B_*N_*64;
static constexpr long OFF_BIG  = OFF_SQ   + (long)B_*N_;          // P / Q0 (aliased)
static constexpr long OFF_IDXG = OFF_BIG  + (long)B_*N_*256;
static constexpr long OFF_IDXF = OFF_IDXG + (long)B_*N_*KG;
static constexpr long OFF_OUTF = OFF_IDXF + (long)B_*N_*KG;
static constexpr long OFF_FPS1 = OFF_OUTF + (long)B_*N_*64;
static constexpr long OFF_NX1  = OFF_FPS1 + (long)B_*NP1;
static constexpr long OFF_IDX1 = OFF_NX1  + (long)B_*NP1*3;
static constexpr long OFF_F0T  = OFF_IDX1 + (long)B_*NP1*NSAMP;
static constexpr long OFF_FPS2 = OFF_F0T  + (long)B_*NP1*128;
static constexpr long OFF_NX2  = OFF_FPS2 + (long)B_*NP2;
static constexpr long OFF_IDX2 = OFF_NX2  + (long)B_*NP2*3;
static constexpr long OFF_Q1   = OFF_IDX2 + (long)B_*NP2*NSAMP;
static constexpr long OFF_V    = OFF_Q1   + (long)B_*NP1*512;
static constexpr long OFF_WPP  = OFF_V    + (long)B_*NP2*1280;
static constexpr long OFF_WPQ0 = OFF_WPP  + 256*64;
static constexpr long OFF_WPQ1 = OFF_WPQ0 + 256*64;
static constexpr long OFF_WFT  = OFF_WPQ1 + 512*128;
static constexpr long OFF_SC   = OFF_WFT  + 128*64;

// SC (bn scale/shift) sub-offsets
static constexpr int SC_S1=0, SC_T1=64, SC_SGEO=128, SC_TGEO=192, SC_SFEAT=256, SC_TFEAT=320,
   SC_SFUSE=384, SC_TFUSE=448, SC_SGL0=512, SC_TGL0=640, SC_SGL1=768, SC_TGL1=1024,
   SC_S2=1280, SC_T2=2304, SC_SF=3328, SC_TF=3840;

__device__ __forceinline__ float lrelu_(float x) { return x >= 0.0f ? x : 0.2f * x; }

// masked DPP max step: masked-off rows keep v (old = v)
template<int CTRL, int RM>
__device__ __forceinline__ float dpp_maxm(float v) {
    int o = __builtin_amdgcn_update_dpp(__float_as_int(v), __float_as_int(v),
                                        CTRL, RM, 0xF, false);
    return fmaxf(v, __int_as_float(o));
}
// pure-VALU wave64 max -> uniform SGPR value (no ds_swizzle/bpermute).
__device__ __forceinline__ float wave_max64_sgpr(float v) {
    v = dpp_maxm<0xB1, 0xF>(v);   // quad_perm(1,0,3,2)
    v = dpp_maxm<0x4E, 0xF>(v);   // quad_perm(2,3,0,1)
    v = dpp_maxm<0x141,0xF>(v);   // row_half_mirror
    v = dpp_maxm<0x140,0xF>(v);   // row_mirror  -> row max in all 16 lanes
    v = dpp_maxm<0x142,0xA>(v);   // row_bcast15 -> rows 1,3 combine
    v = dpp_maxm<0x143,0xC>(v);   // row_bcast31 -> rows 2,3 combine; lane63 = max
    return __int_as_float(__builtin_amdgcn_readlane(__float_as_int(v), 63));
}

// DPP-accelerated wave64 unsigned min (value only, all lanes) — knn topk.
template<int CTRL>
__device__ __forceinline__ unsigned dpp_minu(unsigned x) {
    unsigned o = (unsigned)__builtin_amdgcn_update_dpp(0, (int)x, CTRL, 0xF, 0xF, true);
    return o < x ? o : x;
}
__device__ __forceinline__ unsigned wave_minu(unsigned x) {
    x = dpp_minu<0xB1>(x);
    x = dpp_minu<0x4E>(x);
    x = dpp_minu<0x141>(x);
    x = dpp_minu<0x140>(x);
    { unsigned o = (unsigned)__shfl_xor((int)x, 16); x = o < x ? o : x; }
    { unsigned o = (unsigned)__shfl_xor((int)x, 32); x = o < x ? o : x; }
    return x;
}

// monotone float -> sortable u32 (handles negative values from rounding)
__device__ __forceinline__ unsigned sortable_(float f) {
    unsigned u = __float_as_uint(f);
    return u ^ ((unsigned)((int)u >> 31) | 0x80000000u);
}

// ---------------------------------------------------------------------------
// prep: bn scale/shift + packed weight matrices
// ---------------------------------------------------------------------------
__global__ void k_prep(const float* __restrict__ bn1, const float* __restrict__ bn2,
                       const float* __restrict__ geow, const float* __restrict__ geobn,
                       const float* __restrict__ featw, const float* __restrict__ featbn,
                       const float* __restrict__ fusew, const float* __restrict__ fusebn,
                       const float* __restrict__ gl0w, const float* __restrict__ gl0bn,
                       const float* __restrict__ gl1w, const float* __restrict__ gl1bn,
                       const float* __restrict__ bnfp, float* __restrict__ ws)
{
    const int tid = blockIdx.x * blockDim.x + threadIdx.x;
    const int nt  = gridDim.x * blockDim.x;
    float* sc = ws + OFF_SC;

    {
        const float* ps[8]  = {bn1, geobn, featbn, fusebn, gl0bn, gl1bn, bn2, bnfp};
        const int    ch[8]  = {64, 64, 64, 64, 128, 256, 1024, 512};
        const int    so[8]  = {SC_S1, SC_SGEO, SC_SFEAT, SC_SFUSE, SC_SGL0, SC_SGL1, SC_S2, SC_SF};
        const int    to[8]  = {SC_T1, SC_TGEO, SC_TFEAT, SC_TFUSE, SC_TGL0, SC_TGL1, SC_T2, SC_TF};
        for (int g = 0; g < 8; g++) {
            const float* p = ps[g]; int C = ch[g];
            for (int i = tid; i < C; i += nt) {
                float gg = p[i], bb = p[C+i], mm = p[2*C+i], vv = p[3*C+i];
                float s = gg * (1.0f / sqrtf(vv + 1e-5f));
                sc[so[g] + i] = s;
                sc[to[g] + i] = bb - mm * s;
            }
        }
    }
    for (int j = tid; j < 256*64; j += nt) {
        int o = j >> 6, c = j & 63; float v;
        if      (o < 64)  v = geow[o*128 + c];
        else if (o < 128) v = geow[(o-64)*128 + 64 + c];
        else if (o < 192) v = featw[(o-128)*128 + c];
        else              v = featw[(o-192)*128 + 64 + c];
        ws[OFF_WPP + j] = v;
    }
    for (int j = tid; j < 256*64; j += nt) {
        int o = j >> 6, c = j & 63; float v;
        if (o < 128) v = gl0w[o*128 + c];
        else         v = gl0w[(o-128)*128 + 64 + c] - gl0w[(o-128)*128 + c];
        ws[OFF_WPQ0 + j] = v;
    }
    for (int j = tid; j < 512*128; j += nt) {
        int o = j >> 7, c = j & 127; float v;
        if (o < 256) v = gl1w[o*256 + c];
        else         v = gl1w[(o-256)*256 + 128 + c] - gl1w[(o-256)*256 + c];
        ws[OFF_WPQ1 + j] = v;
    }
    for (int j = tid; j < 128*64; j += nt) {
        int c = j >> 6, o = j & 63;
        ws[OFF_WFT + j] = fusew[o*128 + c];
    }
}

// ---------------------------------------------------------------------------
// f_t[b][n][o] = relu(bn1(sum_c w1[o][c]*x[b][c][n])) ; sq[b][n] = sum_o f^2
// ---------------------------------------------------------------------------
__global__ void __launch_bounds__(256) k_feat0(const float* __restrict__ x,
                                               const float* __restrict__ w1,
                                               const float* __restrict__ sc,
                                               float* __restrict__ ft, float* __restrict__ sq)
{
    const int t = threadIdx.x, lane = t & 63, w = t >> 6;
    const int pid = blockIdx.x*4 + w;
    const int b = pid >> 11, n = pid & (N_-1);
    const float* xb = x + (long)b*6*N_ + n;
    float acc = 0.0f;
    #pragma unroll
    for (int c = 0; c < 6; c++) acc += w1[lane*6 + c] * xb[(long)c*N_];
    float val = fmaxf(sc[SC_S1 + lane]*acc + sc[SC_T1 + lane], 0.0f);
    ft[((long)b*N_ + n)*64 + lane] = val;
    float v2 = val*val;
    #pragma unroll
    for (int s = 1; s < 64; s <<= 1) v2 += __shfl_xor(v2, s);
    if (lane == 0) sq[b*N_ + n] = v2;
}

// ---------------------------------------------------------------------------
// topk_sel3: k smallest (stable first-index ties), index = j*64+lane.
// Per-lane top-2 cache + consumed bitmask; rescan only on second win.
// ---------------------------------------------------------------------------
template<int RPL, int KSEL>
__device__ __forceinline__ void topk_sel3(float (&v)[RPL], int lane, int* __restrict__ out)
{
    unsigned key[RPL];
    #pragma unroll
    for (int j = 0; j < RPL; j++) key[j] = sortable_(v[j]);

    unsigned consumed = 0;
    unsigned m1 = key[0]; int s1 = 0;
    unsigned m2 = 0xFFFFFFFFu; int s2 = 0;
    #pragma unroll
    for (int j = 1; j < RPL; j++) {
        unsigned kk = key[j];
        bool lt1 = kk < m1;
        bool lt2 = kk < m2;
        unsigned nm2 = lt1 ? m1 : (lt2 ? kk : m2);
        int      ns2 = lt1 ? s1 : (lt2 ? j  : s2);
        m1 = lt1 ? kk : m1;
        s1 = lt1 ? j  : s1;
        m2 = nm2; s2 = ns2;
    }

    #pragma unroll 1
    for (int k = 0; k < KSEL; k++) {
        unsigned g = wave_minu(m1);
        unsigned long long cand = __ballot(m1 == g);
        int gi;
        if (__popcll(cand) > 1) {
            int ci = (m1 == g) ? (s1*64 + lane) : 0x7FFFFFFF;
            #pragma unroll
            for (int s = 1; s < 64; s <<= 1) { int o = __shfl_xor(ci, s); ci = o < ci ? o : ci; }
            gi = ci;
        } else {
            int wl = __ffsll((long long)cand) - 1;
            gi = __builtin_amdgcn_readlane(s1, wl) * 64 + wl;
        }
        if (lane == 0) out[k] = gi;
        if (k + 1 < KSEL) {
            bool win = (m1 == g) && (s1*64 + lane == gi);
            if (win) {
                consumed |= 1u << s1;
                m1 = m2; s1 = s2;
                m2 = 0xFFFFFFFFu;
            }
            bool need = win && (m1 == 0xFFFFFFFFu);
            if (__any(need)) {
                if (need) {
                    m1 = 0xFFFFFFFFu; s1 = 0; m2 = 0xFFFFFFFFu; s2 = 0;
                    #pragma unroll
                    for (int j = 0; j < RPL; j++) {
                        unsigned kk = ((consumed >> j) & 1u) ? 0xFFFFFFFFu : key[j];
                        bool lt1 = kk < m1;
                        bool lt2 = kk < m2;
                        unsigned nm2 = lt1 ? m1 : (lt2 ? kk : m2);
                        int      ns2 = lt1 ? s1 : (lt2 ? j  : s2);
                        m1 = lt1 ? kk : m1;
                        s1 = lt1 ? j  : s1;
                        m2 = nm2; s2 = ns2;
                    }
                }
            }
        }
    }
}

// ---------------------------------------------------------------------------
// geo-knn body, global-read refs (L1/L2-resident; no LDS, no barrier).
// ---------------------------------------------------------------------------
template<int NREF, int RPL, int KSEL>
__device__ __forceinline__ void knn_gbody(
    const float* qp, long qBatch, int qsN, int qsD, int NQ,
    const float* rp, long rBatch, long rsN, long rsD,
    int* out, int bid)
{
    const int t = threadIdx.x, lane = t & 63, w = t >> 6;
    const int bpb = NQ / 4;
    const int b = bid / bpb;
    const int qi = (bid % bpb)*4 + w;
    const float* rb = rp + (long)b*rBatch;
    const float* qb = qp + (long)b*qBatch + (long)qi*qsN;
    float qx = qb[0], qy = qb[qsD], qz = qb[2*qsD];
    float sumq = __fadd_rn(__fadd_rn(__fmul_rn(qx,qx), __fmul_rn(qy,qy)), __fmul_rn(qz,qz));
    float v[RPL];
    #pragma unroll
    for (int j = 0; j < RPL; j++) {
        long n = j*64 + lane;
        float rx = rb[n*rsN];
        float ry = rb[n*rsN + rsD];
        float rz = rb[n*rsN + 2*rsD];
        float dot  = __fadd_rn(__fadd_rn(__fmul_rn(qx,rx), __fmul_rn(qy,ry)), __fmul_rn(qz,rz));
        float sumr = __fadd_rn(__fadd_rn(__fmul_rn(rx,rx), __fmul_rn(ry,ry)), __fmul_rn(rz,rz));
        v[j] = __fadd_rn(__fsub_rn(sumq, __fmul_rn(2.0f, dot)), sumr);
    }
    topk_sel3<RPL, KSEL>(v, lane, out + ((long)b*NQ + qi)*KSEL);
}

template<int NREF, int RPL, int KSEL>
__global__ void __launch_bounds__(256, 4) k_knn3d_g(
    const float* __restrict__ qp, long qBatch, int qsN, int qsD, int NQ,
    const float* __restrict__ rp, long rBatch, long rsN, long rsD,
    int* __restrict__ out)
{
    knn_gbody<NREF,RPL,KSEL>(qp, qBatch, qsN, qsD, NQ,
                             rp, rBatch, rsN, rsD, out, blockIdx.x);
}

// ---------------------------------------------------------------------------
// mega-dispatch: blocks [0,16) FPS1->FPS2; remaining 16384 blocks in 8-wide
// stripes alternating geo-knn / feature-knn. Feature-knn stripe position r
// == XCD (blockIdx%8) == batch%8, pinning each batch's FT (512KB) to one
// XCD's L2 (2 batches/XCD = 1MB resident).
// ---------------------------------------------------------------------------
__global__ void __launch_bounds__(256, 4) k_front(
    const float* __restrict__ x, const float* __restrict__ ft,
    const float* __restrict__ sq,
    int* __restrict__ idxg, int* __restrict__ idxf,
    int* __restrict__ fps1, float* __restrict__ nx1,
    int* __restrict__ fps2, float* __restrict__ nx2)
{
    __shared__ float  mx2[NP1], my2[NP1], mz2[NP1];   // 6 KiB (FPS1 -> FPS2)
    __shared__ int    sidx1[NP1];                     // 2 KiB
    __shared__ int    sidx2[NP2];                     // 1 KiB
    __shared__ float4 mrgc[2][4];                     // winner coords + value
    __shared__ int    mrgi[2][4];

    if (blockIdx.x < (unsigned)B_) {
        __builtin_amdgcn_s_setprio(3);
        const int t = threadIdx.x, lane = t & 63, wave = t >> 6;
        const int b = blockIdx.x;
        const float* pb = x + (long)b*6*N_;

        // register-resident coords: thread t owns points [8t, 8t+8)
        float px[8], py[8], pz[8], dl[8];
        {
            const float4* a4 = (const float4*)(pb + 8*t);
            const float4* b4 = (const float4*)(pb + N_ + 8*t);
            const float4* c4p = (const float4*)(pb + 2*N_ + 8*t);
            float4 a0 = a4[0], a1 = a4[1];
            float4 b0 = b4[0], b1 = b4[1];
            float4 c0 = c4p[0], c1 = c4p[1];
            px[0]=a0.x; px[1]=a0.y; px[2]=a0.z; px[3]=a0.w;
            px[4]=a1.x; px[5]=a1.y; px[6]=a1.z; px[7]=a1.w;
            py[0]=b0.x; py[1]=b0.y; py[2]=b0.z; py[3]=b0.w;
            py[4]=b1.x; py[5]=b1.y; py[6]=b1.z; py[7]=b1.w;
            pz[0]=c0.x; pz[1]=c0.y; pz[2]=c0.z; pz[3]=c0.w;
            pz[4]=c1.x; pz[5]=c1.y; pz[6]=c1.z; pz[7]=c1.w;
        }
        #pragma unroll
        for (int p = 0; p < 8; p++) dl[p] = 1e10f;

        float cx = pb[0], cy = pb[N_], cz = pb[2*N_];
        int far = 0;

        // ---------------- FPS1: 2048 -> 512 ----------------
        for (int i = 0; i < NP1; i++) {
            if (t == 0) { sidx1[i] = far; mx2[i] = cx; my2[i] = cy; mz2[i] = cz; }
            float bv = -1.0f; int bp = 0;
            #pragma unroll
            for (int p = 0; p < 8; p++) {
                float dx = __fsub_rn(px[p], cx);
                float dy = __fsub_rn(py[p], cy);
                float dz = __fsub_rn(pz[p], cz);
                float d  = __fadd_rn(__fadd_rn(__fmul_rn(dx,dx), __fmul_rn(dy,dy)), __fmul_rn(dz,dz));
                float nd = fminf(dl[p], d);
                dl[p] = nd;
                if (nd > bv) { bv = nd; bp = p; }   // ascending p: first-index ties
            }
            float wx = px[0], wy = py[0], wz = pz[0];
            #pragma unroll
            for (int p = 1; p < 8; p++) {
                bool c = (bp == p);
                wx = c ? px[p] : wx; wy = c ? py[p] : wy; wz = c ? pz[p] : wz;
            }
            float gm = wave_max64_sgpr(bv);        // pure VALU + readlane
            unsigned long long cand = __ballot(bv == gm);
            int wl = __ffsll((long long)cand) - 1; // lowest lane = lowest orig idx
            int   wbp = __builtin_amdgcn_readlane(bp, wl);
            float sxw = __int_as_float(__builtin_amdgcn_readlane(__float_as_int(wx), wl));
            float syw = __int_as_float(__builtin_amdgcn_readlane(__float_as_int(wy), wl));
            float szw = __int_as_float(__builtin_amdgcn_readlane(__float_as_int(wz), wl));
            int par = i & 1;
            if (lane == 0) {
                mrgc[par][wave] = make_float4(sxw, syw, szw, gm);
                mrgi[par][wave] = (((wave << 6) | wl) << 3) + wbp;
            }
            __syncthreads();
            float4 e0 = mrgc[par][0];
            float fv = e0.w; int fi = mrgi[par][0];
            float ncx = e0.x, ncy = e0.y, ncz = e0.z;
            #pragma unroll
            for (int w2 = 1; w2 < 4; w2++) {
                float4 e2 = mrgc[par][w2]; int i2 = mrgi[par][w2];
                if (e2.w > fv) { fv = e2.w; fi = i2; ncx = e2.x; ncy = e2.y; ncz = e2.z; }
            }
            far = fi; cx = ncx; cy = ncy; cz = ncz;
        }
        __syncthreads();   // mir/sidx1 complete

        int*   f1o = fps1 + b*NP1;
        float* n1o = nx1 + (long)b*NP1*3;
        for (int s = t; s < NP1; s += 256) {
            f1o[s] = sidx1[s];
            n1o[(long)s*3+0] = mx2[s];
            n1o[(long)s*3+1] = my2[s];
            n1o[(long)s*3+2] = mz2[s];
        }

        // ---------------- FPS2: 512 -> 256 (2 pts/thread from mir) ----------
        {
            const int n0 = t << 1;
            float ax = mx2[n0],   ay = my2[n0],   az = mz2[n0];
            float bx = mx2[n0+1], by = my2[n0+1], bz = mz2[n0+1];
            float dl0 = 1e10f, dl1 = 1e10f;
            int far2 = 0;
            float c2x = mx2[0], c2y = my2[0], c2z = mz2[0];
            for (int i = 0; i < NP2; i++) {
                if (t == 0) sidx2[i] = far2;
                float dx = __fsub_rn(ax, c2x), dy = __fsub_rn(ay, c2y), dz = __fsub_rn(az, c2z);
                float d0 = __fadd_rn(__fadd_rn(__fmul_rn(dx,dx), __fmul_rn(dy,dy)), __fmul_rn(dz,dz));
                dx = __fsub_rn(bx, c2x); dy = __fsub_rn(by, c2y); dz = __fsub_rn(bz, c2z);
                float d1 = __fadd_rn(__fadd_rn(__fmul_rn(dx,dx), __fmul_rn(dy,dy)), __fmul_rn(dz,dz));
                dl0 = fminf(dl0, d0);
                dl1 = fminf(dl1, d1);
                float bv = dl0; int bp = 0;
                if (dl1 > bv) { bv = dl1; bp = 1; }
                float wx = bp ? bx : ax, wy = bp ? by : ay, wz = bp ? bz : az;
                float gm = wave_max64_sgpr(bv);
                unsigned long long cand = __ballot(bv == gm);
                int wl = __ffsll((long long)cand) - 1;
                int   wbp = __builtin_amdgcn_readlane(bp, wl);
                float sxw = __int_as_float(__builtin_amdgcn_readlane(__float_as_int(wx), wl));
                float syw = __int_as_float(__builtin_amdgcn_readlane(__float_as_int(wy), wl));
                float szw = __int_as_float(__builtin_amdgcn_readlane(__float_as_int(wz), wl));
                int par = i & 1;
                if (lane == 0) {
                    mrgc[par][wave] = make_float4(sxw, syw, szw, gm);
                    mrgi[par][wave] = (((wave << 6) | wl) << 1) + wbp;
                }
                __syncthreads();
                float4 e0 = mrgc[par][0];
                float fv = e0.w; int fi = mrgi[par][0];
                float ncx = e0.x, ncy = e0.y, ncz = e0.z;
                #pragma unroll
                for (int w2 = 1; w2 < 4; w2++) {
                    float4 e2 = mrgc[par][w2]; int i2 = mrgi[par][w2];
                    if (e2.w > fv) { fv = e2.w; fi = i2; ncx = e2.x; ncy = e2.y; ncz = e2.z; }
                }
                far2 = fi; c2x = ncx; c2y = ncy; c2z = ncz;
            }
        }
        __syncthreads();   // sidx2 visible

        int*   f2o = fps2 + b*NP2;
        float* n2o = nx2 + (long)b*NP2*3;
        for (int s = t; s < NP2; s += 256) {
            int j = sidx2[s];
            f2o[s] = j;
            n2o[(long)s*3+0] = mx2[j];
            n2o[(long)s*3+1] = my2[j];
            n2o[(long)s*3+2] = mz2[j];
        }
        __builtin_amdgcn_s_setprio(0);
        return;
    }

    // stripe decode: 8-wide groups alternate geo / feat; r == XCD
    const unsigned g = (blockIdx.x - B_) >> 3;
    const unsigned r = (blockIdx.x - B_) & 7;
    if ((g & 1u) == 0u) {
        int gi = (int)((g >> 1) * 8 + r);           // 0..8191
        knn_gbody<N_,32,KG>(x, (long)6*N_, 1, N_, N_,
                            x, (long)6*N_, 1, N_, idxg, gi);
        return;
    }

    // -------------------- feature knn (direct, XCD-pinned) --------------------
    {
        const int kk = (int)(g >> 1);               // 0..1023
        const int b  = (int)r + 8 * (kk >> 9);      // batch pinned to XCD r
        const int q4 = kk & 511;
        const int t = threadIdx.x, lane = t & 63, w = t >> 6;
        const int qi = q4*4 + w;
        const float* ftb = ft + ((long)b*N_)*64;
        const float* sqb = sq + (long)b*N_;

        // query row in registers (wave-uniform loads)
        float qv[64];
        {
            const float4* qr = (const float4*)(ftb + (long)qi*64);
            #pragma unroll
            for (int i = 0; i < 16; i++) {
                float4 f = qr[i];
                qv[4*i+0]=f.x; qv[4*i+1]=f.y; qv[4*i+2]=f.z; qv[4*i+3]=f.w;
            }
        }
        float sumq = sqb[qi];
        float v[32];
        #pragma unroll 2
        for (int j = 0; j < 32; j++) {
            const float4* rr = (const float4*)(ftb + (long)(j*64+lane)*64);
            float d0=0.f, d1=0.f, d2=0.f, d3=0.f;
            #pragma unroll
            for (int i = 0; i < 4; i++) {
                float4 r0 = rr[4*i+0], r1 = rr[4*i+1], r2 = rr[4*i+2], r3 = rr[4*i+3];
                d0 += qv[16*i+ 0]*r0.x + qv[16*i+ 1]*r0.y + qv[16*i+ 2]*r0.z + qv[16*i+ 3]*r0.w;
                d1 += qv[16*i+ 4]*r1.x + qv[16*i+ 5]*r1.y + qv[16*i+ 6]*r1.z + qv[16*i+ 7]*r1.w;
                d2 += qv[16*i+ 8]*r2.x + qv[16*i+ 9]*r2.y + qv[16*i+10]*r2.z + qv[16*i+11]*r2.w;
                d3 += qv[16*i+12]*r3.x + qv[16*i+13]*r3.y + qv[16*i+14]*r3.z + qv[16*i+15]*r3.w;
            }
            float dot = (d0 + d1) + (d2 + d3);
            v[j] = (sumq - 2.0f*dot) + sqb[j*64 + lane];
        }
        topk_sel3<32, KG>(v, lane, idxf + ((long)b*N_ + qi)*KG);
    }
}

// ---------------------------------------------------------------------------
// generic 64x64-tile fp32 GEMM: C[b] = A[b] * Bw^T with epilogues.
// ---------------------------------------------------------------------------
__global__ void __launch_bounds__(256) k_gemm(
    const float* __restrict__ A, long aBatch, int aRow,
    const float* __restrict__ Bw, long bBatch, int K,
    float* __restrict__ C, long cBatch, int cRow, int cCol0,
    int act, const float* __restrict__ sv, const float* __restrict__ tv,
    int epi)
{
    __shared__ float As[64][68];
    __shared__ float Bs[64][68];
    const int b  = blockIdx.z;
    const int ib = blockIdx.x * 64;
    const int jb = blockIdx.y * 64;
    const int t  = threadIdx.x;
    const int tx = t & 15, ty = t >> 4;
    const float* Ab = A + (long)b * aBatch;
    const float* Bb = Bw + (long)b * bBatch;
    float acc[4][4];
    #pragma unroll
    for (int i = 0; i < 4; i++)
        #pragma unroll
        for (int j = 0; j < 4; j++) acc[i][j] = 0.0f;

    for (int kb = 0; kb < K; kb += 64) {
        #pragma unroll
        for (int m = 0; m < 4; m++) {
            int li = t + m*256; int r = li >> 4; int c4 = li & 15;
            float4 av = *(const float4*)(Ab + (long)(ib + r)*aRow + kb + c4*4);
            As[c4*4+0][r] = av.x; As[c4*4+1][r] = av.y;
            As[c4*4+2][r] = av.z; As[c4*4+3][r] = av.w;
            float4 bv = *(const float4*)(Bb + (long)(jb + r)*K + kb + c4*4);
            Bs[c4*4+0][r] = bv.x; Bs[c4*4+1][r] = bv.y;
            Bs[c4*4+2][r] = bv.z; Bs[c4*4+3][r] = bv.w;
        }
        __syncthreads();
        #pragma unroll 4
        for (int k = 0; k < 64; k++) {
            float4 a  = *(const float4*)&As[k][ty*4];
            float4 b4 = *(const float4*)&Bs[k][tx*4];
            acc[0][0] += a.x*b4.x; acc[0][1] += a.x*b4.y; acc[0][2] += a.x*b4.z; acc[0][3] += a.x*b4.w;
            acc[1][0] += a.y*b4.x; acc[1][1] += a.y*b4.y; acc[1][2] += a.y*b4.z; acc[1][3] += a.y*b4.w;
            acc[2][0] += a.z*b4.x; acc[2][1] += a.z*b4.y; acc[2][2] += a.z*b4.z; acc[2][3] += a.z*b4.w;
            acc[3][0] += a.w*b4.x; acc[3][1] += a.w*b4.y; acc[3][2] += a.w*b4.z; acc[3][3] += a.w*b4.w;
        }
        __syncthreads();
    }

    const int i0 = ib + ty*4;
    const int j0 = jb + tx*4;
    if (epi == 2) {
        #pragma unroll
        for (int ii = 0; ii < 4; ii++)
            #pragma unroll
            for (int jj = 0; jj < 4; jj++) {
                int j = j0 + jj;
                float vv = lrelu_(sv[j]*acc[ii][jj] + tv[j]);
                C[(long)b*cBatch + (long)j*cRow + (i0+ii)] = vv;
            }
    } else {
        #pragma unroll
        for (int ii = 0; ii < 4; ii++)
            #pragma unroll
            for (int jj = 0; jj < 4; jj++) {
                int j = j0 + jj;
                float vv = acc[ii][jj];
                if (act == 1) vv = fmaxf(sv[j]*vv + tv[j], 0.0f);
                else if (act == 2) vv = lrelu_(sv[j]*vv + tv[j]);
                C[(long)b*cBatch + (long)(i0+ii)*cRow + cCol0 + j] = vv;
            }
    }
}

// ---------------------------------------------------------------------------
// edge gather-max (geo + feat) + fuse GEMM + bn/lrelu -> out_feat_t (B,N,64)
// ---------------------------------------------------------------------------
__global__ void __launch_bounds__(256) k_edgefuse(
    const float* __restrict__ P, const int* __restrict__ idxg, const int* __restrict__ idxf,
    const float* __restrict__ wft, const float* __restrict__ sc,
    float* __restrict__ outf)
{
    __shared__ float wt[128*64];
    __shared__ float fused[4][128];
    const int t = threadIdx.x, lane = t & 63, w = t >> 6;
    for (int i = t; i < 128*64; i += 256) wt[i] = wft[i];
    const int pid = blockIdx.x*4 + w;
    const int b = pid >> 11, n = pid & (N_-1);
    const float* Prow = P + ((long)b*N_ + n)*256;
    const int* ig  = idxg + ((long)b*N_ + n)*KG;
    const int* ifx = idxf + ((long)b*N_ + n)*KG;
    float gmax = -FLT_MAX, hmax = -FLT_MAX;
    for (int k = 0; k < KG; k++) {
        int idg = ig[k];
        gmax = fmaxf(gmax, P[((long)b*N_ + idg)*256 + lane]);
        int idf = ifx[k];
        hmax = fmaxf(hmax, P[((long)b*N_ + idf)*256 + 128 + lane]);
    }
    float glin = gmax - Prow[lane]       + Prow[64 + lane];
    float hlin = hmax - Prow[128 + lane] + Prow[192 + lane];
    float gv = lrelu_(sc[SC_SGEO + lane]*glin + sc[SC_TGEO + lane]);
    float hv = lrelu_(sc[SC_SFEAT + lane]*hlin + sc[SC_TFEAT + lane]);
    fused[w][lane]      = gv;
    fused[w][64 + lane] = hv;
    __syncthreads();
    float acc = 0.0f;
    #pragma unroll 8
    for (int c4 = 0; c4 < 32; c4++) {
        float4 f = *(const float4*)&fused[w][c4*4];
        acc += f.x * wt[(c4*4+0)*64 + lane];
        acc += f.y * wt[(c4*4+1)*64 + lane];
        acc += f.z * wt[(c4*4+2)*64 + lane];
        acc += f.w * wt[(c4*4+3)*64 + lane];
    }
    float ov = lrelu_(sc[SC_SFUSE + lane]*acc + sc[SC_TFUSE + lane]);
    outf[((long)b*N_ + n)*64 + lane] = ov;
}

// ---------------------------------------------------------------------------
// local_op gather-max: out[b,s,o] = relu(bn(max_k Q[idx[k]][o] + Qc[crow][CO+o]))
// ---------------------------------------------------------------------------
template<int QN, int ROWW, int CO, int MROWS, int SO>
__global__ void __launch_bounds__(256) k_gathermax(
    const float* __restrict__ Q, const int* __restrict__ knn, const int* __restrict__ fpsi,
    const float* __restrict__ sv, const float* __restrict__ tv,
    float* __restrict__ outp, int outRow)
{
    const int t = threadIdx.x, lane = t & 63, w = t >> 6;
    const int pid = blockIdx.x*4 + w;
    const int b = pid / SO, s = pid % SO;
    const int* ix = knn + ((long)b*SO + s)*NSAMP;
    float mx[QN];
    #pragma unroll
    for (int q = 0; q < QN; q++) mx[q] = -FLT_MAX;
    for (int k = 0; k < NSAMP; k++) {
        int id = ix[k];
        const float* r = Q + ((long)b*MROWS + id)*ROWW;
        #pragma unroll
        for (int q = 0; q < QN; q++) mx[q] = fmaxf(mx[q], r[lane + 64*q]);
    }
    int crow = fpsi[b*SO + s];
    const float* cr = Q + ((long)b*MROWS + crow)*ROWW + CO;
    #pragma unroll
    for (int q = 0; q < QN; q++) {
        int o = lane + 64*q;
        float lin = mx[q] + cr[o];
        float val = fmaxf(sv[o]*lin + tv[o], 0.0f);
        outp[((long)b*SO + s)*outRow + o] = val;
    }
}

// ---------------------------------------------------------------------------
extern "C" void kernel_launch(void* const* d_in, const int* in_sizes, int n_in,
                              void* d_out, int out_size, void* d_ws, size_t ws_size,
                              hipStream_t stream)
{
    const float* x      = (const float*)d_in[0];
    const float* w1     = (const float*)d_in[1];
    const float* bn1    = (const float*)d_in[2];
    const float* w2     = (const float*)d_in[3];
    const float* bn2    = (const float*)d_in[4];
    const float* geow   = (const float*)d_in[5];
    const float* geobn  = (const float*)d_in[6];
    const float* featw  = (const float*)d_in[7];
    const float* featbn = (const float*)d_in[8];
    const float* fusew  = (const float*)d_in[9];
    const float* fusebn = (const float*)d_in[10];
    const float* gl0w   = (const float*)d_in[11];
    const float* gl0bn  = (const float*)d_in[12];
    const float* gl1w   = (const float*)d_in[13];
    const float* gl1bn  = (const float*)d_in[14];
    const float* wf     = (const float*)d_in[15];
    const float* bnfp   = (const float*)d_in[16];

    float* ws  = (float*)d_ws;
    float* out = (float*)d_out;

    float* FT   = ws + OFF_FT;
    float* SQ   = ws + OFF_SQ;
    float* BIG  = ws + OFF_BIG;
    int*   IDXG = (int*)(ws + OFF_IDXG);
    int*   IDXF = (int*)(ws + OFF_IDXF);
    float* OUTF = ws + OFF_OUTF;
    int*   FPS1 = (int*)(ws + OFF_FPS1);
    float* NX1  = ws + OFF_NX1;
    int*   IDX1 = (int*)(ws + OFF_IDX1);
    float* F0T  = ws + OFF_F0T;
    int*   FPS2 = (int*)(ws + OFF_FPS2);
    float* NX2  = ws + OFF_NX2;
    int*   IDX2 = (int*)(ws + OFF_IDX2);
    float* Q1B  = ws + OFF_Q1;
    float* V    = ws + OFF_V;
    float* WPP  = ws + OFF_WPP;
    float* WPQ0 = ws + OFF_WPQ0;
    float* WPQ1 = ws + OFF_WPQ1;
    float* WFT  = ws + OFF_WFT;
    float* SC   = ws + OFF_SC;
    const float* nfp = nullptr;

    hipLaunchKernelGGL(k_prep, dim3(64), dim3(256), 0, stream,
        bn1, bn2, geow, geobn, featw, featbn, fusew, fusebn, gl0w, gl0bn, gl1w, gl1bn, bnfp, ws);

    hipLaunchKernelGGL(k_feat0, dim3(B_*N_/4), dim3(256), 0, stream, x, w1, SC, FT, SQ);

    // mega-dispatch: FPS chain + geo knn + direct feature knn (XCD-pinned)
    hipLaunchKernelGGL(k_front, dim3(B_ + 2*B_*(N_/4)), dim3(256), 0, stream,
        x, FT, SQ, IDXG, IDXF, FPS1, NX1, FPS2, NX2);

    // P projection (B,N,256) into BIG
    hipLaunchKernelGGL(k_gemm, dim3(N_/64, 256/64, B_), dim3(256), 0, stream,
        FT, (long)N_*64, 64, WPP, (long)0, 64,
        BIG, (long)N_*256, 256, 0, 0, nfp, nfp, 0);

    hipLaunchKernelGGL(k_edgefuse, dim3(B_*N_/4), dim3(256), 0, stream,
        BIG, IDXG, IDXF, WFT, SC, OUTF);

    // grouping knn 1 (queries = NX1 from fused FPS), global-read refs
    hipLaunchKernelGGL((k_knn3d_g<2048,32,32>), dim3(B_*(NP1/4)), dim3(256), 0, stream,
        NX1, (long)NP1*3, 3, 1, NP1, x, (long)6*N_, (long)1, (long)N_, IDX1);

    // Q0 projection (B,N,256) into BIG (P is dead now)
    hipLaunchKernelGGL(k_gemm, dim3(N_/64, 256/64, B_), dim3(256), 0, stream,
        OUTF, (long)N_*64, 64, WPQ0, (long)0, 64,
        BIG, (long)N_*256, 256, 0, 0, nfp, nfp, 0);

    hipLaunchKernelGGL((k_gathermax<2,256,128,2048,512>), dim3(B_*NP1/4), dim3(256), 0, stream,
        BIG, IDX1, FPS1, SC + SC_SGL0, SC + SC_TGL0, F0T, 128);

    // grouping knn 2 (queries = NX2), global-read refs
    hipLaunchKernelGGL((k_knn3d_g<512,8,32>), dim3(B_*(NP2/4)), dim3(256), 0, stream,
        NX2, (long)NP2*3, 3, 1, NP2, NX1, (long)NP1*3, (long)3, (long)1, IDX2);

    // Q1 projection (B,512,512)
    hipLaunchKernelGGL(k_gemm, dim3(NP1/64, 512/64, B_), dim3(256), 0, stream,
        F0T, (long)NP1*128, 128, WPQ1, (long)0, 128,
        Q1B, (long)NP1*512, 512, 0, 0, nfp, nfp, 0);

    hipLaunchKernelGGL((k_gathermax<4,512,256,512,256>), dim3(B_*NP2/4), dim3(256), 0, stream,
        Q1B, IDX2, FPS2, SC + SC_SGL1, SC + SC_TGL1, V, 1280);

    // x_skip -> V[:, :, 256:1280]  (A = f_t rows at stride 8 points)
    hipLaunchKernelGGL(k_gemm, dim3(NP2/64, 1024/64, B_), dim3(256), 0, stream,
        FT, (long)N_*64, 512, w2, (long)0, 64,
        V, (long)NP2*1280, 1280, 256, 1, SC + SC_S2, SC + SC_T2, 0);

    // final (B,512,256) = lrelu(bnf(wf . V^T)), transposed store
    hipLaunchKernelGGL(k_gemm, dim3(NP2/64, 512/64, B_), dim3(256), 0, stream,
        V, (long)NP2*1280, 1280, wf, (long)0, 1280,
        out, (long)512*256, 256, 0, 2, SC + SC_SF, SC + SC_TF, 2);

    (void)in_sizes; (void)n_in; (void)out_size; (void)ws_size;
}

// Round 14
// 1041.362 us; speedup vs baseline: 6.8358x; 6.8358x over previous
//
#include <hip/hip_runtime.h>
#include <float.h>
#include <math.h>

// ---------------------------------------------------------------------------
// SSFE_Net pipeline on MI355X. B=16, N=2048.
// R11/R12: direct feature-knn — FAILED (16.8GB logical FT re-read cannot be
//          made L2-resident; XCD pinning via blockIdx%8 falsified by FETCH).
// R13: revert to R10 structure (1102us) + software-pipeline the feature-knn:
//      one dispatch = {select(chunk i-1) || gemm(chunk i)}, double-buffered
//      chunk storage (buf0=BIG, buf1=Q1+V region, free until Q1 projection).
// ---------------------------------------------------------------------------

static constexpr int B_   = 16;
static constexpr int N_   = 2048;
static constexpr int NP1  = 512;
static constexpr int NP2  = 256;
static constexpr int KG   = 20;
static constexpr int NSAMP= 32;
static constexpr int CHQ  = 256;   // query chunk for feature-knn distance matrix

// workspace offsets (in float elements)
static constexpr long OFF_FT   = 0;
static constexpr long OFF_SQ   = OFF_FT   + (long)B_*N_*64;
static constexpr long OFF_BIG  = OFF_SQ   + (long)B_*N_;          // D chunk A / P / Q0
static constexpr long OFF_IDXG = OFF_BIG  + (long)B_*N_*256;
static constexpr long OFF_IDXF = OFF_IDXG + (long)B_*N_*KG;
static constexpr long OFF_OUTF = OFF_IDXF + (long)B_*N_*KG;
static constexpr long OFF_FPS1 = OFF_OUTF + (long)B_*N_*64;
static constexpr long OFF_NX1  = OFF_FPS1 + (long)B_*NP1;
static constexpr long OFF_IDX1 = OFF_NX1  + (long)B_*NP1*3;
static constexpr long OFF_F0T  = OFF_IDX1 + (long)B_*NP1*NSAMP;
static constexpr long OFF_FPS2 = OFF_F0T  + (long)B_*NP1*128;
static constexpr long OFF_NX2  = OFF_FPS2 + (long)B_*NP2;
static constexpr long OFF_IDX2 = OFF_NX2  + (long)B_*NP2*3;
static constexpr long OFF_Q1   = OFF_IDX2 + (long)B_*NP2*NSAMP;  // D chunk B (Q1+V, 9.4M)
static constexpr long OFF_V    = OFF_Q1   + (long)B_*NP1*512;
static constexpr long OFF_WPP  = OFF_V    + (long)B_*NP2*1280;
static constexpr long OFF_WPQ0 = OFF_WPP  + 256*64;
static constexpr long OFF_WPQ1 = OFF_WPQ0 + 256*64;
static constexpr long OFF_WFT  = OFF_WPQ1 + 512*128;
static constexpr long OFF_SC   = OFF_WFT  + 128*64;

// SC (bn scale/shift) sub-offsets
static constexpr int SC_S1=0, SC_T1=64, SC_SGEO=128, SC_TGEO=192, SC_SFEAT=256, SC_TFEAT=320,
   SC_SFUSE=384, SC_TFUSE=448, SC_SGL0=512, SC_TGL0=640, SC_SGL1=768, SC_TGL1=1024,
   SC_S2=1280, SC_T2=2304, SC_SF=3328, SC_TF=3840;

__device__ __forceinline__ float lrelu_(float x) { return x >= 0.0f ? x : 0.2f * x; }

// masked DPP max step: masked-off rows keep v (old = v)
template<int CTRL, int RM>
__device__ __forceinline__ float dpp_maxm(float v) {
    int o = __builtin_amdgcn_update_dpp(__float_as_int(v), __float_as_int(v),
                                        CTRL, RM, 0xF, false);
    return fmaxf(v, __int_as_float(o));
}
// pure-VALU wave64 max -> uniform SGPR value (no ds_swizzle/bpermute).
__device__ __forceinline__ float wave_max64_sgpr(float v) {
    v = dpp_maxm<0xB1, 0xF>(v);   // quad_perm(1,0,3,2)
    v = dpp_maxm<0x4E, 0xF>(v);   // quad_perm(2,3,0,1)
    v = dpp_maxm<0x141,0xF>(v);   // row_half_mirror
    v = dpp_maxm<0x140,0xF>(v);   // row_mirror  -> row max in all 16 lanes
    v = dpp_maxm<0x142,0xA>(v);   // row_bcast15 -> rows 1,3 combine
    v = dpp_maxm<0x143,0xC>(v);   // row_bcast31 -> lane63 = max
    return __int_as_float(__builtin_amdgcn_readlane(__float_as_int(v), 63));
}

// DPP-accelerated wave64 unsigned min (value only, all lanes) — knn topk.
template<int CTRL>
__device__ __forceinline__ unsigned dpp_minu(unsigned x) {
    unsigned o = (unsigned)__builtin_amdgcn_update_dpp(0, (int)x, CTRL, 0xF, 0xF, true);
    return o < x ? o : x;
}
__device__ __forceinline__ unsigned wave_minu(unsigned x) {
    x = dpp_minu<0xB1>(x);
    x = dpp_minu<0x4E>(x);
    x = dpp_minu<0x141>(x);
    x = dpp_minu<0x140>(x);
    { unsigned o = (unsigned)__shfl_xor((int)x, 16); x = o < x ? o : x; }
    { unsigned o = (unsigned)__shfl_xor((int)x, 32); x = o < x ? o : x; }
    return x;
}

// monotone float -> sortable u32 (handles negative values from rounding)
__device__ __forceinline__ unsigned sortable_(float f) {
    unsigned u = __float_as_uint(f);
    return u ^ ((unsigned)((int)u >> 31) | 0x80000000u);
}

// ---------------------------------------------------------------------------
// prep: bn scale/shift + packed weight matrices
// ---------------------------------------------------------------------------
__global__ void k_prep(const float* __restrict__ bn1, const float* __restrict__ bn2,
                       const float* __restrict__ geow, const float* __restrict__ geobn,
                       const float* __restrict__ featw, const float* __restrict__ featbn,
                       const float* __restrict__ fusew, const float* __restrict__ fusebn,
                       const float* __restrict__ gl0w, const float* __restrict__ gl0bn,
                       const float* __restrict__ gl1w, const float* __restrict__ gl1bn,
                       const float* __restrict__ bnfp, float* __restrict__ ws)
{
    const int tid = blockIdx.x * blockDim.x + threadIdx.x;
    const int nt  = gridDim.x * blockDim.x;
    float* sc = ws + OFF_SC;

    {
        const float* ps[8]  = {bn1, geobn, featbn, fusebn, gl0bn, gl1bn, bn2, bnfp};
        const int    ch[8]  = {64, 64, 64, 64, 128, 256, 1024, 512};
        const int    so[8]  = {SC_S1, SC_SGEO, SC_SFEAT, SC_SFUSE, SC_SGL0, SC_SGL1, SC_S2, SC_SF};
        const int    to[8]  = {SC_T1, SC_TGEO, SC_TFEAT, SC_TFUSE, SC_TGL0, SC_TGL1, SC_T2, SC_TF};
        for (int g = 0; g < 8; g++) {
            const float* p = ps[g]; int C = ch[g];
            for (int i = tid; i < C; i += nt) {
                float gg = p[i], bb = p[C+i], mm = p[2*C+i], vv = p[3*C+i];
                float s = gg * (1.0f / sqrtf(vv + 1e-5f));
                sc[so[g] + i] = s;
                sc[to[g] + i] = bb - mm * s;
            }
        }
    }
    for (int j = tid; j < 256*64; j += nt) {
        int o = j >> 6, c = j & 63; float v;
        if      (o < 64)  v = geow[o*128 + c];
        else if (o < 128) v = geow[(o-64)*128 + 64 + c];
        else if (o < 192) v = featw[(o-128)*128 + c];
        else              v = featw[(o-192)*128 + 64 + c];
        ws[OFF_WPP + j] = v;
    }
    for (int j = tid; j < 256*64; j += nt) {
        int o = j >> 6, c = j & 63; float v;
        if (o < 128) v = gl0w[o*128 + c];
        else         v = gl0w[(o-128)*128 + 64 + c] - gl0w[(o-128)*128 + c];
        ws[OFF_WPQ0 + j] = v;
    }
    for (int j = tid; j < 512*128; j += nt) {
        int o = j >> 7, c = j & 127; float v;
        if (o < 256) v = gl1w[o*256 + c];
        else         v = gl1w[(o-256)*256 + 128 + c] - gl1w[(o-256)*256 + c];
        ws[OFF_WPQ1 + j] = v;
    }
    for (int j = tid; j < 128*64; j += nt) {
        int c = j >> 6, o = j & 63;
        ws[OFF_WFT + j] = fusew[o*128 + c];
    }
}

// ---------------------------------------------------------------------------
// f_t[b][n][o] = relu(bn1(sum_c w1[o][c]*x[b][c][n])) ; sq[b][n] = sum_o f^2
// ---------------------------------------------------------------------------
__global__ void __launch_bounds__(256) k_feat0(const float* __restrict__ x,
                                               const float* __restrict__ w1,
                                               const float* __restrict__ sc,
                                               float* __restrict__ ft, float* __restrict__ sq)
{
    const int t = threadIdx.x, lane = t & 63, w = t >> 6;
    const int pid = blockIdx.x*4 + w;
    const int b = pid >> 11, n = pid & (N_-1);
    const float* xb = x + (long)b*6*N_ + n;
    float acc = 0.0f;
    #pragma unroll
    for (int c = 0; c < 6; c++) acc += w1[lane*6 + c] * xb[(long)c*N_];
    float val = fmaxf(sc[SC_S1 + lane]*acc + sc[SC_T1 + lane], 0.0f);
    ft[((long)b*N_ + n)*64 + lane] = val;
    float v2 = val*val;
    #pragma unroll
    for (int s = 1; s < 64; s <<= 1) v2 += __shfl_xor(v2, s);
    if (lane == 0) sq[b*N_ + n] = v2;
}

// ---------------------------------------------------------------------------
// topk_sel3: k smallest (stable first-index ties), index = j*64+lane.
// Per-lane top-2 cache + consumed bitmask; rescan only on second win.
// ---------------------------------------------------------------------------
template<int RPL, int KSEL>
__device__ __forceinline__ void topk_sel3(float (&v)[RPL], int lane, int* __restrict__ out)
{
    unsigned key[RPL];
    #pragma unroll
    for (int j = 0; j < RPL; j++) key[j] = sortable_(v[j]);

    unsigned consumed = 0;
    unsigned m1 = key[0]; int s1 = 0;
    unsigned m2 = 0xFFFFFFFFu; int s2 = 0;
    #pragma unroll
    for (int j = 1; j < RPL; j++) {
        unsigned kk = key[j];
        bool lt1 = kk < m1;
        bool lt2 = kk < m2;
        unsigned nm2 = lt1 ? m1 : (lt2 ? kk : m2);
        int      ns2 = lt1 ? s1 : (lt2 ? j  : s2);
        m1 = lt1 ? kk : m1;
        s1 = lt1 ? j  : s1;
        m2 = nm2; s2 = ns2;
    }

    #pragma unroll 1
    for (int k = 0; k < KSEL; k++) {
        unsigned g = wave_minu(m1);
        unsigned long long cand = __ballot(m1 == g);
        int gi;
        if (__popcll(cand) > 1) {
            int ci = (m1 == g) ? (s1*64 + lane) : 0x7FFFFFFF;
            #pragma unroll
            for (int s = 1; s < 64; s <<= 1) { int o = __shfl_xor(ci, s); ci = o < ci ? o : ci; }
            gi = ci;
        } else {
            int wl = __ffsll((long long)cand) - 1;
            gi = __builtin_amdgcn_readlane(s1, wl) * 64 + wl;
        }
        if (lane == 0) out[k] = gi;
        if (k + 1 < KSEL) {
            bool win = (m1 == g) && (s1*64 + lane == gi);
            if (win) {
                consumed |= 1u << s1;
                m1 = m2; s1 = s2;
                m2 = 0xFFFFFFFFu;
            }
            bool need = win && (m1 == 0xFFFFFFFFu);
            if (__any(need)) {
                if (need) {
                    m1 = 0xFFFFFFFFu; s1 = 0; m2 = 0xFFFFFFFFu; s2 = 0;
                    #pragma unroll
                    for (int j = 0; j < RPL; j++) {
                        unsigned kk = ((consumed >> j) & 1u) ? 0xFFFFFFFFu : key[j];
                        bool lt1 = kk < m1;
                        bool lt2 = kk < m2;
                        unsigned nm2 = lt1 ? m1 : (lt2 ? kk : m2);
                        int      ns2 = lt1 ? s1 : (lt2 ? j  : s2);
                        m1 = lt1 ? kk : m1;
                        s1 = lt1 ? j  : s1;
                        m2 = nm2; s2 = ns2;
                    }
                }
            }
        }
    }
}

// ---------------------------------------------------------------------------
// geo-knn body, global-read refs (L1/L2-resident; no LDS, no barrier).
// ---------------------------------------------------------------------------
template<int NREF, int RPL, int KSEL>
__device__ __forceinline__ void knn_gbody(
    const float* qp, long qBatch, int qsN, int qsD, int NQ,
    const float* rp, long rBatch, long rsN, long rsD,
    int* out, int bid)
{
    const int t = threadIdx.x, lane = t & 63, w = t >> 6;
    const int bpb = NQ / 4;
    const int b = bid / bpb;
    const int qi = (bid % bpb)*4 + w;
    const float* rb = rp + (long)b*rBatch;
    const float* qb = qp + (long)b*qBatch + (long)qi*qsN;
    float qx = qb[0], qy = qb[qsD], qz = qb[2*qsD];
    float sumq = __fadd_rn(__fadd_rn(__fmul_rn(qx,qx), __fmul_rn(qy,qy)), __fmul_rn(qz,qz));
    float v[RPL];
    #pragma unroll
    for (int j = 0; j < RPL; j++) {
        long n = j*64 + lane;
        float rx = rb[n*rsN];
        float ry = rb[n*rsN + rsD];
        float rz = rb[n*rsN + 2*rsD];
        float dot  = __fadd_rn(__fadd_rn(__fmul_rn(qx,rx), __fmul_rn(qy,ry)), __fmul_rn(qz,rz));
        float sumr = __fadd_rn(__fadd_rn(__fmul_rn(rx,rx), __fmul_rn(ry,ry)), __fmul_rn(rz,rz));
        v[j] = __fadd_rn(__fsub_rn(sumq, __fmul_rn(2.0f, dot)), sumr);
    }
    topk_sel3<RPL, KSEL>(v, lane, out + ((long)b*NQ + qi)*KSEL);
}

template<int NREF, int RPL, int KSEL>
__global__ void __launch_bounds__(256, 4) k_knn3d_g(
    const float* __restrict__ qp, long qBatch, int qsN, int qsD, int NQ,
    const float* __restrict__ rp, long rBatch, long rsN, long rsD,
    int* __restrict__ out)
{
    knn_gbody<NREF,RPL,KSEL>(qp, qBatch, qsN, qsD, NQ,
                             rp, rBatch, rsN, rsD, out, blockIdx.x);
}

// ---------------------------------------------------------------------------
// fused dispatch: blocks [0,16) FPS1->FPS2; blocks [16,16+8192) geo-knn.
// (R10 version — 416us, best verified front-end.)
// ---------------------------------------------------------------------------
__global__ void __launch_bounds__(256, 4) k_geoknn_fps(
    const float* __restrict__ x, int* __restrict__ idxg,
    int* __restrict__ fps1, float* __restrict__ nx1,
    int* __restrict__ fps2, float* __restrict__ nx2)
{
    __shared__ float  mx2[NP1], my2[NP1], mz2[NP1];
    __shared__ int    sidx1[NP1];
    __shared__ int    sidx2[NP2];
    __shared__ float4 mrgc[2][4];
    __shared__ int    mrgi[2][4];

    if (blockIdx.x < (unsigned)B_) {
        __builtin_amdgcn_s_setprio(3);
        const int t = threadIdx.x, lane = t & 63, wave = t >> 6;
        const int b = blockIdx.x;
        const float* pb = x + (long)b*6*N_;

        float px[8], py[8], pz[8], dl[8];
        {
            const float4* a4 = (const float4*)(pb + 8*t);
            const float4* b4 = (const float4*)(pb + N_ + 8*t);
            const float4* c4p = (const float4*)(pb + 2*N_ + 8*t);
            float4 a0 = a4[0], a1 = a4[1];
            float4 b0 = b4[0], b1 = b4[1];
            float4 c0 = c4p[0], c1 = c4p[1];
            px[0]=a0.x; px[1]=a0.y; px[2]=a0.z; px[3]=a0.w;
            px[4]=a1.x; px[5]=a1.y; px[6]=a1.z; px[7]=a1.w;
            py[0]=b0.x; py[1]=b0.y; py[2]=b0.z; py[3]=b0.w;
            py[4]=b1.x; py[5]=b1.y; py[6]=b1.z; py[7]=b1.w;
            pz[0]=c0.x; pz[1]=c0.y; pz[2]=c0.z; pz[3]=c0.w;
            pz[4]=c1.x; pz[5]=c1.y; pz[6]=c1.z; pz[7]=c1.w;
        }
        #pragma unroll
        for (int p = 0; p < 8; p++) dl[p] = 1e10f;

        float cx = pb[0], cy = pb[N_], cz = pb[2*N_];
        int far = 0;

        for (int i = 0; i < NP1; i++) {
            if (t == 0) { sidx1[i] = far; mx2[i] = cx; my2[i] = cy; mz2[i] = cz; }
            float bv = -1.0f; int bp = 0;
            #pragma unroll
            for (int p = 0; p < 8; p++) {
                float dx = __fsub_rn(px[p], cx);
                float dy = __fsub_rn(py[p], cy);
                float dz = __fsub_rn(pz[p], cz);
                float d  = __fadd_rn(__fadd_rn(__fmul_rn(dx,dx), __fmul_rn(dy,dy)), __fmul_rn(dz,dz));
                float nd = fminf(dl[p], d);
                dl[p] = nd;
                if (nd > bv) { bv = nd; bp = p; }
            }
            float wx = px[0], wy = py[0], wz = pz[0];
            #pragma unroll
            for (int p = 1; p < 8; p++) {
                bool c = (bp == p);
                wx = c ? px[p] : wx; wy = c ? py[p] : wy; wz = c ? pz[p] : wz;
            }
            float gm = wave_max64_sgpr(bv);
            unsigned long long cand = __ballot(bv == gm);
            int wl = __ffsll((long long)cand) - 1;
            int   wbp = __builtin_amdgcn_readlane(bp, wl);
            float sxw = __int_as_float(__builtin_amdgcn_readlane(__float_as_int(wx), wl));
            float syw = __int_as_float(__builtin_amdgcn_readlane(__float_as_int(wy), wl));
            float szw = __int_as_float(__builtin_amdgcn_readlane(__float_as_int(wz), wl));
            int par = i & 1;
            if (lane == 0) {
                mrgc[par][wave] = make_float4(sxw, syw, szw, gm);
                mrgi[par][wave] = (((wave << 6) | wl) << 3) + wbp;
            }
            __syncthreads();
            float4 e0 = mrgc[par][0];
            float fv = e0.w; int fi = mrgi[par][0];
            float ncx = e0.x, ncy = e0.y, ncz = e0.z;
            #pragma unroll
            for (int w2 = 1; w2 < 4; w2++) {
                float4 e2 = mrgc[par][w2]; int i2 = mrgi[par][w2];
                if (e2.w > fv) { fv = e2.w; fi = i2; ncx = e2.x; ncy = e2.y; ncz = e2.z; }
            }
            far = fi; cx = ncx; cy = ncy; cz = ncz;
        }
        __syncthreads();

        int*   f1o = fps1 + b*NP1;
        float* n1o = nx1 + (long)b*NP1*3;
        for (int s = t; s < NP1; s += 256) {
            f1o[s] = sidx1[s];
            n1o[(long)s*3+0] = mx2[s];
            n1o[(long)s*3+1] = my2[s];
            n1o[(long)s*3+2] = mz2[s];
        }

        {
            const int n0 = t << 1;
            float ax = mx2[n0],   ay = my2[n0],   az = mz2[n0];
            float bx = mx2[n0+1], by = my2[n0+1], bz = mz2[n0+1];
            float dl0 = 1e10f, dl1 = 1e10f;
            int far2 = 0;
            float c2x = mx2[0], c2y = my2[0], c2z = mz2[0];
            for (int i = 0; i < NP2; i++) {
                if (t == 0) sidx2[i] = far2;
                float dx = __fsub_rn(ax, c2x), dy = __fsub_rn(ay, c2y), dz = __fsub_rn(az, c2z);
                float d0 = __fadd_rn(__fadd_rn(__fmul_rn(dx,dx), __fmul_rn(dy,dy)), __fmul_rn(dz,dz));
                dx = __fsub_rn(bx, c2x); dy = __fsub_rn(by, c2y); dz = __fsub_rn(bz, c2z);
                float d1 = __fadd_rn(__fadd_rn(__fmul_rn(dx,dx), __fmul_rn(dy,dy)), __fmul_rn(dz,dz));
                dl0 = fminf(dl0, d0);
                dl1 = fminf(dl1, d1);
                float bv = dl0; int bp = 0;
                if (dl1 > bv) { bv = dl1; bp = 1; }
                float wx = bp ? bx : ax, wy = bp ? by : ay, wz = bp ? bz : az;
                float gm = wave_max64_sgpr(bv);
                unsigned long long cand = __ballot(bv == gm);
                int wl = __ffsll((long long)cand) - 1;
                int   wbp = __builtin_amdgcn_readlane(bp, wl);
                float sxw = __int_as_float(__builtin_amdgcn_readlane(__float_as_int(wx), wl));
                float syw = __int_as_float(__builtin_amdgcn_readlane(__float_as_int(wy), wl));
                float szw = __int_as_float(__builtin_amdgcn_readlane(__float_as_int(wz), wl));
                int par = i & 1;
                if (lane == 0) {
                    mrgc[par][wave] = make_float4(sxw, syw, szw, gm);
                    mrgi[par][wave] = (((wave << 6) | wl) << 1) + wbp;
                }
                __syncthreads();
                float4 e0 = mrgc[par][0];
                float fv = e0.w; int fi = mrgi[par][0];
                float ncx = e0.x, ncy = e0.y, ncz = e0.z;
                #pragma unroll
                for (int w2 = 1; w2 < 4; w2++) {
                    float4 e2 = mrgc[par][w2]; int i2 = mrgi[par][w2];
                    if (e2.w > fv) { fv = e2.w; fi = i2; ncx = e2.x; ncy = e2.y; ncz = e2.z; }
                }
                far2 = fi; c2x = ncx; c2y = ncy; c2z = ncz;
            }
        }
        __syncthreads();

        int*   f2o = fps2 + b*NP2;
        float* n2o = nx2 + (long)b*NP2*3;
        for (int s = t; s < NP2; s += 256) {
            int j = sidx2[s];
            f2o[s] = j;
            n2o[(long)s*3+0] = mx2[j];
            n2o[(long)s*3+1] = my2[j];
            n2o[(long)s*3+2] = mz2[j];
        }
        __builtin_amdgcn_s_setprio(0);
        return;
    }
    knn_gbody<N_,32,KG>(x, (long)6*N_, 1, N_, N_,
                        x, (long)6*N_, 1, N_, idxg, blockIdx.x - B_);
}

// ---------------------------------------------------------------------------
// pipelined feature-knn: blocks [0,1024) = select(chunk ci-1, from Dold);
// blocks [1024, 3072) = distance GEMM (chunk ci -> Dnew). K=64 single tile.
// ---------------------------------------------------------------------------
__global__ void __launch_bounds__(256) k_dist_sel(
    const float* __restrict__ ft, const float* __restrict__ sq,
    float* __restrict__ Dnew, int qbNew,
    const float* __restrict__ Dold, int qbOld,
    int* __restrict__ idxf, int doSel)
{
    __shared__ float As[64][68];
    __shared__ float Bs[64][68];

    if (blockIdx.x < 1024u) {
        if (!doSel) return;
        const int t = threadIdx.x, lane = t & 63, w = t >> 6;
        const int r = blockIdx.x*4 + w;
        const int b = r >> 8, qi = r & (CHQ-1);
        const float* row = Dold + ((long)b*CHQ + qi) * N_;
        float v[32];
        #pragma unroll
        for (int j = 0; j < 32; j++) v[j] = row[j*64 + lane];
        topk_sel3<32, KG>(v, lane, idxf + ((long)b*N_ + qbOld + qi)*KG);
        return;
    }

    const int gi = (int)blockIdx.x - 1024;
    const int ib = gi & 3;          // CHQ/64
    const int jb = (gi >> 2) & 31;  // N/64
    const int b  = gi >> 7;
    const int t  = threadIdx.x;
    const int tx = t & 15, ty = t >> 4;
    const float* Ab = ft + ((long)b*N_ + qbNew + (long)ib*64)*64;
    const float* Bb = ft + ((long)b*N_ + (long)jb*64)*64;
    const float* sqb = sq + (long)b*N_;

    #pragma unroll
    for (int m = 0; m < 4; m++) {
        int li = t + m*256; int r = li >> 4; int c4 = li & 15;
        float4 av = *(const float4*)(Ab + (long)r*64 + c4*4);
        As[c4*4+0][r] = av.x; As[c4*4+1][r] = av.y;
        As[c4*4+2][r] = av.z; As[c4*4+3][r] = av.w;
        float4 bv = *(const float4*)(Bb + (long)r*64 + c4*4);
        Bs[c4*4+0][r] = bv.x; Bs[c4*4+1][r] = bv.y;
        Bs[c4*4+2][r] = bv.z; Bs[c4*4+3][r] = bv.w;
    }
    __syncthreads();
    float acc[4][4];
    #pragma unroll
    for (int i = 0; i < 4; i++)
        #pragma unroll
        for (int j = 0; j < 4; j++) acc[i][j] = 0.0f;
    #pragma unroll 4
    for (int k = 0; k < 64; k++) {
        float4 a  = *(const float4*)&As[k][ty*4];
        float4 b4 = *(const float4*)&Bs[k][tx*4];
        acc[0][0] += a.x*b4.x; acc[0][1] += a.x*b4.y; acc[0][2] += a.x*b4.z; acc[0][3] += a.x*b4.w;
        acc[1][0] += a.y*b4.x; acc[1][1] += a.y*b4.y; acc[1][2] += a.y*b4.z; acc[1][3] += a.y*b4.w;
        acc[2][0] += a.z*b4.x; acc[2][1] += a.z*b4.y; acc[2][2] += a.z*b4.z; acc[2][3] += a.z*b4.w;
        acc[3][0] += a.w*b4.x; acc[3][1] += a.w*b4.y; acc[3][2] += a.w*b4.z; acc[3][3] += a.w*b4.w;
    }
    const int i0 = ib*64 + ty*4;       // row within chunk
    const int j0 = jb*64 + tx*4;       // ref index
    #pragma unroll
    for (int ii = 0; ii < 4; ii++) {
        float sqq = sqb[qbNew + i0 + ii];
        #pragma unroll
        for (int jj = 0; jj < 4; jj++) {
            int r = j0 + jj;
            Dnew[((long)b*CHQ + i0 + ii)*N_ + r] = (sqq - 2.0f*acc[ii][jj]) + sqb[r];
        }
    }
}

// ---------------------------------------------------------------------------
// standalone top-20 selection (final chunk)
// ---------------------------------------------------------------------------
__global__ void __launch_bounds__(256, 4) k_selectD(const float* __restrict__ D, int qbase,
                                                    int* __restrict__ out)
{
    const int t = threadIdx.x, lane = t & 63, w = t >> 6;
    const int r = blockIdx.x*4 + w;
    const int b = r / CHQ, qi = r % CHQ;
    const float* row = D + ((long)b*CHQ + qi) * N_;
    float v[32];
    #pragma unroll
    for (int j = 0; j < 32; j++) v[j] = row[j*64 + lane];
    topk_sel3<32, KG>(v, lane, out + ((long)b*N_ + qbase + qi)*KG);
}

// ---------------------------------------------------------------------------
// generic 64x64-tile fp32 GEMM: C[b] = A[b] * Bw^T with epilogues.
// ---------------------------------------------------------------------------
__global__ void __launch_bounds__(256) k_gemm(
    const float* __restrict__ A, long aBatch, int aRow,
    const float* __restrict__ Bw, long bBatch, int K,
    float* __restrict__ C, long cBatch, int cRow, int cCol0,
    int act, const float* __restrict__ sv, const float* __restrict__ tv,
    int epi)
{
    __shared__ float As[64][68];
    __shared__ float Bs[64][68];
    const int b  = blockIdx.z;
    const int ib = blockIdx.x * 64;
    const int jb = blockIdx.y * 64;
    const int t  = threadIdx.x;
    const int tx = t & 15, ty = t >> 4;
    const float* Ab = A + (long)b * aBatch;
    const float* Bb = Bw + (long)b * bBatch;
    float acc[4][4];
    #pragma unroll
    for (int i = 0; i < 4; i++)
        #pragma unroll
        for (int j = 0; j < 4; j++) acc[i][j] = 0.0f;

    for (int kb = 0; kb < K; kb += 64) {
        #pragma unroll
        for (int m = 0; m < 4; m++) {
            int li = t + m*256; int r = li >> 4; int c4 = li & 15;
            float4 av = *(const float4*)(Ab + (long)(ib + r)*aRow + kb + c4*4);
            As[c4*4+0][r] = av.x; As[c4*4+1][r] = av.y;
            As[c4*4+2][r] = av.z; As[c4*4+3][r] = av.w;
            float4 bv = *(const float4*)(Bb + (long)(jb + r)*K + kb + c4*4);
            Bs[c4*4+0][r] = bv.x; Bs[c4*4+1][r] = bv.y;
            Bs[c4*4+2][r] = bv.z; Bs[c4*4+3][r] = bv.w;
        }
        __syncthreads();
        #pragma unroll 4
        for (int k = 0; k < 64; k++) {
            float4 a  = *(const float4*)&As[k][ty*4];
            float4 b4 = *(const float4*)&Bs[k][tx*4];
            acc[0][0] += a.x*b4.x; acc[0][1] += a.x*b4.y; acc[0][2] += a.x*b4.z; acc[0][3] += a.x*b4.w;
            acc[1][0] += a.y*b4.x; acc[1][1] += a.y*b4.y; acc[1][2] += a.y*b4.z; acc[1][3] += a.y*b4.w;
            acc[2][0] += a.z*b4.x; acc[2][1] += a.z*b4.y; acc[2][2] += a.z*b4.z; acc[2][3] += a.z*b4.w;
            acc[3][0] += a.w*b4.x; acc[3][1] += a.w*b4.y; acc[3][2] += a.w*b4.z; acc[3][3] += a.w*b4.w;
        }
        __syncthreads();
    }

    const int i0 = ib + ty*4;
    const int j0 = jb + tx*4;
    if (epi == 2) {
        #pragma unroll
        for (int ii = 0; ii < 4; ii++)
            #pragma unroll
            for (int jj = 0; jj < 4; jj++) {
                int j = j0 + jj;
                float vv = lrelu_(sv[j]*acc[ii][jj] + tv[j]);
                C[(long)b*cBatch + (long)j*cRow + (i0+ii)] = vv;
            }
    } else {
        #pragma unroll
        for (int ii = 0; ii < 4; ii++)
            #pragma unroll
            for (int jj = 0; jj < 4; jj++) {
                int j = j0 + jj;
                float vv = acc[ii][jj];
                if (act == 1) vv = fmaxf(sv[j]*vv + tv[j], 0.0f);
                else if (act == 2) vv = lrelu_(sv[j]*vv + tv[j]);
                C[(long)b*cBatch + (long)(i0+ii)*cRow + cCol0 + j] = vv;
            }
    }
}

// ---------------------------------------------------------------------------
// edge gather-max (geo + feat) + fuse GEMM + bn/lrelu -> out_feat_t (B,N,64)
// ---------------------------------------------------------------------------
__global__ void __launch_bounds__(256) k_edgefuse(
    const float* __restrict__ P, const int* __restrict__ idxg, const int* __restrict__ idxf,
    const float* __restrict__ wft, const float* __restrict__ sc,
    float* __restrict__ outf)
{
    __shared__ float wt[128*64];
    __shared__ float fused[4][128];
    const int t = threadIdx.x, lane = t & 63, w = t >> 6;
    for (int i = t; i < 128*64; i += 256) wt[i] = wft[i];
    const int pid = blockIdx.x*4 + w;
    const int b = pid >> 11, n = pid & (N_-1);
    const float* Prow = P + ((long)b*N_ + n)*256;
    const int* ig  = idxg + ((long)b*N_ + n)*KG;
    const int* ifx = idxf + ((long)b*N_ + n)*KG;
    float gmax = -FLT_MAX, hmax = -FLT_MAX;
    for (int k = 0; k < KG; k++) {
        int idg = ig[k];
        gmax = fmaxf(gmax, P[((long)b*N_ + idg)*256 + lane]);
        int idf = ifx[k];
        hmax = fmaxf(hmax, P[((long)b*N_ + idf)*256 + 128 + lane]);
    }
    float glin = gmax - Prow[lane]       + Prow[64 + lane];
    float hlin = hmax - Prow[128 + lane] + Prow[192 + lane];
    float gv = lrelu_(sc[SC_SGEO + lane]*glin + sc[SC_TGEO + lane]);
    float hv = lrelu_(sc[SC_SFEAT + lane]*hlin + sc[SC_TFEAT + lane]);
    fused[w][lane]      = gv;
    fused[w][64 + lane] = hv;
    __syncthreads();
    float acc = 0.0f;
    #pragma unroll 8
    for (int c4 = 0; c4 < 32; c4++) {
        float4 f = *(const float4*)&fused[w][c4*4];
        acc += f.x * wt[(c4*4+0)*64 + lane];
        acc += f.y * wt[(c4*4+1)*64 + lane];
        acc += f.z * wt[(c4*4+2)*64 + lane];
        acc += f.w * wt[(c4*4+3)*64 + lane];
    }
    float ov = lrelu_(sc[SC_SFUSE + lane]*acc + sc[SC_TFUSE + lane]);
    outf[((long)b*N_ + n)*64 + lane] = ov;
}

// ---------------------------------------------------------------------------
// local_op gather-max
// ---------------------------------------------------------------------------
template<int QN, int ROWW, int CO, int MROWS, int SO>
__global__ void __launch_bounds__(256) k_gathermax(
    const float* __restrict__ Q, const int* __restrict__ knn, const int* __restrict__ fpsi,
    const float* __restrict__ sv, const float* __restrict__ tv,
    float* __restrict__ outp, int outRow)
{
    const int t = threadIdx.x, lane = t & 63, w = t >> 6;
    const int pid = blockIdx.x*4 + w;
    const int b = pid / SO, s = pid % SO;
    const int* ix = knn + ((long)b*SO + s)*NSAMP;
    float mx[QN];
    #pragma unroll
    for (int q = 0; q < QN; q++) mx[q] = -FLT_MAX;
    for (int k = 0; k < NSAMP; k++) {
        int id = ix[k];
        const float* r = Q + ((long)b*MROWS + id)*ROWW;
        #pragma unroll
        for (int q = 0; q < QN; q++) mx[q] = fmaxf(mx[q], r[lane + 64*q]);
    }
    int crow = fpsi[b*SO + s];
    const float* cr = Q + ((long)b*MROWS + crow)*ROWW + CO;
    #pragma unroll
    for (int q = 0; q < QN; q++) {
        int o = lane + 64*q;
        float lin = mx[q] + cr[o];
        float val = fmaxf(sv[o]*lin + tv[o], 0.0f);
        outp[((long)b*SO + s)*outRow + o] = val;
    }
}

// ---------------------------------------------------------------------------
extern "C" void kernel_launch(void* const* d_in, const int* in_sizes, int n_in,
                              void* d_out, int out_size, void* d_ws, size_t ws_size,
                              hipStream_t stream)
{
    const float* x      = (const float*)d_in[0];
    const float* w1     = (const float*)d_in[1];
    const float* bn1    = (const float*)d_in[2];
    const float* w2     = (const float*)d_in[3];
    const float* bn2    = (const float*)d_in[4];
    const float* geow   = (const float*)d_in[5];
    const float* geobn  = (const float*)d_in[6];
    const float* featw  = (const float*)d_in[7];
    const float* featbn = (const float*)d_in[8];
    const float* fusew  = (const float*)d_in[9];
    const float* fusebn = (const float*)d_in[10];
    const float* gl0w   = (const float*)d_in[11];
    const float* gl0bn  = (const float*)d_in[12];
    const float* gl1w   = (const float*)d_in[13];
    const float* gl1bn  = (const float*)d_in[14];
    const float* wf     = (const float*)d_in[15];
    const float* bnfp   = (const float*)d_in[16];

    float* ws  = (float*)d_ws;
    float* out = (float*)d_out;

    float* FT   = ws + OFF_FT;
    float* SQ   = ws + OFF_SQ;
    float* BIG  = ws + OFF_BIG;
    int*   IDXG = (int*)(ws + OFF_IDXG);
    int*   IDXF = (int*)(ws + OFF_IDXF);
    float* OUTF = ws + OFF_OUTF;
    int*   FPS1 = (int*)(ws + OFF_FPS1);
    float* NX1  = ws + OFF_NX1;
    int*   IDX1 = (int*)(ws + OFF_IDX1);
    float* F0T  = ws + OFF_F0T;
    int*   FPS2 = (int*)(ws + OFF_FPS2);
    float* NX2  = ws + OFF_NX2;
    int*   IDX2 = (int*)(ws + OFF_IDX2);
    float* Q1B  = ws + OFF_Q1;
    float* V    = ws + OFF_V;
    float* WPP  = ws + OFF_WPP;
    float* WPQ0 = ws + OFF_WPQ0;
    float* WPQ1 = ws + OFF_WPQ1;
    float* WFT  = ws + OFF_WFT;
    float* SC   = ws + OFF_SC;
    const float* nfp = nullptr;

    hipLaunchKernelGGL(k_prep, dim3(64), dim3(256), 0, stream,
        bn1, bn2, geow, geobn, featw, featbn, fusew, fusebn, gl0w, gl0bn, gl1w, gl1bn, bnfp, ws);

    hipLaunchKernelGGL(k_feat0, dim3(B_*N_/4), dim3(256), 0, stream, x, w1, SC, FT, SQ);

    // fused: FPS1->FPS2 chain (16 leading blocks) + geo knn (8192 blocks)
    hipLaunchKernelGGL(k_geoknn_fps, dim3(B_ + B_*(N_/4)), dim3(256), 0, stream,
        x, IDXG, FPS1, NX1, FPS2, NX2);

    // feature knn: pipelined {select(ci-1) || gemm(ci)} with double buffer
    float* bufs[2] = { BIG, Q1B };
    for (int ci = 0; ci < N_/CHQ; ci++) {
        hipLaunchKernelGGL(k_dist_sel, dim3(1024 + 2048), dim3(256), 0, stream,
            FT, SQ,
            bufs[ci & 1], ci*CHQ,
            bufs[(ci + 1) & 1], (ci - 1)*CHQ,
            IDXF, ci > 0 ? 1 : 0);
    }
    // final select: chunk 7 lives in bufs[1]
    hipLaunchKernelGGL(k_selectD, dim3(B_*CHQ/4), dim3(256), 0, stream,
        bufs[(N_/CHQ - 1) & 1], (N_/CHQ - 1)*CHQ, IDXF);

    // P projection (B,N,256) into BIG
    hipLaunchKernelGGL(k_gemm, dim3(N_/64, 256/64, B_), dim3(256), 0, stream,
        FT, (long)N_*64, 64, WPP, (long)0, 64,
        BIG, (long)N_*256, 256, 0, 0, nfp, nfp, 0);

    hipLaunchKernelGGL(k_edgefuse, dim3(B_*N_/4), dim3(256), 0, stream,
        BIG, IDXG, IDXF, WFT, SC, OUTF);

    // grouping knn 1 (queries = NX1 from fused FPS), global-read refs
    hipLaunchKernelGGL((k_knn3d_g<2048,32,32>), dim3(B_*(NP1/4)), dim3(256), 0, stream,
        NX1, (long)NP1*3, 3, 1, NP1, x, (long)6*N_, (long)1, (long)N_, IDX1);

    // Q0 projection (B,N,256) into BIG (P is dead now)
    hipLaunchKernelGGL(k_gemm, dim3(N_/64, 256/64, B_), dim3(256), 0, stream,
        OUTF, (long)N_*64, 64, WPQ0, (long)0, 64,
        BIG, (long)N_*256, 256, 0, 0, nfp, nfp, 0);

    hipLaunchKernelGGL((k_gathermax<2,256,128,2048,512>), dim3(B_*NP1/4), dim3(256), 0, stream,
        BIG, IDX1, FPS1, SC + SC_SGL0, SC + SC_TGL0, F0T, 128);

    // grouping knn 2 (queries = NX2), global-read refs
    hipLaunchKernelGGL((k_knn3d_g<512,8,32>), dim3(B_*(NP2/4)), dim3(256), 0, stream,
        NX2, (long)NP2*3, 3, 1, NP2, NX1, (long)NP1*3, (long)3, (long)1, IDX2);

    // Q1 projection (B,512,512) — overwrites chunk buffer B (feature knn done)
    hipLaunchKernelGGL(k_gemm, dim3(NP1/64, 512/64, B_), dim3(256), 0, stream,
        F0T, (long)NP1*128, 128, WPQ1, (long)0, 128,
        Q1B, (long)NP1*512, 512, 0, 0, nfp, nfp, 0);

    hipLaunchKernelGGL((k_gathermax<4,512,256,512,256>), dim3(B_*NP2/4), dim3(256), 0, stream,
        Q1B, IDX2, FPS2, SC + SC_SGL1, SC + SC_TGL1, V, 1280);

    // x_skip -> V[:, :, 256:1280]  (A = f_t rows at stride 8 points)
    hipLaunchKernelGGL(k_gemm, dim3(NP2/64, 1024/64, B_), dim3(256), 0, stream,
        FT, (long)N_*64, 512, w2, (long)0, 64,
        V, (long)NP2*1280, 1280, 256, 1, SC + SC_S2, SC + SC_T2, 0);

    // final (B,512,256) = lrelu(bnf(wf . V^T)), transposed store
    hipLaunchKernelGGL(k_gemm, dim3(NP2/64, 512/64, B_), dim3(256), 0, stream,
        V, (long)NP2*1280, 1280, wf, (long)0, 1280,
        out, (long)512*256, 256, 0, 2, SC + SC_SF, SC + SC_TF, 2);

    (void)in_sizes; (void)n_in; (void)out_size; (void)ws_size;
}

// Round 15
// 710.725 us; speedup vs baseline: 10.0159x; 1.4652x over previous
//
#include <hip/hip_runtime.h>
#include <float.h>
#include <math.h>

// ---------------------------------------------------------------------------
// SSFE_Net pipeline on MI355X. B=16, N=2048.
// R13: pipelined {sel || gemm} feature chain. 1041us; FPS tail (200us on 16
//      CUs) still blocks the dispatch queue.
// R14: FPS made checkpointable (dl/far/centroid persisted in scratch) and
//      smeared across dispatches as segments: 256 iters under geo-knn+gemm0,
//      32 per chain dispatch, FPS2 2x128 under tail dispatches. Independent
//      GEMMs (gemm0, Pproj, xskip, Q0proj, knn1, knn2) folded into host
//      dispatches. FPS arithmetic byte-identical.
// ---------------------------------------------------------------------------

static constexpr int B_   = 16;
static constexpr int N_   = 2048;
static constexpr int NP1  = 512;
static constexpr int NP2  = 256;
static constexpr int KG   = 20;
static constexpr int NSAMP= 32;
static constexpr int CHQ  = 256;

// workspace offsets (in float elements)
static constexpr long OFF_FT   = 0;
static constexpr long OFF_SQ   = OFF_FT   + (long)B_*N_*64;
static constexpr long OFF_BIG  = OFF_SQ   + (long)B_*N_;          // D chunk A / P / Q0
static constexpr long OFF_IDXG = OFF_BIG  + (long)B_*N_*256;
static constexpr long OFF_IDXF = OFF_IDXG + (long)B_*N_*KG;
static constexpr long OFF_OUTF = OFF_IDXF + (long)B_*N_*KG;
static constexpr long OFF_FPS1 = OFF_OUTF + (long)B_*N_*64;
static constexpr long OFF_NX1  = OFF_FPS1 + (long)B_*NP1;
static constexpr long OFF_IDX1 = OFF_NX1  + (long)B_*NP1*3;
static constexpr long OFF_F0T  = OFF_IDX1 + (long)B_*NP1*NSAMP;
static constexpr long OFF_FPS2 = OFF_F0T  + (long)B_*NP1*128;
static constexpr long OFF_NX2  = OFF_FPS2 + (long)B_*NP2;
static constexpr long OFF_IDX2 = OFF_NX2  + (long)B_*NP2*3;
static constexpr long OFF_Q1   = OFF_IDX2 + (long)B_*NP2*NSAMP;  // D chunk B (Q1+V)
static constexpr long OFF_V    = OFF_Q1   + (long)B_*NP1*512;
static constexpr long OFF_WPP  = OFF_V    + (long)B_*NP2*1280;
static constexpr long OFF_WPQ0 = OFF_WPP  + 256*64;
static constexpr long OFF_WPQ1 = OFF_WPQ0 + 256*64;
static constexpr long OFF_WFT  = OFF_WPQ1 + 512*128;
static constexpr long OFF_SC   = OFF_WFT  + 128*64;
static constexpr long OFF_DL1  = OFF_SC   + 4352;               // FPS1 dl state
static constexpr long OFF_DL2  = OFF_DL1  + (long)B_*256*8;     // FPS2 dl state
static constexpr long OFF_ST   = OFF_DL2  + (long)B_*512;       // far/centroid state

// SC (bn scale/shift) sub-offsets
static constexpr int SC_S1=0, SC_T1=64, SC_SGEO=128, SC_TGEO=192, SC_SFEAT=256, SC_TFEAT=320,
   SC_SFUSE=384, SC_TFUSE=448, SC_SGL0=512, SC_TGL0=640, SC_SGL1=768, SC_TGL1=1024,
   SC_S2=1280, SC_T2=2304, SC_SF=3328, SC_TF=3840;

__device__ __forceinline__ float lrelu_(float x) { return x >= 0.0f ? x : 0.2f * x; }

// masked DPP max step
template<int CTRL, int RM>
__device__ __forceinline__ float dpp_maxm(float v) {
    int o = __builtin_amdgcn_update_dpp(__float_as_int(v), __float_as_int(v),
                                        CTRL, RM, 0xF, false);
    return fmaxf(v, __int_as_float(o));
}
__device__ __forceinline__ float wave_max64_sgpr(float v) {
    v = dpp_maxm<0xB1, 0xF>(v);
    v = dpp_maxm<0x4E, 0xF>(v);
    v = dpp_maxm<0x141,0xF>(v);
    v = dpp_maxm<0x140,0xF>(v);
    v = dpp_maxm<0x142,0xA>(v);
    v = dpp_maxm<0x143,0xC>(v);
    return __int_as_float(__builtin_amdgcn_readlane(__float_as_int(v), 63));
}

template<int CTRL>
__device__ __forceinline__ unsigned dpp_minu(unsigned x) {
    unsigned o = (unsigned)__builtin_amdgcn_update_dpp(0, (int)x, CTRL, 0xF, 0xF, true);
    return o < x ? o : x;
}
__device__ __forceinline__ unsigned wave_minu(unsigned x) {
    x = dpp_minu<0xB1>(x);
    x = dpp_minu<0x4E>(x);
    x = dpp_minu<0x141>(x);
    x = dpp_minu<0x140>(x);
    { unsigned o = (unsigned)__shfl_xor((int)x, 16); x = o < x ? o : x; }
    { unsigned o = (unsigned)__shfl_xor((int)x, 32); x = o < x ? o : x; }
    return x;
}

__device__ __forceinline__ unsigned sortable_(float f) {
    unsigned u = __float_as_uint(f);
    return u ^ ((unsigned)((int)u >> 31) | 0x80000000u);
}

// ---------------------------------------------------------------------------
// prep + feat0 (unchanged)
// ---------------------------------------------------------------------------
__global__ void k_prep(const float* __restrict__ bn1, const float* __restrict__ bn2,
                       const float* __restrict__ geow, const float* __restrict__ geobn,
                       const float* __restrict__ featw, const float* __restrict__ featbn,
                       const float* __restrict__ fusew, const float* __restrict__ fusebn,
                       const float* __restrict__ gl0w, const float* __restrict__ gl0bn,
                       const float* __restrict__ gl1w, const float* __restrict__ gl1bn,
                       const float* __restrict__ bnfp, float* __restrict__ ws)
{
    const int tid = blockIdx.x * blockDim.x + threadIdx.x;
    const int nt  = gridDim.x * blockDim.x;
    float* sc = ws + OFF_SC;
    {
        const float* ps[8]  = {bn1, geobn, featbn, fusebn, gl0bn, gl1bn, bn2, bnfp};
        const int    ch[8]  = {64, 64, 64, 64, 128, 256, 1024, 512};
        const int    so[8]  = {SC_S1, SC_SGEO, SC_SFEAT, SC_SFUSE, SC_SGL0, SC_SGL1, SC_S2, SC_SF};
        const int    to[8]  = {SC_T1, SC_TGEO, SC_TFEAT, SC_TFUSE, SC_TGL0, SC_TGL1, SC_T2, SC_TF};
        for (int g = 0; g < 8; g++) {
            const float* p = ps[g]; int C = ch[g];
            for (int i = tid; i < C; i += nt) {
                float gg = p[i], bb = p[C+i], mm = p[2*C+i], vv = p[3*C+i];
                float s = gg * (1.0f / sqrtf(vv + 1e-5f));
                sc[so[g] + i] = s;
                sc[to[g] + i] = bb - mm * s;
            }
        }
    }
    for (int j = tid; j < 256*64; j += nt) {
        int o = j >> 6, c = j & 63; float v;
        if      (o < 64)  v = geow[o*128 + c];
        else if (o < 128) v = geow[(o-64)*128 + 64 + c];
        else if (o < 192) v = featw[(o-128)*128 + c];
        else              v = featw[(o-192)*128 + 64 + c];
        ws[OFF_WPP + j] = v;
    }
    for (int j = tid; j < 256*64; j += nt) {
        int o = j >> 6, c = j & 63; float v;
        if (o < 128) v = gl0w[o*128 + c];
        else         v = gl0w[(o-128)*128 + 64 + c] - gl0w[(o-128)*128 + c];
        ws[OFF_WPQ0 + j] = v;
    }
    for (int j = tid; j < 512*128; j += nt) {
        int o = j >> 7, c = j & 127; float v;
        if (o < 256) v = gl1w[o*256 + c];
        else         v = gl1w[(o-256)*256 + 128 + c] - gl1w[(o-256)*256 + c];
        ws[OFF_WPQ1 + j] = v;
    }
    for (int j = tid; j < 128*64; j += nt) {
        int c = j >> 6, o = j & 63;
        ws[OFF_WFT + j] = fusew[o*128 + c];
    }
}

__global__ void __launch_bounds__(256) k_feat0(const float* __restrict__ x,
                                               const float* __restrict__ w1,
                                               const float* __restrict__ sc,
                                               float* __restrict__ ft, float* __restrict__ sq)
{
    const int t = threadIdx.x, lane = t & 63, w = t >> 6;
    const int pid = blockIdx.x*4 + w;
    const int b = pid >> 11, n = pid & (N_-1);
    const float* xb = x + (long)b*6*N_ + n;
    float acc = 0.0f;
    #pragma unroll
    for (int c = 0; c < 6; c++) acc += w1[lane*6 + c] * xb[(long)c*N_];
    float val = fmaxf(sc[SC_S1 + lane]*acc + sc[SC_T1 + lane], 0.0f);
    ft[((long)b*N_ + n)*64 + lane] = val;
    float v2 = val*val;
    #pragma unroll
    for (int s = 1; s < 64; s <<= 1) v2 += __shfl_xor(v2, s);
    if (lane == 0) sq[b*N_ + n] = v2;
}

// ---------------------------------------------------------------------------
// topk_sel3 (unchanged semantics)
// ---------------------------------------------------------------------------
template<int RPL, int KSEL>
__device__ __forceinline__ void topk_sel3(float (&v)[RPL], int lane, int* __restrict__ out)
{
    unsigned key[RPL];
    #pragma unroll
    for (int j = 0; j < RPL; j++) key[j] = sortable_(v[j]);

    unsigned consumed = 0;
    unsigned m1 = key[0]; int s1 = 0;
    unsigned m2 = 0xFFFFFFFFu; int s2 = 0;
    #pragma unroll
    for (int j = 1; j < RPL; j++) {
        unsigned kk = key[j];
        bool lt1 = kk < m1;
        bool lt2 = kk < m2;
        unsigned nm2 = lt1 ? m1 : (lt2 ? kk : m2);
        int      ns2 = lt1 ? s1 : (lt2 ? j  : s2);
        m1 = lt1 ? kk : m1;
        s1 = lt1 ? j  : s1;
        m2 = nm2; s2 = ns2;
    }
    #pragma unroll 1
    for (int k = 0; k < KSEL; k++) {
        unsigned g = wave_minu(m1);
        unsigned long long cand = __ballot(m1 == g);
        int gi;
        if (__popcll(cand) > 1) {
            int ci = (m1 == g) ? (s1*64 + lane) : 0x7FFFFFFF;
            #pragma unroll
            for (int s = 1; s < 64; s <<= 1) { int o = __shfl_xor(ci, s); ci = o < ci ? o : ci; }
            gi = ci;
        } else {
            int wl = __ffsll((long long)cand) - 1;
            gi = __builtin_amdgcn_readlane(s1, wl) * 64 + wl;
        }
        if (lane == 0) out[k] = gi;
        if (k + 1 < KSEL) {
            bool win = (m1 == g) && (s1*64 + lane == gi);
            if (win) {
                consumed |= 1u << s1;
                m1 = m2; s1 = s2;
                m2 = 0xFFFFFFFFu;
            }
            bool need = win && (m1 == 0xFFFFFFFFu);
            if (__any(need)) {
                if (need) {
                    m1 = 0xFFFFFFFFu; s1 = 0; m2 = 0xFFFFFFFFu; s2 = 0;
                    #pragma unroll
                    for (int j = 0; j < RPL; j++) {
                        unsigned kk = ((consumed >> j) & 1u) ? 0xFFFFFFFFu : key[j];
                        bool lt1 = kk < m1;
                        bool lt2 = kk < m2;
                        unsigned nm2 = lt1 ? m1 : (lt2 ? kk : m2);
                        int      ns2 = lt1 ? s1 : (lt2 ? j  : s2);
                        m1 = lt1 ? kk : m1;
                        s1 = lt1 ? j  : s1;
                        m2 = nm2; s2 = ns2;
                    }
                }
            }
        }
    }
}

// ---------------------------------------------------------------------------
// geo/group knn body (bid param)
// ---------------------------------------------------------------------------
template<int NREF, int RPL, int KSEL>
__device__ __forceinline__ void knn_gbody(
    const float* qp, long qBatch, int qsN, int qsD, int NQ,
    const float* rp, long rBatch, long rsN, long rsD,
    int* out, int bid)
{
    const int t = threadIdx.x, lane = t & 63, w = t >> 6;
    const int bpb = NQ / 4;
    const int b = bid / bpb;
    const int qi = (bid % bpb)*4 + w;
    const float* rb = rp + (long)b*rBatch;
    const float* qb = qp + (long)b*qBatch + (long)qi*qsN;
    float qx = qb[0], qy = qb[qsD], qz = qb[2*qsD];
    float sumq = __fadd_rn(__fadd_rn(__fmul_rn(qx,qx), __fmul_rn(qy,qy)), __fmul_rn(qz,qz));
    float v[RPL];
    #pragma unroll
    for (int j = 0; j < RPL; j++) {
        long n = j*64 + lane;
        float rx = rb[n*rsN];
        float ry = rb[n*rsN + rsD];
        float rz = rb[n*rsN + 2*rsD];
        float dot  = __fadd_rn(__fadd_rn(__fmul_rn(qx,rx), __fmul_rn(qy,ry)), __fmul_rn(qz,rz));
        float sumr = __fadd_rn(__fadd_rn(__fmul_rn(rx,rx), __fmul_rn(ry,ry)), __fmul_rn(rz,rz));
        v[j] = __fadd_rn(__fsub_rn(sumq, __fmul_rn(2.0f, dot)), sumr);
    }
    topk_sel3<RPL, KSEL>(v, lane, out + ((long)b*NQ + qi)*KSEL);
}

// ---------------------------------------------------------------------------
// FPS1 segment: iterations [i0, i0+cnt). State in dl1s/st. smem >= 1100 floats.
// ---------------------------------------------------------------------------
__device__ __forceinline__ void fps1_seg_body(
    const float* __restrict__ x, int b, int i0, int cnt,
    int* __restrict__ fps1, float* __restrict__ nx1,
    float* __restrict__ dl1s, float* __restrict__ st, float* __restrict__ smem)
{
    __builtin_amdgcn_s_setprio(3);
    const int t = threadIdx.x, lane = t & 63, wave = t >> 6;
    const float* pb = x + (long)b*6*N_;

    float4* mrgc   = (float4*)smem;            // 8 float4
    int*    mrgi   = (int*)(smem + 32);        // 8
    int*    sidxsg = (int*)(smem + 40);        // up to 256
    float*  mxsg   = smem + 296;               // up to 256
    float*  mysg   = smem + 552;
    float*  mzsg   = smem + 808;               // ends 1064

    float px[8], py[8], pz[8], dl[8];
    {
        const float4* a4  = (const float4*)(pb + 8*t);
        const float4* b4  = (const float4*)(pb + N_ + 8*t);
        const float4* c4p = (const float4*)(pb + 2*N_ + 8*t);
        float4 a0 = a4[0], a1 = a4[1];
        float4 b0 = b4[0], b1 = b4[1];
        float4 c0 = c4p[0], c1 = c4p[1];
        px[0]=a0.x; px[1]=a0.y; px[2]=a0.z; px[3]=a0.w;
        px[4]=a1.x; px[5]=a1.y; px[6]=a1.z; px[7]=a1.w;
        py[0]=b0.x; py[1]=b0.y; py[2]=b0.z; py[3]=b0.w;
        py[4]=b1.x; py[5]=b1.y; py[6]=b1.z; py[7]=b1.w;
        pz[0]=c0.x; pz[1]=c0.y; pz[2]=c0.z; pz[3]=c0.w;
        pz[4]=c1.x; pz[5]=c1.y; pz[6]=c1.z; pz[7]=c1.w;
    }
    int far; float cx, cy, cz;
    if (i0 == 0) {
        #pragma unroll
        for (int p = 0; p < 8; p++) dl[p] = 1e10f;
        far = 0; cx = pb[0]; cy = pb[N_]; cz = pb[2*N_];
    } else {
        const float4* ds = (const float4*)(dl1s + ((long)b*256 + t)*8);
        float4 d0 = ds[0], d1 = ds[1];
        dl[0]=d0.x; dl[1]=d0.y; dl[2]=d0.z; dl[3]=d0.w;
        dl[4]=d1.x; dl[5]=d1.y; dl[6]=d1.z; dl[7]=d1.w;
        far = __float_as_int(st[b*16+0]);
        cx = st[b*16+1]; cy = st[b*16+2]; cz = st[b*16+3];
    }

    for (int k = 0; k < cnt; k++) {
        if (t == 0) { sidxsg[k] = far; mxsg[k] = cx; mysg[k] = cy; mzsg[k] = cz; }
        float bv = -1.0f; int bp = 0;
        #pragma unroll
        for (int p = 0; p < 8; p++) {
            float dx = __fsub_rn(px[p], cx);
            float dy = __fsub_rn(py[p], cy);
            float dz = __fsub_rn(pz[p], cz);
            float d  = __fadd_rn(__fadd_rn(__fmul_rn(dx,dx), __fmul_rn(dy,dy)), __fmul_rn(dz,dz));
            float nd = fminf(dl[p], d);
            dl[p] = nd;
            if (nd > bv) { bv = nd; bp = p; }
        }
        float wx = px[0], wy = py[0], wz = pz[0];
        #pragma unroll
        for (int p = 1; p < 8; p++) {
            bool c = (bp == p);
            wx = c ? px[p] : wx; wy = c ? py[p] : wy; wz = c ? pz[p] : wz;
        }
        float gm = wave_max64_sgpr(bv);
        unsigned long long cand = __ballot(bv == gm);
        int wl = __ffsll((long long)cand) - 1;
        int   wbp = __builtin_amdgcn_readlane(bp, wl);
        float sxw = __int_as_float(__builtin_amdgcn_readlane(__float_as_int(wx), wl));
        float syw = __int_as_float(__builtin_amdgcn_readlane(__float_as_int(wy), wl));
        float szw = __int_as_float(__builtin_amdgcn_readlane(__float_as_int(wz), wl));
        int par = k & 1;
        if (lane == 0) {
            mrgc[par*4 + wave] = make_float4(sxw, syw, szw, gm);
            mrgi[par*4 + wave] = (((wave << 6) | wl) << 3) + wbp;
        }
        __syncthreads();
        float4 e0 = mrgc[par*4 + 0];
        float fv = e0.w; int fi = mrgi[par*4 + 0];
        float ncx = e0.x, ncy = e0.y, ncz = e0.z;
        #pragma unroll
        for (int w2 = 1; w2 < 4; w2++) {
            float4 e2 = mrgc[par*4 + w2]; int i2 = mrgi[par*4 + w2];
            if (e2.w > fv) { fv = e2.w; fi = i2; ncx = e2.x; ncy = e2.y; ncz = e2.z; }
        }
        far = fi; cx = ncx; cy = ncy; cz = ncz;
    }
    __syncthreads();

    int*   f1o = fps1 + b*NP1;
    float* n1o = nx1 + (long)b*NP1*3;
    for (int s = t; s < cnt; s += 256) {
        f1o[i0+s] = sidxsg[s];
        n1o[(long)(i0+s)*3+0] = mxsg[s];
        n1o[(long)(i0+s)*3+1] = mysg[s];
        n1o[(long)(i0+s)*3+2] = mzsg[s];
    }
    float4* ds = (float4*)(dl1s + ((long)b*256 + t)*8);
    ds[0] = make_float4(dl[0], dl[1], dl[2], dl[3]);
    ds[1] = make_float4(dl[4], dl[5], dl[6], dl[7]);
    if (t == 0) {
        st[b*16+0] = __int_as_float(far);
        st[b*16+1] = cx; st[b*16+2] = cy; st[b*16+3] = cz;
    }
    __builtin_amdgcn_s_setprio(0);
}

// ---------------------------------------------------------------------------
// FPS2 segment: iterations [i0, i0+cnt), cnt<=128. mir from NX1 (global).
// smem >= 1750 floats.
// ---------------------------------------------------------------------------
__device__ __forceinline__ void fps2_seg_body(
    int b, int i0, int cnt,
    const float* __restrict__ nx1, int* __restrict__ fps2, float* __restrict__ nx2,
    float* __restrict__ dl2s, float* __restrict__ st, float* __restrict__ smem)
{
    __builtin_amdgcn_s_setprio(3);
    const int t = threadIdx.x, lane = t & 63, wave = t >> 6;
    float4* mrgc   = (float4*)smem;
    int*    mrgi   = (int*)(smem + 32);
    int*    sidxsg = (int*)(smem + 40);        // 128
    float*  mx2    = smem + 168;               // 512
    float*  my2    = smem + 680;
    float*  mz2    = smem + 1192;              // ends 1704

    const float* n1 = nx1 + (long)b*NP1*3;
    for (int s = t; s < NP1; s += 256) {
        mx2[s] = n1[(long)s*3+0];
        my2[s] = n1[(long)s*3+1];
        mz2[s] = n1[(long)s*3+2];
    }
    __syncthreads();

    const int n0 = t << 1;
    float ax = mx2[n0],   ay = my2[n0],   az = mz2[n0];
    float bx = mx2[n0+1], by = my2[n0+1], bz = mz2[n0+1];
    float dl0, dl1; int far2; float c2x, c2y, c2z;
    if (i0 == 0) {
        dl0 = dl1 = 1e10f; far2 = 0;
        c2x = mx2[0]; c2y = my2[0]; c2z = mz2[0];
    } else {
        dl0 = dl2s[(long)b*512 + n0];
        dl1 = dl2s[(long)b*512 + n0 + 1];
        far2 = __float_as_int(st[b*16+4]);
        c2x = st[b*16+5]; c2y = st[b*16+6]; c2z = st[b*16+7];
    }

    for (int k = 0; k < cnt; k++) {
        if (t == 0) sidxsg[k] = far2;
        float dx = __fsub_rn(ax, c2x), dy = __fsub_rn(ay, c2y), dz = __fsub_rn(az, c2z);
        float d0 = __fadd_rn(__fadd_rn(__fmul_rn(dx,dx), __fmul_rn(dy,dy)), __fmul_rn(dz,dz));
        dx = __fsub_rn(bx, c2x); dy = __fsub_rn(by, c2y); dz = __fsub_rn(bz, c2z);
        float d1 = __fadd_rn(__fadd_rn(__fmul_rn(dx,dx), __fmul_rn(dy,dy)), __fmul_rn(dz,dz));
        dl0 = fminf(dl0, d0);
        dl1 = fminf(dl1, d1);
        float bv = dl0; int bp = 0;
        if (dl1 > bv) { bv = dl1; bp = 1; }
        float wx = bp ? bx : ax, wy = bp ? by : ay, wz = bp ? bz : az;
        float gm = wave_max64_sgpr(bv);
        unsigned long long cand = __ballot(bv == gm);
        int wl = __ffsll((long long)cand) - 1;
        int   wbp = __builtin_amdgcn_readlane(bp, wl);
        float sxw = __int_as_float(__builtin_amdgcn_readlane(__float_as_int(wx), wl));
        float syw = __int_as_float(__builtin_amdgcn_readlane(__float_as_int(wy), wl));
        float szw = __int_as_float(__builtin_amdgcn_readlane(__float_as_int(wz), wl));
        int par = k & 1;
        if (lane == 0) {
            mrgc[par*4 + wave] = make_float4(sxw, syw, szw, gm);
            mrgi[par*4 + wave] = (((wave << 6) | wl) << 1) + wbp;
        }
        __syncthreads();
        float4 e0 = mrgc[par*4 + 0];
        float fv = e0.w; int fi = mrgi[par*4 + 0];
        float ncx = e0.x, ncy = e0.y, ncz = e0.z;
        #pragma unroll
        for (int w2 = 1; w2 < 4; w2++) {
            float4 e2 = mrgc[par*4 + w2]; int i2 = mrgi[par*4 + w2];
            if (e2.w > fv) { fv = e2.w; fi = i2; ncx = e2.x; ncy = e2.y; ncz = e2.z; }
        }
        far2 = fi; c2x = ncx; c2y = ncy; c2z = ncz;
    }
    __syncthreads();

    int*   f2o = fps2 + b*NP2;
    float* n2o = nx2 + (long)b*NP2*3;
    for (int s = t; s < cnt; s += 256) {
        int j = sidxsg[s];
        f2o[i0+s] = j;
        n2o[(long)(i0+s)*3+0] = mx2[j];
        n2o[(long)(i0+s)*3+1] = my2[j];
        n2o[(long)(i0+s)*3+2] = mz2[j];
    }
    dl2s[(long)b*512 + n0]     = dl0;
    dl2s[(long)b*512 + n0 + 1] = dl1;
    if (t == 0) {
        st[b*16+4] = __int_as_float(far2);
        st[b*16+5] = c2x; st[b*16+6] = c2y; st[b*16+7] = c2z;
    }
    __builtin_amdgcn_s_setprio(0);
}

// ---------------------------------------------------------------------------
// distance chunk GEMM body (K=64), gi in [0,2048)
// ---------------------------------------------------------------------------
__device__ __forceinline__ void dist_gemm_body(
    const float* __restrict__ ft, const float* __restrict__ sq,
    float* __restrict__ Dnew, int qbNew, int gi, float* __restrict__ smem)
{
    float* As = smem;
    float* Bs = smem + 64*68;
    const int ib = gi & 3;
    const int jb = (gi >> 2) & 31;
    const int b  = gi >> 7;
    const int t  = threadIdx.x;
    const int tx = t & 15, ty = t >> 4;
    const float* Ab = ft + ((long)b*N_ + qbNew + (long)ib*64)*64;
    const float* Bb = ft + ((long)b*N_ + (long)jb*64)*64;
    const float* sqb = sq + (long)b*N_;
    #pragma unroll
    for (int m = 0; m < 4; m++) {
        int li = t + m*256; int r = li >> 4; int c4 = li & 15;
        float4 av = *(const float4*)(Ab + (long)r*64 + c4*4);
        As[(c4*4+0)*68+r]=av.x; As[(c4*4+1)*68+r]=av.y; As[(c4*4+2)*68+r]=av.z; As[(c4*4+3)*68+r]=av.w;
        float4 bv = *(const float4*)(Bb + (long)r*64 + c4*4);
        Bs[(c4*4+0)*68+r]=bv.x; Bs[(c4*4+1)*68+r]=bv.y; Bs[(c4*4+2)*68+r]=bv.z; Bs[(c4*4+3)*68+r]=bv.w;
    }
    __syncthreads();
    float acc[4][4];
    #pragma unroll
    for (int i = 0; i < 4; i++)
        #pragma unroll
        for (int j = 0; j < 4; j++) acc[i][j] = 0.0f;
    #pragma unroll 4
    for (int k = 0; k < 64; k++) {
        float4 a  = *(const float4*)&As[k*68 + ty*4];
        float4 b4 = *(const float4*)&Bs[k*68 + tx*4];
        acc[0][0] += a.x*b4.x; acc[0][1] += a.x*b4.y; acc[0][2] += a.x*b4.z; acc[0][3] += a.x*b4.w;
        acc[1][0] += a.y*b4.x; acc[1][1] += a.y*b4.y; acc[1][2] += a.y*b4.z; acc[1][3] += a.y*b4.w;
        acc[2][0] += a.z*b4.x; acc[2][1] += a.z*b4.y; acc[2][2] += a.z*b4.z; acc[2][3] += a.z*b4.w;
        acc[3][0] += a.w*b4.x; acc[3][1] += a.w*b4.y; acc[3][2] += a.w*b4.z; acc[3][3] += a.w*b4.w;
    }
    const int i0 = ib*64 + ty*4;
    const int j0 = jb*64 + tx*4;
    #pragma unroll
    for (int ii = 0; ii < 4; ii++) {
        float sqq = sqb[qbNew + i0 + ii];
        #pragma unroll
        for (int jj = 0; jj < 4; jj++) {
            int r = j0 + jj;
            Dnew[((long)b*CHQ + i0 + ii)*N_ + r] = (sqq - 2.0f*acc[ii][jj]) + sqb[r];
        }
    }
}

// ---------------------------------------------------------------------------
// generic K=64 projection GEMM body: C[b] = A[b] * Bw^T
// ---------------------------------------------------------------------------
__device__ __forceinline__ void proj64_body(
    int gi, int nIB, int nJB,
    const float* __restrict__ A, long aBatch, int aRow,
    const float* __restrict__ Bw,
    float* __restrict__ C, long cBatch, int cRow, int cCol0,
    int act, const float* __restrict__ sv, const float* __restrict__ tv,
    float* __restrict__ smem)
{
    float* As = smem;
    float* Bs = smem + 64*68;
    const int ib = gi % nIB;
    const int jb = (gi / nIB) % nJB;
    const int b  = gi / (nIB*nJB);
    const int t  = threadIdx.x;
    const int tx = t & 15, ty = t >> 4;
    const float* Ab = A + (long)b*aBatch + (long)(ib*64)*aRow;
    #pragma unroll
    for (int m = 0; m < 4; m++) {
        int li = t + m*256; int r = li >> 4; int c4 = li & 15;
        float4 av = *(const float4*)(Ab + (long)r*aRow + c4*4);
        As[(c4*4+0)*68+r]=av.x; As[(c4*4+1)*68+r]=av.y; As[(c4*4+2)*68+r]=av.z; As[(c4*4+3)*68+r]=av.w;
        float4 bv = *(const float4*)(Bw + (long)(jb*64 + r)*64 + c4*4);
        Bs[(c4*4+0)*68+r]=bv.x; Bs[(c4*4+1)*68+r]=bv.y; Bs[(c4*4+2)*68+r]=bv.z; Bs[(c4*4+3)*68+r]=bv.w;
    }
    __syncthreads();
    float acc[4][4];
    #pragma unroll
    for (int i = 0; i < 4; i++)
        #pragma unroll
        for (int j = 0; j < 4; j++) acc[i][j] = 0.0f;
    #pragma unroll 4
    for (int k = 0; k < 64; k++) {
        float4 a  = *(const float4*)&As[k*68 + ty*4];
        float4 b4 = *(const float4*)&Bs[k*68 + tx*4];
        acc[0][0] += a.x*b4.x; acc[0][1] += a.x*b4.y; acc[0][2] += a.x*b4.z; acc[0][3] += a.x*b4.w;
        acc[1][0] += a.y*b4.x; acc[1][1] += a.y*b4.y; acc[1][2] += a.y*b4.z; acc[1][3] += a.y*b4.w;
        acc[2][0] += a.z*b4.x; acc[2][1] += a.z*b4.y; acc[2][2] += a.z*b4.z; acc[2][3] += a.z*b4.w;
        acc[3][0] += a.w*b4.x; acc[3][1] += a.w*b4.y; acc[3][2] += a.w*b4.z; acc[3][3] += a.w*b4.w;
    }
    const int i0 = ib*64 + ty*4;
    const int j0 = jb*64 + tx*4;
    #pragma unroll
    for (int ii = 0; ii < 4; ii++)
        #pragma unroll
        for (int jj = 0; jj < 4; jj++) {
            int j = j0 + jj;
            float vv = acc[ii][jj];
            if (act == 1) vv = fmaxf(sv[j]*vv + tv[j], 0.0f);
            C[(long)b*cBatch + (long)(i0+ii)*cRow + cCol0 + j] = vv;
        }
}

// ---------------------------------------------------------------------------
// select body (top-20 from a chunk row), bid in [0,1024)
// ---------------------------------------------------------------------------
__device__ __forceinline__ void sel_body(
    const float* __restrict__ Dold, int qbOld, int* __restrict__ idxf, int bid)
{
    const int t = threadIdx.x, lane = t & 63, w = t >> 6;
    const int r = bid*4 + w;
    const int b = r >> 8, qi = r & (CHQ-1);
    const float* row = Dold + ((long)b*CHQ + qi) * N_;
    float v[32];
    #pragma unroll
    for (int j = 0; j < 32; j++) v[j] = row[j*64 + lane];
    topk_sel3<32, KG>(v, lane, idxf + ((long)b*N_ + qbOld + qi)*KG);
}

// ---------------------------------------------------------------------------
// edgefuse body, bid in [0,8192); smem: wt 8192 + fused 512
// ---------------------------------------------------------------------------
__device__ __forceinline__ void edgefuse_body(
    const float* __restrict__ P, const int* __restrict__ idxg, const int* __restrict__ idxf,
    const float* __restrict__ wft, const float* __restrict__ sc,
    float* __restrict__ outf, int bid, float* __restrict__ smem)
{
    float* wt = smem;
    float* fused = smem + 8192;
    const int t = threadIdx.x, lane = t & 63, w = t >> 6;
    for (int i = t; i < 128*64; i += 256) wt[i] = wft[i];
    const int pid = bid*4 + w;
    const int b = pid >> 11, n = pid & (N_-1);
    const float* Prow = P + ((long)b*N_ + n)*256;
    const int* ig  = idxg + ((long)b*N_ + n)*KG;
    const int* ifx = idxf + ((long)b*N_ + n)*KG;
    float gmax = -FLT_MAX, hmax = -FLT_MAX;
    for (int k = 0; k < KG; k++) {
        int idg = ig[k];
        gmax = fmaxf(gmax, P[((long)b*N_ + idg)*256 + lane]);
        int idf = ifx[k];
        hmax = fmaxf(hmax, P[((long)b*N_ + idf)*256 + 128 + lane]);
    }
    float glin = gmax - Prow[lane]       + Prow[64 + lane];
    float hlin = hmax - Prow[128 + lane] + Prow[192 + lane];
    float gv = lrelu_(sc[SC_SGEO + lane]*glin + sc[SC_TGEO + lane]);
    float hv = lrelu_(sc[SC_SFEAT + lane]*hlin + sc[SC_TFEAT + lane]);
    fused[w*128 + lane]      = gv;
    fused[w*128 + 64 + lane] = hv;
    __syncthreads();
    float acc = 0.0f;
    #pragma unroll 8
    for (int c4 = 0; c4 < 32; c4++) {
        float4 f = *(const float4*)&fused[w*128 + c4*4];
        acc += f.x * wt[(c4*4+0)*64 + lane];
        acc += f.y * wt[(c4*4+1)*64 + lane];
        acc += f.z * wt[(c4*4+2)*64 + lane];
        acc += f.w * wt[(c4*4+3)*64 + lane];
    }
    float ov = lrelu_(sc[SC_SFUSE + lane]*acc + sc[SC_TFUSE + lane]);
    outf[((long)b*N_ + n)*64 + lane] = ov;
}

// ---------------------------------------------------------------------------
// gathermax body
// ---------------------------------------------------------------------------
template<int QN, int ROWW, int CO, int MROWS, int SO>
__device__ __forceinline__ void gathermax_body(
    const float* __restrict__ Q, const int* __restrict__ knn, const int* __restrict__ fpsi,
    const float* __restrict__ sv, const float* __restrict__ tv,
    float* __restrict__ outp, int outRow, int bid)
{
    const int t = threadIdx.x, lane = t & 63, w = t >> 6;
    const int pid = bid*4 + w;
    const int b = pid / SO, s = pid % SO;
    const int* ix = knn + ((long)b*SO + s)*NSAMP;
    float mx[QN];
    #pragma unroll
    for (int q = 0; q < QN; q++) mx[q] = -FLT_MAX;
    for (int k = 0; k < NSAMP; k++) {
        int id = ix[k];
        const float* r = Q + ((long)b*MROWS + id)*ROWW;
        #pragma unroll
        for (int q = 0; q < QN; q++) mx[q] = fmaxf(mx[q], r[lane + 64*q]);
    }
    int crow = fpsi[b*SO + s];
    const float* cr = Q + ((long)b*MROWS + crow)*ROWW + CO;
    #pragma unroll
    for (int q = 0; q < QN; q++) {
        int o = lane + 64*q;
        float lin = mx[q] + cr[o];
        float val = fmaxf(sv[o]*lin + tv[o], 0.0f);
        outp[((long)b*SO + s)*outRow + o] = val;
    }
}

// ---------------------------------------------------------------------------
// d1: FPS1(0,256) + geo-knn + dist gemm chunk0
// ---------------------------------------------------------------------------
__global__ void __launch_bounds__(256, 4) k_geo0(
    const float* __restrict__ x, int* __restrict__ idxg,
    int* __restrict__ fps1, float* __restrict__ nx1,
    float* __restrict__ dl1s, float* __restrict__ st,
    const float* __restrict__ ft, const float* __restrict__ sq,
    float* __restrict__ D0)
{
    __shared__ float smem[8704];
    if (blockIdx.x < (unsigned)B_) {
        fps1_seg_body(x, blockIdx.x, 0, 256, fps1, nx1, dl1s, st, smem);
        return;
    }
    if (blockIdx.x < (unsigned)(B_ + 8192)) {
        knn_gbody<N_,32,KG>(x, (long)6*N_, 1, N_, N_,
                            x, (long)6*N_, 1, N_, idxg, blockIdx.x - B_);
        return;
    }
    dist_gemm_body(ft, sq, D0, 0, blockIdx.x - (B_ + 8192), smem);
}

// ---------------------------------------------------------------------------
// chain: FPS1 segment + sel(ci-1) + gemm(ci)
// ---------------------------------------------------------------------------
__global__ void __launch_bounds__(256, 4) k_chain(
    const float* __restrict__ x, const float* __restrict__ ft, const float* __restrict__ sq,
    float* __restrict__ Dnew, int qbNew,
    const float* __restrict__ Dold, int qbOld,
    int* __restrict__ idxf,
    int* __restrict__ fps1, float* __restrict__ nx1,
    float* __restrict__ dl1s, float* __restrict__ st, int i0)
{
    __shared__ float smem[8704];
    if (blockIdx.x < 16u) {
        fps1_seg_body(x, blockIdx.x, i0, 32, fps1, nx1, dl1s, st, smem);
        return;
    }
    if (blockIdx.x < 1040u) {
        sel_body(Dold, qbOld, idxf, blockIdx.x - 16);
        return;
    }
    dist_gemm_body(ft, sq, Dnew, qbNew, blockIdx.x - 1040, smem);
}

// ---------------------------------------------------------------------------
// d9: FPS1(480,32) + sel7 + P projection
// ---------------------------------------------------------------------------
__global__ void __launch_bounds__(256, 4) k_tail9(
    const float* __restrict__ x, const float* __restrict__ ft,
    const float* __restrict__ Dold, int qbOld, int* __restrict__ idxf,
    int* __restrict__ fps1, float* __restrict__ nx1,
    float* __restrict__ dl1s, float* __restrict__ st,
    const float* __restrict__ wpp, float* __restrict__ big)
{
    __shared__ float smem[8704];
    if (blockIdx.x < 16u) {
        fps1_seg_body(x, blockIdx.x, 480, 32, fps1, nx1, dl1s, st, smem);
        return;
    }
    if (blockIdx.x < 1040u) {
        sel_body(Dold, qbOld, idxf, blockIdx.x - 16);
        return;
    }
    proj64_body(blockIdx.x - 1040, 32, 4, ft, (long)N_*64, 64, wpp,
                big, (long)N_*256, 256, 0, 0, nullptr, nullptr, smem);
}

// ---------------------------------------------------------------------------
// d10: FPS2(0,128) + edgefuse + x_skip projection
// ---------------------------------------------------------------------------
__global__ void __launch_bounds__(256, 4) k_tail10(
    const float* __restrict__ nx1, int* __restrict__ fps2, float* __restrict__ nx2,
    float* __restrict__ dl2s, float* __restrict__ st,
    const float* __restrict__ P, const int* __restrict__ idxg, const int* __restrict__ idxf,
    const float* __restrict__ wft, const float* __restrict__ sc, float* __restrict__ outf,
    const float* __restrict__ ft, const float* __restrict__ w2, float* __restrict__ V)
{
    __shared__ float smem[8704];
    if (blockIdx.x < 16u) {
        fps2_seg_body(blockIdx.x, 0, 128, nx1, fps2, nx2, dl2s, st, smem);
        return;
    }
    if (blockIdx.x < (unsigned)(16 + 8192)) {
        edgefuse_body(P, idxg, idxf, wft, sc, outf, blockIdx.x - 16, smem);
        return;
    }
    // x_skip: rows = 256 sampled points (stride 8), cols = 1024, relu(bn2)
    proj64_body(blockIdx.x - (16 + 8192), 4, 16, ft, (long)N_*64, 512, w2,
                V, (long)NP2*1280, 1280, 256, 1, sc + SC_S2, sc + SC_T2, smem);
}

// ---------------------------------------------------------------------------
// d11: FPS2(128,128) + knn1 + Q0 projection
// ---------------------------------------------------------------------------
__global__ void __launch_bounds__(256, 4) k_tail11(
    const float* __restrict__ nx1, int* __restrict__ fps2, float* __restrict__ nx2,
    float* __restrict__ dl2s, float* __restrict__ st,
    const float* __restrict__ x, int* __restrict__ idx1,
    const float* __restrict__ outf, const float* __restrict__ wpq0, float* __restrict__ big)
{
    __shared__ float smem[8704];
    if (blockIdx.x < 16u) {
        fps2_seg_body(blockIdx.x, 128, 128, nx1, fps2, nx2, dl2s, st, smem);
        return;
    }
    if (blockIdx.x < (unsigned)(16 + 2048)) {
        knn_gbody<2048,32,32>(nx1, (long)NP1*3, 3, 1, NP1,
                              x, (long)6*N_, (long)1, (long)N_, idx1, blockIdx.x - 16);
        return;
    }
    proj64_body(blockIdx.x - (16 + 2048), 32, 4, outf, (long)N_*64, 64, wpq0,
                big, (long)N_*256, 256, 0, 0, nullptr, nullptr, smem);
}

// ---------------------------------------------------------------------------
// d12: gathermax0 + knn2
// ---------------------------------------------------------------------------
__global__ void __launch_bounds__(256, 4) k_gm0knn2(
    const float* __restrict__ big, const int* __restrict__ idx1, const int* __restrict__ fps1,
    const float* __restrict__ sc, float* __restrict__ f0t,
    const float* __restrict__ nx2, const float* __restrict__ nx1, int* __restrict__ idx2)
{
    if (blockIdx.x < 2048u) {
        gathermax_body<2,256,128,2048,512>(big, idx1, fps1,
            sc + SC_SGL0, sc + SC_TGL0, f0t, 128, blockIdx.x);
        return;
    }
    knn_gbody<512,8,32>(nx2, (long)NP2*3, 3, 1, NP2,
                        nx1, (long)NP1*3, (long)3, (long)1, idx2, blockIdx.x - 2048);
}

// ---------------------------------------------------------------------------
// generic GEMM (Q1 projection K=128, final K=1280)
// ---------------------------------------------------------------------------
__global__ void __launch_bounds__(256) k_gemm(
    const float* __restrict__ A, long aBatch, int aRow,
    const float* __restrict__ Bw, long bBatch, int K,
    float* __restrict__ C, long cBatch, int cRow, int cCol0,
    int act, const float* __restrict__ sv, const float* __restrict__ tv,
    int epi)
{
    __shared__ float As[64][68];
    __shared__ float Bs[64][68];
    const int b  = blockIdx.z;
    const int ib = blockIdx.x * 64;
    const int jb = blockIdx.y * 64;
    const int t  = threadIdx.x;
    const int tx = t & 15, ty = t >> 4;
    const float* Ab = A + (long)b * aBatch;
    const float* Bb = Bw + (long)b * bBatch;
    float acc[4][4];
    #pragma unroll
    for (int i = 0; i < 4; i++)
        #pragma unroll
        for (int j = 0; j < 4; j++) acc[i][j] = 0.0f;

    for (int kb = 0; kb < K; kb += 64) {
        #pragma unroll
        for (int m = 0; m < 4; m++) {
            int li = t + m*256; int r = li >> 4; int c4 = li & 15;
            float4 av = *(const float4*)(Ab + (long)(ib + r)*aRow + kb + c4*4);
            As[c4*4+0][r] = av.x; As[c4*4+1][r] = av.y;
            As[c4*4+2][r] = av.z; As[c4*4+3][r] = av.w;
            float4 bv = *(const float4*)(Bb + (long)(jb + r)*K + kb + c4*4);
            Bs[c4*4+0][r] = bv.x; Bs[c4*4+1][r] = bv.y;
            Bs[c4*4+2][r] = bv.z; Bs[c4*4+3][r] = bv.w;
        }
        __syncthreads();
        #pragma unroll 4
        for (int k = 0; k < 64; k++) {
            float4 a  = *(const float4*)&As[k][ty*4];
            float4 b4 = *(const float4*)&Bs[k][tx*4];
            acc[0][0] += a.x*b4.x; acc[0][1] += a.x*b4.y; acc[0][2] += a.x*b4.z; acc[0][3] += a.x*b4.w;
            acc[1][0] += a.y*b4.x; acc[1][1] += a.y*b4.y; acc[1][2] += a.y*b4.z; acc[1][3] += a.y*b4.w;
            acc[2][0] += a.z*b4.x; acc[2][1] += a.z*b4.y; acc[2][2] += a.z*b4.z; acc[2][3] += a.z*b4.w;
            acc[3][0] += a.w*b4.x; acc[3][1] += a.w*b4.y; acc[3][2] += a.w*b4.z; acc[3][3] += a.w*b4.w;
        }
        __syncthreads();
    }

    const int i0 = ib + ty*4;
    const int j0 = jb + tx*4;
    if (epi == 2) {
        #pragma unroll
        for (int ii = 0; ii < 4; ii++)
            #pragma unroll
            for (int jj = 0; jj < 4; jj++) {
                int j = j0 + jj;
                float vv = lrelu_(sv[j]*acc[ii][jj] + tv[j]);
                C[(long)b*cBatch + (long)j*cRow + (i0+ii)] = vv;
            }
    } else {
        #pragma unroll
        for (int ii = 0; ii < 4; ii++)
            #pragma unroll
            for (int jj = 0; jj < 4; jj++) {
                int j = j0 + jj;
                float vv = acc[ii][jj];
                if (act == 1) vv = fmaxf(sv[j]*vv + tv[j], 0.0f);
                else if (act == 2) vv = lrelu_(sv[j]*vv + tv[j]);
                C[(long)b*cBatch + (long)(i0+ii)*cRow + cCol0 + j] = vv;
            }
    }
}

// ---------------------------------------------------------------------------
// standalone gathermax (d14)
// ---------------------------------------------------------------------------
template<int QN, int ROWW, int CO, int MROWS, int SO>
__global__ void __launch_bounds__(256) k_gathermax(
    const float* __restrict__ Q, const int* __restrict__ knn, const int* __restrict__ fpsi,
    const float* __restrict__ sv, const float* __restrict__ tv,
    float* __restrict__ outp, int outRow)
{
    gathermax_body<QN,ROWW,CO,MROWS,SO>(Q, knn, fpsi, sv, tv, outp, outRow, blockIdx.x);
}

// ---------------------------------------------------------------------------
extern "C" void kernel_launch(void* const* d_in, const int* in_sizes, int n_in,
                              void* d_out, int out_size, void* d_ws, size_t ws_size,
                              hipStream_t stream)
{
    const float* x      = (const float*)d_in[0];
    const float* w1     = (const float*)d_in[1];
    const float* bn1    = (const float*)d_in[2];
    const float* w2     = (const float*)d_in[3];
    const float* bn2    = (const float*)d_in[4];
    const float* geow   = (const float*)d_in[5];
    const float* geobn  = (const float*)d_in[6];
    const float* featw  = (const float*)d_in[7];
    const float* featbn = (const float*)d_in[8];
    const float* fusew  = (const float*)d_in[9];
    const float* fusebn = (const float*)d_in[10];
    const float* gl0w   = (const float*)d_in[11];
    const float* gl0bn  = (const float*)d_in[12];
    const float* gl1w   = (const float*)d_in[13];
    const float* gl1bn  = (const float*)d_in[14];
    const float* wf     = (const float*)d_in[15];
    const float* bnfp   = (const float*)d_in[16];

    float* ws  = (float*)d_ws;
    float* out = (float*)d_out;

    float* FT   = ws + OFF_FT;
    float* SQ   = ws + OFF_SQ;
    float* BIG  = ws + OFF_BIG;
    int*   IDXG = (int*)(ws + OFF_IDXG);
    int*   IDXF = (int*)(ws + OFF_IDXF);
    float* OUTF = ws + OFF_OUTF;
    int*   FPS1 = (int*)(ws + OFF_FPS1);
    float* NX1  = ws + OFF_NX1;
    int*   IDX1 = (int*)(ws + OFF_IDX1);
    float* F0T  = ws + OFF_F0T;
    int*   FPS2 = (int*)(ws + OFF_FPS2);
    float* NX2  = ws + OFF_NX2;
    int*   IDX2 = (int*)(ws + OFF_IDX2);
    float* Q1B  = ws + OFF_Q1;
    float* V    = ws + OFF_V;
    float* WPP  = ws + OFF_WPP;
    float* WPQ0 = ws + OFF_WPQ0;
    float* WPQ1 = ws + OFF_WPQ1;
    float* WFT  = ws + OFF_WFT;
    float* SC   = ws + OFF_SC;
    float* DL1  = ws + OFF_DL1;
    float* DL2  = ws + OFF_DL2;
    float* ST   = ws + OFF_ST;

    hipLaunchKernelGGL(k_prep, dim3(64), dim3(256), 0, stream,
        bn1, bn2, geow, geobn, featw, featbn, fusew, fusebn, gl0w, gl0bn, gl1w, gl1bn, bnfp, ws);

    hipLaunchKernelGGL(k_feat0, dim3(B_*N_/4), dim3(256), 0, stream, x, w1, SC, FT, SQ);

    // d1: FPS1 first 256 iters + geo-knn + dist gemm chunk0 -> BIG
    hipLaunchKernelGGL(k_geo0, dim3(B_ + 8192 + 2048), dim3(256), 0, stream,
        x, IDXG, FPS1, NX1, DL1, ST, FT, SQ, BIG);

    // d2..d8: {FPS1 seg (32) + sel(ci-1) + gemm(ci)}
    float* bufs[2] = { BIG, Q1B };
    for (int ci = 1; ci < 8; ci++) {
        hipLaunchKernelGGL(k_chain, dim3(16 + 1024 + 2048), dim3(256), 0, stream,
            x, FT, SQ,
            bufs[ci & 1], ci*CHQ,
            bufs[(ci - 1) & 1], (ci - 1)*CHQ,
            IDXF, FPS1, NX1, DL1, ST, 256 + 32*(ci - 1));
    }

    // d9: FPS1 last 32 + sel7 + P projection -> BIG
    hipLaunchKernelGGL(k_tail9, dim3(16 + 1024 + 2048), dim3(256), 0, stream,
        x, FT, bufs[1], 7*CHQ, IDXF, FPS1, NX1, DL1, ST, WPP, BIG);

    // d10: FPS2 seg0 + edgefuse + x_skip
    hipLaunchKernelGGL(k_tail10, dim3(16 + 8192 + 1024), dim3(256), 0, stream,
        NX1, FPS2, NX2, DL2, ST,
        BIG, IDXG, IDXF, WFT, SC, OUTF,
        FT, w2, V);

    // d11: FPS2 seg1 + knn1 + Q0 projection -> BIG
    hipLaunchKernelGGL(k_tail11, dim3(16 + 2048 + 2048), dim3(256), 0, stream,
        NX1, FPS2, NX2, DL2, ST,
        x, IDX1,
        OUTF, WPQ0, BIG);

    // d12: gathermax0 + knn2
    hipLaunchKernelGGL(k_gm0knn2, dim3(2048 + 1024), dim3(256), 0, stream,
        BIG, IDX1, FPS1, SC, F0T, NX2, NX1, IDX2);

    // d13: Q1 projection (K=128)
    hipLaunchKernelGGL(k_gemm, dim3(NP1/64, 512/64, B_), dim3(256), 0, stream,
        F0T, (long)NP1*128, 128, WPQ1, (long)0, 128,
        Q1B, (long)NP1*512, 512, 0, 0, nullptr, nullptr, 0);

    // d14: gathermax1
    hipLaunchKernelGGL((k_gathermax<4,512,256,512,256>), dim3(B_*NP2/4), dim3(256), 0, stream,
        Q1B, IDX2, FPS2, SC + SC_SGL1, SC + SC_TGL1, V, 1280);

    // d15: final (B,512,256) = lrelu(bnf(wf . V^T)), transposed store
    hipLaunchKernelGGL(k_gemm, dim3(NP2/64, 512/64, B_), dim3(256), 0, stream,
        V, (long)NP2*1280, 1280, wf, (long)0, 1280,
        out, (long)512*256, 256, 0, 2, SC + SC_SF, SC + SC_TF, 2);

    (void)in_sizes; (void)n_in; (void)out_size; (void)ws_size;
}

// Round 16
// 660.475 us; speedup vs baseline: 10.7779x; 1.0761x over previous
//
#include <hip/hip_runtime.h>
#include <float.h>
#include <math.h>

// ---------------------------------------------------------------------------
// SSFE_Net pipeline on MI355X. B=16, N=2048.
// R14: FPS smeared across dispatches; fused chain. 711us.
// R15: (a) XOR-swizzled conflict-free LDS staging in ALL GEMM bodies
//      (write bank was 8-way: (16*c4+r)%32; now r^4*(c4&7) -> 2-way free);
//      (b) precomputed ref sumsq (gsq) for geo-knn/knn1, bit-identical
//      rounding order (computed in k_feat0).
// ---------------------------------------------------------------------------

static constexpr int B_   = 16;
static constexpr int N_   = 2048;
static constexpr int NP1  = 512;
static constexpr int NP2  = 256;
static constexpr int KG   = 20;
static constexpr int NSAMP= 32;
static constexpr int CHQ  = 256;

// workspace offsets (in float elements)
static constexpr long OFF_FT   = 0;
static constexpr long OFF_SQ   = OFF_FT   + (long)B_*N_*64;
static constexpr long OFF_BIG  = OFF_SQ   + (long)B_*N_;          // D chunk A / P / Q0
static constexpr long OFF_IDXG = OFF_BIG  + (long)B_*N_*256;
static constexpr long OFF_IDXF = OFF_IDXG + (long)B_*N_*KG;
static constexpr long OFF_OUTF = OFF_IDXF + (long)B_*N_*KG;
static constexpr long OFF_FPS1 = OFF_OUTF + (long)B_*N_*64;
static constexpr long OFF_NX1  = OFF_FPS1 + (long)B_*NP1;
static constexpr long OFF_IDX1 = OFF_NX1  + (long)B_*NP1*3;
static constexpr long OFF_F0T  = OFF_IDX1 + (long)B_*NP1*NSAMP;
static constexpr long OFF_FPS2 = OFF_F0T  + (long)B_*NP1*128;
static constexpr long OFF_NX2  = OFF_FPS2 + (long)B_*NP2;
static constexpr long OFF_IDX2 = OFF_NX2  + (long)B_*NP2*3;
static constexpr long OFF_Q1   = OFF_IDX2 + (long)B_*NP2*NSAMP;  // D chunk B (Q1+V)
static constexpr long OFF_V    = OFF_Q1   + (long)B_*NP1*512;
static constexpr long OFF_WPP  = OFF_V    + (long)B_*NP2*1280;
static constexpr long OFF_WPQ0 = OFF_WPP  + 256*64;
static constexpr long OFF_WPQ1 = OFF_WPQ0 + 256*64;
static constexpr long OFF_WFT  = OFF_WPQ1 + 512*128;
static constexpr long OFF_SC   = OFF_WFT  + 128*64;
static constexpr long OFF_DL1  = OFF_SC   + 4352;               // FPS1 dl state
static constexpr long OFF_DL2  = OFF_DL1  + (long)B_*256*8;     // FPS2 dl state
static constexpr long OFF_ST   = OFF_DL2  + (long)B_*512;       // far/centroid state
static constexpr long OFF_GSQ  = OFF_ST   + 256;                // xyz sumsq (B*N)

// SC (bn scale/shift) sub-offsets
static constexpr int SC_S1=0, SC_T1=64, SC_SGEO=128, SC_TGEO=192, SC_SFEAT=256, SC_TFEAT=320,
   SC_SFUSE=384, SC_TFUSE=448, SC_SGL0=512, SC_TGL0=640, SC_SGL1=768, SC_TGL1=1024,
   SC_S2=1280, SC_T2=2304, SC_SF=3328, SC_TF=3840;

__device__ __forceinline__ float lrelu_(float x) { return x >= 0.0f ? x : 0.2f * x; }

// masked DPP max step
template<int CTRL, int RM>
__device__ __forceinline__ float dpp_maxm(float v) {
    int o = __builtin_amdgcn_update_dpp(__float_as_int(v), __float_as_int(v),
                                        CTRL, RM, 0xF, false);
    return fmaxf(v, __int_as_float(o));
}
__device__ __forceinline__ float wave_max64_sgpr(float v) {
    v = dpp_maxm<0xB1, 0xF>(v);
    v = dpp_maxm<0x4E, 0xF>(v);
    v = dpp_maxm<0x141,0xF>(v);
    v = dpp_maxm<0x140,0xF>(v);
    v = dpp_maxm<0x142,0xA>(v);
    v = dpp_maxm<0x143,0xC>(v);
    return __int_as_float(__builtin_amdgcn_readlane(__float_as_int(v), 63));
}

template<int CTRL>
__device__ __forceinline__ unsigned dpp_minu(unsigned x) {
    unsigned o = (unsigned)__builtin_amdgcn_update_dpp(0, (int)x, CTRL, 0xF, 0xF, true);
    return o < x ? o : x;
}
__device__ __forceinline__ unsigned wave_minu(unsigned x) {
    x = dpp_minu<0xB1>(x);
    x = dpp_minu<0x4E>(x);
    x = dpp_minu<0x141>(x);
    x = dpp_minu<0x140>(x);
    { unsigned o = (unsigned)__shfl_xor((int)x, 16); x = o < x ? o : x; }
    { unsigned o = (unsigned)__shfl_xor((int)x, 32); x = o < x ? o : x; }
    return x;
}

__device__ __forceinline__ unsigned sortable_(float f) {
    unsigned u = __float_as_uint(f);
    return u ^ ((unsigned)((int)u >> 31) | 0x80000000u);
}

// ---------------------------------------------------------------------------
// prep
// ---------------------------------------------------------------------------
__global__ void k_prep(const float* __restrict__ bn1, const float* __restrict__ bn2,
                       const float* __restrict__ geow, const float* __restrict__ geobn,
                       const float* __restrict__ featw, const float* __restrict__ featbn,
                       const float* __restrict__ fusew, const float* __restrict__ fusebn,
                       const float* __restrict__ gl0w, const float* __restrict__ gl0bn,
                       const float* __restrict__ gl1w, const float* __restrict__ gl1bn,
                       const float* __restrict__ bnfp, float* __restrict__ ws)
{
    const int tid = blockIdx.x * blockDim.x + threadIdx.x;
    const int nt  = gridDim.x * blockDim.x;
    float* sc = ws + OFF_SC;
    {
        const float* ps[8]  = {bn1, geobn, featbn, fusebn, gl0bn, gl1bn, bn2, bnfp};
        const int    ch[8]  = {64, 64, 64, 64, 128, 256, 1024, 512};
        const int    so[8]  = {SC_S1, SC_SGEO, SC_SFEAT, SC_SFUSE, SC_SGL0, SC_SGL1, SC_S2, SC_SF};
        const int    to[8]  = {SC_T1, SC_TGEO, SC_TFEAT, SC_TFUSE, SC_TGL0, SC_TGL1, SC_T2, SC_TF};
        for (int g = 0; g < 8; g++) {
            const float* p = ps[g]; int C = ch[g];
            for (int i = tid; i < C; i += nt) {
                float gg = p[i], bb = p[C+i], mm = p[2*C+i], vv = p[3*C+i];
                float s = gg * (1.0f / sqrtf(vv + 1e-5f));
                sc[so[g] + i] = s;
                sc[to[g] + i] = bb - mm * s;
            }
        }
    }
    for (int j = tid; j < 256*64; j += nt) {
        int o = j >> 6, c = j & 63; float v;
        if      (o < 64)  v = geow[o*128 + c];
        else if (o < 128) v = geow[(o-64)*128 + 64 + c];
        else if (o < 192) v = featw[(o-128)*128 + c];
        else              v = featw[(o-192)*128 + 64 + c];
        ws[OFF_WPP + j] = v;
    }
    for (int j = tid; j < 256*64; j += nt) {
        int o = j >> 6, c = j & 63; float v;
        if (o < 128) v = gl0w[o*128 + c];
        else         v = gl0w[(o-128)*128 + 64 + c] - gl0w[(o-128)*128 + c];
        ws[OFF_WPQ0 + j] = v;
    }
    for (int j = tid; j < 512*128; j += nt) {
        int o = j >> 7, c = j & 127; float v;
        if (o < 256) v = gl1w[o*256 + c];
        else         v = gl1w[(o-256)*256 + 128 + c] - gl1w[(o-256)*256 + c];
        ws[OFF_WPQ1 + j] = v;
    }
    for (int j = tid; j < 128*64; j += nt) {
        int c = j >> 6, o = j & 63;
        ws[OFF_WFT + j] = fusew[o*128 + c];
    }
}

// ---------------------------------------------------------------------------
// feat0 (+ gsq: xyz sumsq, exact knn rounding order)
// ---------------------------------------------------------------------------
__global__ void __launch_bounds__(256) k_feat0(const float* __restrict__ x,
                                               const float* __restrict__ w1,
                                               const float* __restrict__ sc,
                                               float* __restrict__ ft, float* __restrict__ sq,
                                               float* __restrict__ gsq)
{
    const int t = threadIdx.x, lane = t & 63, w = t >> 6;
    const int pid = blockIdx.x*4 + w;
    const int b = pid >> 11, n = pid & (N_-1);
    const float* xb = x + (long)b*6*N_ + n;
    float acc = 0.0f;
    #pragma unroll
    for (int c = 0; c < 6; c++) acc += w1[lane*6 + c] * xb[(long)c*N_];
    float val = fmaxf(sc[SC_S1 + lane]*acc + sc[SC_T1 + lane], 0.0f);
    ft[((long)b*N_ + n)*64 + lane] = val;
    float v2 = val*val;
    #pragma unroll
    for (int s = 1; s < 64; s <<= 1) v2 += __shfl_xor(v2, s);
    if (lane == 0) {
        sq[b*N_ + n] = v2;
        float rx = xb[0], ry = xb[N_], rz = xb[2*N_];
        gsq[b*N_ + n] = __fadd_rn(__fadd_rn(__fmul_rn(rx,rx), __fmul_rn(ry,ry)),
                                  __fmul_rn(rz,rz));
    }
}

// ---------------------------------------------------------------------------
// topk_sel3
// ---------------------------------------------------------------------------
template<int RPL, int KSEL>
__device__ __forceinline__ void topk_sel3(float (&v)[RPL], int lane, int* __restrict__ out)
{
    unsigned key[RPL];
    #pragma unroll
    for (int j = 0; j < RPL; j++) key[j] = sortable_(v[j]);

    unsigned consumed = 0;
    unsigned m1 = key[0]; int s1 = 0;
    unsigned m2 = 0xFFFFFFFFu; int s2 = 0;
    #pragma unroll
    for (int j = 1; j < RPL; j++) {
        unsigned kk = key[j];
        bool lt1 = kk < m1;
        bool lt2 = kk < m2;
        unsigned nm2 = lt1 ? m1 : (lt2 ? kk : m2);
        int      ns2 = lt1 ? s1 : (lt2 ? j  : s2);
        m1 = lt1 ? kk : m1;
        s1 = lt1 ? j  : s1;
        m2 = nm2; s2 = ns2;
    }
    #pragma unroll 1
    for (int k = 0; k < KSEL; k++) {
        unsigned g = wave_minu(m1);
        unsigned long long cand = __ballot(m1 == g);
        int gi;
        if (__popcll(cand) > 1) {
            int ci = (m1 == g) ? (s1*64 + lane) : 0x7FFFFFFF;
            #pragma unroll
            for (int s = 1; s < 64; s <<= 1) { int o = __shfl_xor(ci, s); ci = o < ci ? o : ci; }
            gi = ci;
        } else {
            int wl = __ffsll((long long)cand) - 1;
            gi = __builtin_amdgcn_readlane(s1, wl) * 64 + wl;
        }
        if (lane == 0) out[k] = gi;
        if (k + 1 < KSEL) {
            bool win = (m1 == g) && (s1*64 + lane == gi);
            if (win) {
                consumed |= 1u << s1;
                m1 = m2; s1 = s2;
                m2 = 0xFFFFFFFFu;
            }
            bool need = win && (m1 == 0xFFFFFFFFu);
            if (__any(need)) {
                if (need) {
                    m1 = 0xFFFFFFFFu; s1 = 0; m2 = 0xFFFFFFFFu; s2 = 0;
                    #pragma unroll
                    for (int j = 0; j < RPL; j++) {
                        unsigned kk = ((consumed >> j) & 1u) ? 0xFFFFFFFFu : key[j];
                        bool lt1 = kk < m1;
                        bool lt2 = kk < m2;
                        unsigned nm2 = lt1 ? m1 : (lt2 ? kk : m2);
                        int      ns2 = lt1 ? s1 : (lt2 ? j  : s2);
                        m1 = lt1 ? kk : m1;
                        s1 = lt1 ? j  : s1;
                        m2 = nm2; s2 = ns2;
                    }
                }
            }
        }
    }
}

// ---------------------------------------------------------------------------
// knn body; RSQ: ref sumsq from precomputed buffer (bit-identical value).
// ---------------------------------------------------------------------------
template<int NREF, int RPL, int KSEL, bool RSQ>
__device__ __forceinline__ void knn_gbody(
    const float* qp, long qBatch, int qsN, int qsD, int NQ,
    const float* rp, long rBatch, long rsN, long rsD,
    const float* rsq, long rsqBatch,
    int* out, int bid)
{
    const int t = threadIdx.x, lane = t & 63, w = t >> 6;
    const int bpb = NQ / 4;
    const int b = bid / bpb;
    const int qi = (bid % bpb)*4 + w;
    const float* rb = rp + (long)b*rBatch;
    const float* qb = qp + (long)b*qBatch + (long)qi*qsN;
    float qx = qb[0], qy = qb[qsD], qz = qb[2*qsD];
    float sumq = __fadd_rn(__fadd_rn(__fmul_rn(qx,qx), __fmul_rn(qy,qy)), __fmul_rn(qz,qz));
    float v[RPL];
    #pragma unroll
    for (int j = 0; j < RPL; j++) {
        long n = j*64 + lane;
        float rx = rb[n*rsN];
        float ry = rb[n*rsN + rsD];
        float rz = rb[n*rsN + 2*rsD];
        float dot = __fadd_rn(__fadd_rn(__fmul_rn(qx,rx), __fmul_rn(qy,ry)), __fmul_rn(qz,rz));
        float sumr;
        if constexpr (RSQ) sumr = rsq[(long)b*rsqBatch + n];
        else sumr = __fadd_rn(__fadd_rn(__fmul_rn(rx,rx), __fmul_rn(ry,ry)), __fmul_rn(rz,rz));
        v[j] = __fadd_rn(__fsub_rn(sumq, __fmul_rn(2.0f, dot)), sumr);
    }
    topk_sel3<RPL, KSEL>(v, lane, out + ((long)b*NQ + qi)*KSEL);
}

// ---------------------------------------------------------------------------
// FPS1 segment (unchanged from R14)
// ---------------------------------------------------------------------------
__device__ __forceinline__ void fps1_seg_body(
    const float* __restrict__ x, int b, int i0, int cnt,
    int* __restrict__ fps1, float* __restrict__ nx1,
    float* __restrict__ dl1s, float* __restrict__ st, float* __restrict__ smem)
{
    __builtin_amdgcn_s_setprio(3);
    const int t = threadIdx.x, lane = t & 63, wave = t >> 6;
    const float* pb = x + (long)b*6*N_;

    float4* mrgc   = (float4*)smem;
    int*    mrgi   = (int*)(smem + 32);
    int*    sidxsg = (int*)(smem + 40);
    float*  mxsg   = smem + 296;
    float*  mysg   = smem + 552;
    float*  mzsg   = smem + 808;

    float px[8], py[8], pz[8], dl[8];
    {
        const float4* a4  = (const float4*)(pb + 8*t);
        const float4* b4  = (const float4*)(pb + N_ + 8*t);
        const float4* c4p = (const float4*)(pb + 2*N_ + 8*t);
        float4 a0 = a4[0], a1 = a4[1];
        float4 b0 = b4[0], b1 = b4[1];
        float4 c0 = c4p[0], c1 = c4p[1];
        px[0]=a0.x; px[1]=a0.y; px[2]=a0.z; px[3]=a0.w;
        px[4]=a1.x; px[5]=a1.y; px[6]=a1.z; px[7]=a1.w;
        py[0]=b0.x; py[1]=b0.y; py[2]=b0.z; py[3]=b0.w;
        py[4]=b1.x; py[5]=b1.y; py[6]=b1.z; py[7]=b1.w;
        pz[0]=c0.x; pz[1]=c0.y; pz[2]=c0.z; pz[3]=c0.w;
        pz[4]=c1.x; pz[5]=c1.y; pz[6]=c1.z; pz[7]=c1.w;
    }
    int far; float cx, cy, cz;
    if (i0 == 0) {
        #pragma unroll
        for (int p = 0; p < 8; p++) dl[p] = 1e10f;
        far = 0; cx = pb[0]; cy = pb[N_]; cz = pb[2*N_];
    } else {
        const float4* ds = (const float4*)(dl1s + ((long)b*256 + t)*8);
        float4 d0 = ds[0], d1 = ds[1];
        dl[0]=d0.x; dl[1]=d0.y; dl[2]=d0.z; dl[3]=d0.w;
        dl[4]=d1.x; dl[5]=d1.y; dl[6]=d1.z; dl[7]=d1.w;
        far = __float_as_int(st[b*16+0]);
        cx = st[b*16+1]; cy = st[b*16+2]; cz = st[b*16+3];
    }

    for (int k = 0; k < cnt; k++) {
        if (t == 0) { sidxsg[k] = far; mxsg[k] = cx; mysg[k] = cy; mzsg[k] = cz; }
        float bv = -1.0f; int bp = 0;
        #pragma unroll
        for (int p = 0; p < 8; p++) {
            float dx = __fsub_rn(px[p], cx);
            float dy = __fsub_rn(py[p], cy);
            float dz = __fsub_rn(pz[p], cz);
            float d  = __fadd_rn(__fadd_rn(__fmul_rn(dx,dx), __fmul_rn(dy,dy)), __fmul_rn(dz,dz));
            float nd = fminf(dl[p], d);
            dl[p] = nd;
            if (nd > bv) { bv = nd; bp = p; }
        }
        float wx = px[0], wy = py[0], wz = pz[0];
        #pragma unroll
        for (int p = 1; p < 8; p++) {
            bool c = (bp == p);
            wx = c ? px[p] : wx; wy = c ? py[p] : wy; wz = c ? pz[p] : wz;
        }
        float gm = wave_max64_sgpr(bv);
        unsigned long long cand = __ballot(bv == gm);
        int wl = __ffsll((long long)cand) - 1;
        int   wbp = __builtin_amdgcn_readlane(bp, wl);
        float sxw = __int_as_float(__builtin_amdgcn_readlane(__float_as_int(wx), wl));
        float syw = __int_as_float(__builtin_amdgcn_readlane(__float_as_int(wy), wl));
        float szw = __int_as_float(__builtin_amdgcn_readlane(__float_as_int(wz), wl));
        int par = k & 1;
        if (lane == 0) {
            mrgc[par*4 + wave] = make_float4(sxw, syw, szw, gm);
            mrgi[par*4 + wave] = (((wave << 6) | wl) << 3) + wbp;
        }
        __syncthreads();
        float4 e0 = mrgc[par*4 + 0];
        float fv = e0.w; int fi = mrgi[par*4 + 0];
        float ncx = e0.x, ncy = e0.y, ncz = e0.z;
        #pragma unroll
        for (int w2 = 1; w2 < 4; w2++) {
            float4 e2 = mrgc[par*4 + w2]; int i2 = mrgi[par*4 + w2];
            if (e2.w > fv) { fv = e2.w; fi = i2; ncx = e2.x; ncy = e2.y; ncz = e2.z; }
        }
        far = fi; cx = ncx; cy = ncy; cz = ncz;
    }
    __syncthreads();

    int*   f1o = fps1 + b*NP1;
    float* n1o = nx1 + (long)b*NP1*3;
    for (int s = t; s < cnt; s += 256) {
        f1o[i0+s] = sidxsg[s];
        n1o[(long)(i0+s)*3+0] = mxsg[s];
        n1o[(long)(i0+s)*3+1] = mysg[s];
        n1o[(long)(i0+s)*3+2] = mzsg[s];
    }
    float4* ds = (float4*)(dl1s + ((long)b*256 + t)*8);
    ds[0] = make_float4(dl[0], dl[1], dl[2], dl[3]);
    ds[1] = make_float4(dl[4], dl[5], dl[6], dl[7]);
    if (t == 0) {
        st[b*16+0] = __int_as_float(far);
        st[b*16+1] = cx; st[b*16+2] = cy; st[b*16+3] = cz;
    }
    __builtin_amdgcn_s_setprio(0);
}

// ---------------------------------------------------------------------------
// FPS2 segment (unchanged from R14)
// ---------------------------------------------------------------------------
__device__ __forceinline__ void fps2_seg_body(
    int b, int i0, int cnt,
    const float* __restrict__ nx1, int* __restrict__ fps2, float* __restrict__ nx2,
    float* __restrict__ dl2s, float* __restrict__ st, float* __restrict__ smem)
{
    __builtin_amdgcn_s_setprio(3);
    const int t = threadIdx.x, lane = t & 63, wave = t >> 6;
    float4* mrgc   = (float4*)smem;
    int*    mrgi   = (int*)(smem + 32);
    int*    sidxsg = (int*)(smem + 40);
    float*  mx2    = smem + 168;
    float*  my2    = smem + 680;
    float*  mz2    = smem + 1192;

    const float* n1 = nx1 + (long)b*NP1*3;
    for (int s = t; s < NP1; s += 256) {
        mx2[s] = n1[(long)s*3+0];
        my2[s] = n1[(long)s*3+1];
        mz2[s] = n1[(long)s*3+2];
    }
    __syncthreads();

    const int n0 = t << 1;
    float ax = mx2[n0],   ay = my2[n0],   az = mz2[n0];
    float bx = mx2[n0+1], by = my2[n0+1], bz = mz2[n0+1];
    float dl0, dl1; int far2; float c2x, c2y, c2z;
    if (i0 == 0) {
        dl0 = dl1 = 1e10f; far2 = 0;
        c2x = mx2[0]; c2y = my2[0]; c2z = mz2[0];
    } else {
        dl0 = dl2s[(long)b*512 + n0];
        dl1 = dl2s[(long)b*512 + n0 + 1];
        far2 = __float_as_int(st[b*16+4]);
        c2x = st[b*16+5]; c2y = st[b*16+6]; c2z = st[b*16+7];
    }

    for (int k = 0; k < cnt; k++) {
        if (t == 0) sidxsg[k] = far2;
        float dx = __fsub_rn(ax, c2x), dy = __fsub_rn(ay, c2y), dz = __fsub_rn(az, c2z);
        float d0 = __fadd_rn(__fadd_rn(__fmul_rn(dx,dx), __fmul_rn(dy,dy)), __fmul_rn(dz,dz));
        dx = __fsub_rn(bx, c2x); dy = __fsub_rn(by, c2y); dz = __fsub_rn(bz, c2z);
        float d1 = __fadd_rn(__fadd_rn(__fmul_rn(dx,dx), __fmul_rn(dy,dy)), __fmul_rn(dz,dz));
        dl0 = fminf(dl0, d0);
        dl1 = fminf(dl1, d1);
        float bv = dl0; int bp = 0;
        if (dl1 > bv) { bv = dl1; bp = 1; }
        float wx = bp ? bx : ax, wy = bp ? by : ay, wz = bp ? bz : az;
        float gm = wave_max64_sgpr(bv);
        unsigned long long cand = __ballot(bv == gm);
        int wl = __ffsll((long long)cand) - 1;
        int   wbp = __builtin_amdgcn_readlane(bp, wl);
        float sxw = __int_as_float(__builtin_amdgcn_readlane(__float_as_int(wx), wl));
        float syw = __int_as_float(__builtin_amdgcn_readlane(__float_as_int(wy), wl));
        float szw = __int_as_float(__builtin_amdgcn_readlane(__float_as_int(wz), wl));
        int par = k & 1;
        if (lane == 0) {
            mrgc[par*4 + wave] = make_float4(sxw, syw, szw, gm);
            mrgi[par*4 + wave] = (((wave << 6) | wl) << 1) + wbp;
        }
        __syncthreads();
        float4 e0 = mrgc[par*4 + 0];
        float fv = e0.w; int fi = mrgi[par*4 + 0];
        float ncx = e0.x, ncy = e0.y, ncz = e0.z;
        #pragma unroll
        for (int w2 = 1; w2 < 4; w2++) {
            float4 e2 = mrgc[par*4 + w2]; int i2 = mrgi[par*4 + w2];
            if (e2.w > fv) { fv = e2.w; fi = i2; ncx = e2.x; ncy = e2.y; ncz = e2.z; }
        }
        far2 = fi; c2x = ncx; c2y = ncy; c2z = ncz;
    }
    __syncthreads();

    int*   f2o = fps2 + b*NP2;
    float* n2o = nx2 + (long)b*NP2*3;
    for (int s = t; s < cnt; s += 256) {
        int j = sidxsg[s];
        f2o[i0+s] = j;
        n2o[(long)(i0+s)*3+0] = mx2[j];
        n2o[(long)(i0+s)*3+1] = my2[j];
        n2o[(long)(i0+s)*3+2] = mz2[j];
    }
    dl2s[(long)b*512 + n0]     = dl0;
    dl2s[(long)b*512 + n0 + 1] = dl1;
    if (t == 0) {
        st[b*16+4] = __int_as_float(far2);
        st[b*16+5] = c2x; st[b*16+6] = c2y; st[b*16+7] = c2z;
    }
    __builtin_amdgcn_s_setprio(0);
}

// ---------------------------------------------------------------------------
// distance chunk GEMM body (K=64), XOR-swizzled conflict-free staging.
// LDS layout: X[k*64 + (col ^ 4*((k>>2)&7))]. smem >= 8192 floats.
// ---------------------------------------------------------------------------
__device__ __forceinline__ void dist_gemm_body(
    const float* __restrict__ ft, const float* __restrict__ sq,
    float* __restrict__ Dnew, int qbNew, int gi, float* __restrict__ smem)
{
    float* As = smem;
    float* Bs = smem + 4096;
    const int ib = gi & 3;
    const int jb = (gi >> 2) & 31;
    const int b  = gi >> 7;
    const int t  = threadIdx.x;
    const int tx = t & 15, ty = t >> 4;
    const float* Ab = ft + ((long)b*N_ + qbNew + (long)ib*64)*64;
    const float* Bb = ft + ((long)b*N_ + (long)jb*64)*64;
    const float* sqb = sq + (long)b*N_;
    #pragma unroll
    for (int m = 0; m < 4; m++) {
        int li = t + m*256; int r = li >> 4; int c4 = li & 15;
        int cs = r ^ ((c4 & 7) << 2);
        float4 av = *(const float4*)(Ab + (long)r*64 + c4*4);
        As[(c4*4+0)*64 + cs] = av.x; As[(c4*4+1)*64 + cs] = av.y;
        As[(c4*4+2)*64 + cs] = av.z; As[(c4*4+3)*64 + cs] = av.w;
        float4 bv = *(const float4*)(Bb + (long)r*64 + c4*4);
        Bs[(c4*4+0)*64 + cs] = bv.x; Bs[(c4*4+1)*64 + cs] = bv.y;
        Bs[(c4*4+2)*64 + cs] = bv.z; Bs[(c4*4+3)*64 + cs] = bv.w;
    }
    __syncthreads();
    float acc[4][4];
    #pragma unroll
    for (int i = 0; i < 4; i++)
        #pragma unroll
        for (int j = 0; j < 4; j++) acc[i][j] = 0.0f;
    #pragma unroll 4
    for (int k = 0; k < 64; k++) {
        int s4 = ((k >> 2) & 7) << 2;
        float4 a  = *(const float4*)&As[k*64 + ((ty*4) ^ s4)];
        float4 b4 = *(const float4*)&Bs[k*64 + ((tx*4) ^ s4)];
        acc[0][0] += a.x*b4.x; acc[0][1] += a.x*b4.y; acc[0][2] += a.x*b4.z; acc[0][3] += a.x*b4.w;
        acc[1][0] += a.y*b4.x; acc[1][1] += a.y*b4.y; acc[1][2] += a.y*b4.z; acc[1][3] += a.y*b4.w;
        acc[2][0] += a.z*b4.x; acc[2][1] += a.z*b4.y; acc[2][2] += a.z*b4.z; acc[2][3] += a.z*b4.w;
        acc[3][0] += a.w*b4.x; acc[3][1] += a.w*b4.y; acc[3][2] += a.w*b4.z; acc[3][3] += a.w*b4.w;
    }
    const int i0 = ib*64 + ty*4;
    const int j0 = jb*64 + tx*4;
    #pragma unroll
    for (int ii = 0; ii < 4; ii++) {
        float sqq = sqb[qbNew + i0 + ii];
        #pragma unroll
        for (int jj = 0; jj < 4; jj++) {
            int r = j0 + jj;
            Dnew[((long)b*CHQ + i0 + ii)*N_ + r] = (sqq - 2.0f*acc[ii][jj]) + sqb[r];
        }
    }
}

// ---------------------------------------------------------------------------
// generic K=64 projection GEMM body (swizzled staging)
// ---------------------------------------------------------------------------
__device__ __forceinline__ void proj64_body(
    int gi, int nIB, int nJB,
    const float* __restrict__ A, long aBatch, int aRow,
    const float* __restrict__ Bw,
    float* __restrict__ C, long cBatch, int cRow, int cCol0,
    int act, const float* __restrict__ sv, const float* __restrict__ tv,
    float* __restrict__ smem)
{
    float* As = smem;
    float* Bs = smem + 4096;
    const int ib = gi % nIB;
    const int jb = (gi / nIB) % nJB;
    const int b  = gi / (nIB*nJB);
    const int t  = threadIdx.x;
    const int tx = t & 15, ty = t >> 4;
    const float* Ab = A + (long)b*aBatch + (long)(ib*64)*aRow;
    #pragma unroll
    for (int m = 0; m < 4; m++) {
        int li = t + m*256; int r = li >> 4; int c4 = li & 15;
        int cs = r ^ ((c4 & 7) << 2);
        float4 av = *(const float4*)(Ab + (long)r*aRow + c4*4);
        As[(c4*4+0)*64 + cs] = av.x; As[(c4*4+1)*64 + cs] = av.y;
        As[(c4*4+2)*64 + cs] = av.z; As[(c4*4+3)*64 + cs] = av.w;
        float4 bv = *(const float4*)(Bw + (long)(jb*64 + r)*64 + c4*4);
        Bs[(c4*4+0)*64 + cs] = bv.x; Bs[(c4*4+1)*64 + cs] = bv.y;
        Bs[(c4*4+2)*64 + cs] = bv.z; Bs[(c4*4+3)*64 + cs] = bv.w;
    }
    __syncthreads();
    float acc[4][4];
    #pragma unroll
    for (int i = 0; i < 4; i++)
        #pragma unroll
        for (int j = 0; j < 4; j++) acc[i][j] = 0.0f;
    #pragma unroll 4
    for (int k = 0; k < 64; k++) {
        int s4 = ((k >> 2) & 7) << 2;
        float4 a  = *(const float4*)&As[k*64 + ((ty*4) ^ s4)];
        float4 b4 = *(const float4*)&Bs[k*64 + ((tx*4) ^ s4)];
        acc[0][0] += a.x*b4.x; acc[0][1] += a.x*b4.y; acc[0][2] += a.x*b4.z; acc[0][3] += a.x*b4.w;
        acc[1][0] += a.y*b4.x; acc[1][1] += a.y*b4.y; acc[1][2] += a.y*b4.z; acc[1][3] += a.y*b4.w;
        acc[2][0] += a.z*b4.x; acc[2][1] += a.z*b4.y; acc[2][2] += a.z*b4.z; acc[2][3] += a.z*b4.w;
        acc[3][0] += a.w*b4.x; acc[3][1] += a.w*b4.y; acc[3][2] += a.w*b4.z; acc[3][3] += a.w*b4.w;
    }
    const int i0 = ib*64 + ty*4;
    const int j0 = jb*64 + tx*4;
    #pragma unroll
    for (int ii = 0; ii < 4; ii++)
        #pragma unroll
        for (int jj = 0; jj < 4; jj++) {
            int j = j0 + jj;
            float vv = acc[ii][jj];
            if (act == 1) vv = fmaxf(sv[j]*vv + tv[j], 0.0f);
            C[(long)b*cBatch + (long)(i0+ii)*cRow + cCol0 + j] = vv;
        }
}

// ---------------------------------------------------------------------------
// select body
// ---------------------------------------------------------------------------
__device__ __forceinline__ void sel_body(
    const float* __restrict__ Dold, int qbOld, int* __restrict__ idxf, int bid)
{
    const int t = threadIdx.x, lane = t & 63, w = t >> 6;
    const int r = bid*4 + w;
    const int b = r >> 8, qi = r & (CHQ-1);
    const float* row = Dold + ((long)b*CHQ + qi) * N_;
    float v[32];
    #pragma unroll
    for (int j = 0; j < 32; j++) v[j] = row[j*64 + lane];
    topk_sel3<32, KG>(v, lane, idxf + ((long)b*N_ + qbOld + qi)*KG);
}

// ---------------------------------------------------------------------------
// edgefuse body (smem: wt 8192 + fused 512)
// ---------------------------------------------------------------------------
__device__ __forceinline__ void edgefuse_body(
    const float* __restrict__ P, const int* __restrict__ idxg, const int* __restrict__ idxf,
    const float* __restrict__ wft, const float* __restrict__ sc,
    float* __restrict__ outf, int bid, float* __restrict__ smem)
{
    float* wt = smem;
    float* fused = smem + 8192;
    const int t = threadIdx.x, lane = t & 63, w = t >> 6;
    for (int i = t; i < 128*64; i += 256) wt[i] = wft[i];
    const int pid = bid*4 + w;
    const int b = pid >> 11, n = pid & (N_-1);
    const float* Prow = P + ((long)b*N_ + n)*256;
    const int* ig  = idxg + ((long)b*N_ + n)*KG;
    const int* ifx = idxf + ((long)b*N_ + n)*KG;
    float gmax = -FLT_MAX, hmax = -FLT_MAX;
    for (int k = 0; k < KG; k++) {
        int idg = ig[k];
        gmax = fmaxf(gmax, P[((long)b*N_ + idg)*256 + lane]);
        int idf = ifx[k];
        hmax = fmaxf(hmax, P[((long)b*N_ + idf)*256 + 128 + lane]);
    }
    float glin = gmax - Prow[lane]       + Prow[64 + lane];
    float hlin = hmax - Prow[128 + lane] + Prow[192 + lane];
    float gv = lrelu_(sc[SC_SGEO + lane]*glin + sc[SC_TGEO + lane]);
    float hv = lrelu_(sc[SC_SFEAT + lane]*hlin + sc[SC_TFEAT + lane]);
    fused[w*128 + lane]      = gv;
    fused[w*128 + 64 + lane] = hv;
    __syncthreads();
    float acc = 0.0f;
    #pragma unroll 8
    for (int c4 = 0; c4 < 32; c4++) {
        float4 f = *(const float4*)&fused[w*128 + c4*4];
        acc += f.x * wt[(c4*4+0)*64 + lane];
        acc += f.y * wt[(c4*4+1)*64 + lane];
        acc += f.z * wt[(c4*4+2)*64 + lane];
        acc += f.w * wt[(c4*4+3)*64 + lane];
    }
    float ov = lrelu_(sc[SC_SFUSE + lane]*acc + sc[SC_TFUSE + lane]);
    outf[((long)b*N_ + n)*64 + lane] = ov;
}

// ---------------------------------------------------------------------------
// gathermax body
// ---------------------------------------------------------------------------
template<int QN, int ROWW, int CO, int MROWS, int SO>
__device__ __forceinline__ void gathermax_body(
    const float* __restrict__ Q, const int* __restrict__ knn, const int* __restrict__ fpsi,
    const float* __restrict__ sv, const float* __restrict__ tv,
    float* __restrict__ outp, int outRow, int bid)
{
    const int t = threadIdx.x, lane = t & 63, w = t >> 6;
    const int pid = bid*4 + w;
    const int b = pid / SO, s = pid % SO;
    const int* ix = knn + ((long)b*SO + s)*NSAMP;
    float mx[QN];
    #pragma unroll
    for (int q = 0; q < QN; q++) mx[q] = -FLT_MAX;
    for (int k = 0; k < NSAMP; k++) {
        int id = ix[k];
        const float* r = Q + ((long)b*MROWS + id)*ROWW;
        #pragma unroll
        for (int q = 0; q < QN; q++) mx[q] = fmaxf(mx[q], r[lane + 64*q]);
    }
    int crow = fpsi[b*SO + s];
    const float* cr = Q + ((long)b*MROWS + crow)*ROWW + CO;
    #pragma unroll
    for (int q = 0; q < QN; q++) {
        int o = lane + 64*q;
        float lin = mx[q] + cr[o];
        float val = fmaxf(sv[o]*lin + tv[o], 0.0f);
        outp[((long)b*SO + s)*outRow + o] = val;
    }
}

// ---------------------------------------------------------------------------
// d1: FPS1(0,256) + geo-knn + dist gemm chunk0
// ---------------------------------------------------------------------------
__global__ void __launch_bounds__(256, 4) k_geo0(
    const float* __restrict__ x, int* __restrict__ idxg,
    int* __restrict__ fps1, float* __restrict__ nx1,
    float* __restrict__ dl1s, float* __restrict__ st,
    const float* __restrict__ ft, const float* __restrict__ sq,
    const float* __restrict__ gsq, float* __restrict__ D0)
{
    __shared__ float smem[8192];
    if (blockIdx.x < (unsigned)B_) {
        fps1_seg_body(x, blockIdx.x, 0, 256, fps1, nx1, dl1s, st, smem);
        return;
    }
    if (blockIdx.x < (unsigned)(B_ + 8192)) {
        knn_gbody<N_,32,KG,true>(x, (long)6*N_, 1, N_, N_,
                                 x, (long)6*N_, 1, N_,
                                 gsq, (long)N_, idxg, blockIdx.x - B_);
        return;
    }
    dist_gemm_body(ft, sq, D0, 0, blockIdx.x - (B_ + 8192), smem);
}

// ---------------------------------------------------------------------------
// chain: FPS1 segment + sel(ci-1) + gemm(ci)
// ---------------------------------------------------------------------------
__global__ void __launch_bounds__(256, 4) k_chain(
    const float* __restrict__ x, const float* __restrict__ ft, const float* __restrict__ sq,
    float* __restrict__ Dnew, int qbNew,
    const float* __restrict__ Dold, int qbOld,
    int* __restrict__ idxf,
    int* __restrict__ fps1, float* __restrict__ nx1,
    float* __restrict__ dl1s, float* __restrict__ st, int i0)
{
    __shared__ float smem[8192];
    if (blockIdx.x < 16u) {
        fps1_seg_body(x, blockIdx.x, i0, 32, fps1, nx1, dl1s, st, smem);
        return;
    }
    if (blockIdx.x < 1040u) {
        sel_body(Dold, qbOld, idxf, blockIdx.x - 16);
        return;
    }
    dist_gemm_body(ft, sq, Dnew, qbNew, blockIdx.x - 1040, smem);
}

// ---------------------------------------------------------------------------
// d9: FPS1(480,32) + sel7 + P projection
// ---------------------------------------------------------------------------
__global__ void __launch_bounds__(256, 4) k_tail9(
    const float* __restrict__ x, const float* __restrict__ ft,
    const float* __restrict__ Dold, int qbOld, int* __restrict__ idxf,
    int* __restrict__ fps1, float* __restrict__ nx1,
    float* __restrict__ dl1s, float* __restrict__ st,
    const float* __restrict__ wpp, float* __restrict__ big)
{
    __shared__ float smem[8192];
    if (blockIdx.x < 16u) {
        fps1_seg_body(x, blockIdx.x, 480, 32, fps1, nx1, dl1s, st, smem);
        return;
    }
    if (blockIdx.x < 1040u) {
        sel_body(Dold, qbOld, idxf, blockIdx.x - 16);
        return;
    }
    proj64_body(blockIdx.x - 1040, 32, 4, ft, (long)N_*64, 64, wpp,
                big, (long)N_*256, 256, 0, 0, nullptr, nullptr, smem);
}

// ---------------------------------------------------------------------------
// d10: FPS2(0,128) + edgefuse + x_skip projection
// ---------------------------------------------------------------------------
__global__ void __launch_bounds__(256, 4) k_tail10(
    const float* __restrict__ nx1, int* __restrict__ fps2, float* __restrict__ nx2,
    float* __restrict__ dl2s, float* __restrict__ st,
    const float* __restrict__ P, const int* __restrict__ idxg, const int* __restrict__ idxf,
    const float* __restrict__ wft, const float* __restrict__ sc, float* __restrict__ outf,
    const float* __restrict__ ft, const float* __restrict__ w2, float* __restrict__ V)
{
    __shared__ float smem[8704];
    if (blockIdx.x < 16u) {
        fps2_seg_body(blockIdx.x, 0, 128, nx1, fps2, nx2, dl2s, st, smem);
        return;
    }
    if (blockIdx.x < (unsigned)(16 + 8192)) {
        edgefuse_body(P, idxg, idxf, wft, sc, outf, blockIdx.x - 16, smem);
        return;
    }
    proj64_body(blockIdx.x - (16 + 8192), 4, 16, ft, (long)N_*64, 512, w2,
                V, (long)NP2*1280, 1280, 256, 1, sc + SC_S2, sc + SC_T2, smem);
}

// ---------------------------------------------------------------------------
// d11: FPS2(128,128) + knn1 + Q0 projection
// ---------------------------------------------------------------------------
__global__ void __launch_bounds__(256, 4) k_tail11(
    const float* __restrict__ nx1, int* __restrict__ fps2, float* __restrict__ nx2,
    float* __restrict__ dl2s, float* __restrict__ st,
    const float* __restrict__ x, const float* __restrict__ gsq, int* __restrict__ idx1,
    const float* __restrict__ outf, const float* __restrict__ wpq0, float* __restrict__ big)
{
    __shared__ float smem[8192];
    if (blockIdx.x < 16u) {
        fps2_seg_body(blockIdx.x, 128, 128, nx1, fps2, nx2, dl2s, st, smem);
        return;
    }
    if (blockIdx.x < (unsigned)(16 + 2048)) {
        knn_gbody<2048,32,32,true>(nx1, (long)NP1*3, 3, 1, NP1,
                                   x, (long)6*N_, (long)1, (long)N_,
                                   gsq, (long)N_, idx1, blockIdx.x - 16);
        return;
    }
    proj64_body(blockIdx.x - (16 + 2048), 32, 4, outf, (long)N_*64, 64, wpq0,
                big, (long)N_*256, 256, 0, 0, nullptr, nullptr, smem);
}

// ---------------------------------------------------------------------------
// d12: gathermax0 + knn2
// ---------------------------------------------------------------------------
__global__ void __launch_bounds__(256, 4) k_gm0knn2(
    const float* __restrict__ big, const int* __restrict__ idx1, const int* __restrict__ fps1,
    const float* __restrict__ sc, float* __restrict__ f0t,
    const float* __restrict__ nx2, const float* __restrict__ nx1, int* __restrict__ idx2)
{
    if (blockIdx.x < 2048u) {
        gathermax_body<2,256,128,2048,512>(big, idx1, fps1,
            sc + SC_SGL0, sc + SC_TGL0, f0t, 128, blockIdx.x);
        return;
    }
    knn_gbody<512,8,32,false>(nx2, (long)NP2*3, 3, 1, NP2,
                              nx1, (long)NP1*3, (long)3, (long)1,
                              nullptr, 0, idx2, blockIdx.x - 2048);
}

// ---------------------------------------------------------------------------
// generic GEMM (Q1 projection K=128, final K=1280), swizzled staging
// ---------------------------------------------------------------------------
__global__ void __launch_bounds__(256) k_gemm(
    const float* __restrict__ A, long aBatch, int aRow,
    const float* __restrict__ Bw, long bBatch, int K,
    float* __restrict__ C, long cBatch, int cRow, int cCol0,
    int act, const float* __restrict__ sv, const float* __restrict__ tv,
    int epi)
{
    __shared__ float As[4096];
    __shared__ float Bs[4096];
    const int b  = blockIdx.z;
    const int ib = blockIdx.x * 64;
    const int jb = blockIdx.y * 64;
    const int t  = threadIdx.x;
    const int tx = t & 15, ty = t >> 4;
    const float* Ab = A + (long)b * aBatch;
    const float* Bb = Bw + (long)b * bBatch;
    float acc[4][4];
    #pragma unroll
    for (int i = 0; i < 4; i++)
        #pragma unroll
        for (int j = 0; j < 4; j++) acc[i][j] = 0.0f;

    for (int kb = 0; kb < K; kb += 64) {
        #pragma unroll
        for (int m = 0; m < 4; m++) {
            int li = t + m*256; int r = li >> 4; int c4 = li & 15;
            int cs = r ^ ((c4 & 7) << 2);
            float4 av = *(const float4*)(Ab + (long)(ib + r)*aRow + kb + c4*4);
            As[(c4*4+0)*64 + cs] = av.x; As[(c4*4+1)*64 + cs] = av.y;
            As[(c4*4+2)*64 + cs] = av.z; As[(c4*4+3)*64 + cs] = av.w;
            float4 bv = *(const float4*)(Bb + (long)(jb + r)*K + kb + c4*4);
            Bs[(c4*4+0)*64 + cs] = bv.x; Bs[(c4*4+1)*64 + cs] = bv.y;
            Bs[(c4*4+2)*64 + cs] = bv.z; Bs[(c4*4+3)*64 + cs] = bv.w;
        }
        __syncthreads();
        #pragma unroll 4
        for (int k = 0; k < 64; k++) {
            int s4 = ((k >> 2) & 7) << 2;
            float4 a  = *(const float4*)&As[k*64 + ((ty*4) ^ s4)];
            float4 b4 = *(const float4*)&Bs[k*64 + ((tx*4) ^ s4)];
            acc[0][0] += a.x*b4.x; acc[0][1] += a.x*b4.y; acc[0][2] += a.x*b4.z; acc[0][3] += a.x*b4.w;
            acc[1][0] += a.y*b4.x; acc[1][1] += a.y*b4.y; acc[1][2] += a.y*b4.z; acc[1][3] += a.y*b4.w;
            acc[2][0] += a.z*b4.x; acc[2][1] += a.z*b4.y; acc[2][2] += a.z*b4.z; acc[2][3] += a.z*b4.w;
            acc[3][0] += a.w*b4.x; acc[3][1] += a.w*b4.y; acc[3][2] += a.w*b4.z; acc[3][3] += a.w*b4.w;
        }
        __syncthreads();
    }

    const int i0 = ib + ty*4;
    const int j0 = jb + tx*4;
    if (epi == 2) {
        #pragma unroll
        for (int ii = 0; ii < 4; ii++)
            #pragma unroll
            for (int jj = 0; jj < 4; jj++) {
                int j = j0 + jj;
                float vv = lrelu_(sv[j]*acc[ii][jj] + tv[j]);
                C[(long)b*cBatch + (long)j*cRow + (i0+ii)] = vv;
            }
    } else {
        #pragma unroll
        for (int ii = 0; ii < 4; ii++)
            #pragma unroll
            for (int jj = 0; jj < 4; jj++) {
                int j = j0 + jj;
                float vv = acc[ii][jj];
                if (act == 1) vv = fmaxf(sv[j]*vv + tv[j], 0.0f);
                else if (act == 2) vv = lrelu_(sv[j]*vv + tv[j]);
                C[(long)b*cBatch + (long)(i0+ii)*cRow + cCol0 + j] = vv;
            }
    }
}

// ---------------------------------------------------------------------------
// standalone gathermax (d14)
// ---------------------------------------------------------------------------
template<int QN, int ROWW, int CO, int MROWS, int SO>
__global__ void __launch_bounds__(256) k_gathermax(
    const float* __restrict__ Q, const int* __restrict__ knn, const int* __restrict__ fpsi,
    const float* __restrict__ sv, const float* __restrict__ tv,
    float* __restrict__ outp, int outRow)
{
    gathermax_body<QN,ROWW,CO,MROWS,SO>(Q, knn, fpsi, sv, tv, outp, outRow, blockIdx.x);
}

// ---------------------------------------------------------------------------
extern "C" void kernel_launch(void* const* d_in, const int* in_sizes, int n_in,
                              void* d_out, int out_size, void* d_ws, size_t ws_size,
                              hipStream_t stream)
{
    const float* x      = (const float*)d_in[0];
    const float* w1     = (const float*)d_in[1];
    const float* bn1    = (const float*)d_in[2];
    const float* w2     = (const float*)d_in[3];
    const float* bn2    = (const float*)d_in[4];
    const float* geow   = (const float*)d_in[5];
    const float* geobn  = (const float*)d_in[6];
    const float* featw  = (const float*)d_in[7];
    const float* featbn = (const float*)d_in[8];
    const float* fusew  = (const float*)d_in[9];
    const float* fusebn = (const float*)d_in[10];
    const float* gl0w   = (const float*)d_in[11];
    const float* gl0bn  = (const float*)d_in[12];
    const float* gl1w   = (const float*)d_in[13];
    const float* gl1bn  = (const float*)d_in[14];
    const float* wf     = (const float*)d_in[15];
    const float* bnfp   = (const float*)d_in[16];

    float* ws  = (float*)d_ws;
    float* out = (float*)d_out;

    float* FT   = ws + OFF_FT;
    float* SQ   = ws + OFF_SQ;
    float* BIG  = ws + OFF_BIG;
    int*   IDXG = (int*)(ws + OFF_IDXG);
    int*   IDXF = (int*)(ws + OFF_IDXF);
    float* OUTF = ws + OFF_OUTF;
    int*   FPS1 = (int*)(ws + OFF_FPS1);
    float* NX1  = ws + OFF_NX1;
    int*   IDX1 = (int*)(ws + OFF_IDX1);
    float* F0T  = ws + OFF_F0T;
    int*   FPS2 = (int*)(ws + OFF_FPS2);
    float* NX2  = ws + OFF_NX2;
    int*   IDX2 = (int*)(ws + OFF_IDX2);
    float* Q1B  = ws + OFF_Q1;
    float* V    = ws + OFF_V;
    float* WPP  = ws + OFF_WPP;
    float* WPQ0 = ws + OFF_WPQ0;
    float* WPQ1 = ws + OFF_WPQ1;
    float* WFT  = ws + OFF_WFT;
    float* SC   = ws + OFF_SC;
    float* DL1  = ws + OFF_DL1;
    float* DL2  = ws + OFF_DL2;
    float* ST   = ws + OFF_ST;
    float* GSQ  = ws + OFF_GSQ;

    hipLaunchKernelGGL(k_prep, dim3(64), dim3(256), 0, stream,
        bn1, bn2, geow, geobn, featw, featbn, fusew, fusebn, gl0w, gl0bn, gl1w, gl1bn, bnfp, ws);

    hipLaunchKernelGGL(k_feat0, dim3(B_*N_/4), dim3(256), 0, stream, x, w1, SC, FT, SQ, GSQ);

    // d1: FPS1 first 256 iters + geo-knn + dist gemm chunk0 -> BIG
    hipLaunchKernelGGL(k_geo0, dim3(B_ + 8192 + 2048), dim3(256), 0, stream,
        x, IDXG, FPS1, NX1, DL1, ST, FT, SQ, GSQ, BIG);

    // d2..d8: {FPS1 seg (32) + sel(ci-1) + gemm(ci)}
    float* bufs[2] = { BIG, Q1B };
    for (int ci = 1; ci < 8; ci++) {
        hipLaunchKernelGGL(k_chain, dim3(16 + 1024 + 2048), dim3(256), 0, stream,
            x, FT, SQ,
            bufs[ci & 1], ci*CHQ,
            bufs[(ci - 1) & 1], (ci - 1)*CHQ,
            IDXF, FPS1, NX1, DL1, ST, 256 + 32*(ci - 1));
    }

    // d9: FPS1 last 32 + sel7 + P projection -> BIG
    hipLaunchKernelGGL(k_tail9, dim3(16 + 1024 + 2048), dim3(256), 0, stream,
        x, FT, bufs[1], 7*CHQ, IDXF, FPS1, NX1, DL1, ST, WPP, BIG);

    // d10: FPS2 seg0 + edgefuse + x_skip
    hipLaunchKernelGGL(k_tail10, dim3(16 + 8192 + 1024), dim3(256), 0, stream,
        NX1, FPS2, NX2, DL2, ST,
        BIG, IDXG, IDXF, WFT, SC, OUTF,
        FT, w2, V);

    // d11: FPS2 seg1 + knn1 + Q0 projection -> BIG
    hipLaunchKernelGGL(k_tail11, dim3(16 + 2048 + 2048), dim3(256), 0, stream,
        NX1, FPS2, NX2, DL2, ST,
        x, GSQ, IDX1,
        OUTF, WPQ0, BIG);

    // d12: gathermax0 + knn2
    hipLaunchKernelGGL(k_gm0knn2, dim3(2048 + 1024), dim3(256), 0, stream,
        BIG, IDX1, FPS1, SC, F0T, NX2, NX1, IDX2);

    // d13: Q1 projection (K=128)
    hipLaunchKernelGGL(k_gemm, dim3(NP1/64, 512/64, B_), dim3(256), 0, stream,
        F0T, (long)NP1*128, 128, WPQ1, (long)0, 128,
        Q1B, (long)NP1*512, 512, 0, 0, nullptr, nullptr, 0);

    // d14: gathermax1
    hipLaunchKernelGGL((k_gathermax<4,512,256,512,256>), dim3(B_*NP2/4), dim3(256), 0, stream,
        Q1B, IDX2, FPS2, SC + SC_SGL1, SC + SC_TGL1, V, 1280);

    // d15: final (B,512,256) = lrelu(bnf(wf . V^T)), transposed store
    hipLaunchKernelGGL(k_gemm, dim3(NP2/64, 512/64, B_), dim3(256), 0, stream,
        V, (long)NP2*1280, 1280, wf, (long)0, 1280,
        out, (long)512*256, 256, 0, 2, SC + SC_SF, SC + SC_TF, 2);

    (void)in_sizes; (void)n_in; (void)out_size; (void)ws_size;
}

// Round 17
// 621.452 us; speedup vs baseline: 11.4547x; 1.0628x over previous
//
#include <hip/hip_runtime.h>
#include <float.h>
#include <math.h>

// ---------------------------------------------------------------------------
// SSFE_Net pipeline on MI355X. B=16, N=2048.
// R15: swizzled GEMM staging + gsq. 660us; k_geo0 VALU-issue-bound (78%).
// R16: knn instruction diet: (a) packed xyz4{x,y,z,gsq} refs -> 1 dwordx4/ref,
//      compile-time strides; (b) topk reduce = pure-DPP min ladder + readlane
//      (no ds_swizzle in serial chain); (c) top-3 cache (rescans ~0.3/query) +
//      batched index store; (d) prep+feat0 merged (feat0 self-computes bn1).
// ---------------------------------------------------------------------------

static constexpr int B_   = 16;
static constexpr int N_   = 2048;
static constexpr int NP1  = 512;
static constexpr int NP2  = 256;
static constexpr int KG   = 20;
static constexpr int NSAMP= 32;
static constexpr int CHQ  = 256;

// workspace offsets (in float elements)
static constexpr long OFF_FT   = 0;
static constexpr long OFF_SQ   = OFF_FT   + (long)B_*N_*64;
static constexpr long OFF_BIG  = OFF_SQ   + (long)B_*N_;          // D chunk A / P / Q0
static constexpr long OFF_IDXG = OFF_BIG  + (long)B_*N_*256;
static constexpr long OFF_IDXF = OFF_IDXG + (long)B_*N_*KG;
static constexpr long OFF_OUTF = OFF_IDXF + (long)B_*N_*KG;
static constexpr long OFF_FPS1 = OFF_OUTF + (long)B_*N_*64;
static constexpr long OFF_NX1  = OFF_FPS1 + (long)B_*NP1;
static constexpr long OFF_IDX1 = OFF_NX1  + (long)B_*NP1*3;
static constexpr long OFF_F0T  = OFF_IDX1 + (long)B_*NP1*NSAMP;
static constexpr long OFF_FPS2 = OFF_F0T  + (long)B_*NP1*128;
static constexpr long OFF_NX2  = OFF_FPS2 + (long)B_*NP2;
static constexpr long OFF_IDX2 = OFF_NX2  + (long)B_*NP2*3;
static constexpr long OFF_Q1   = OFF_IDX2 + (long)B_*NP2*NSAMP;  // D chunk B (Q1+V)
static constexpr long OFF_V    = OFF_Q1   + (long)B_*NP1*512;
static constexpr long OFF_WPP  = OFF_V    + (long)B_*NP2*1280;
static constexpr long OFF_WPQ0 = OFF_WPP  + 256*64;
static constexpr long OFF_WPQ1 = OFF_WPQ0 + 256*64;
static constexpr long OFF_WFT  = OFF_WPQ1 + 512*128;
static constexpr long OFF_SC   = OFF_WFT  + 128*64;
static constexpr long OFF_DL1  = OFF_SC   + 4352;               // FPS1 dl state
static constexpr long OFF_DL2  = OFF_DL1  + (long)B_*256*8;     // FPS2 dl state
static constexpr long OFF_ST   = OFF_DL2  + (long)B_*512;       // far/centroid state
static constexpr long OFF_XYZ4 = OFF_ST   + 256;                // packed {x,y,z,gsq} B*N*4

// SC (bn scale/shift) sub-offsets
static constexpr int SC_S1=0, SC_T1=64, SC_SGEO=128, SC_TGEO=192, SC_SFEAT=256, SC_TFEAT=320,
   SC_SFUSE=384, SC_TFUSE=448, SC_SGL0=512, SC_TGL0=640, SC_SGL1=768, SC_TGL1=1024,
   SC_S2=1280, SC_T2=2304, SC_SF=3328, SC_TF=3840;

__device__ __forceinline__ float lrelu_(float x) { return x >= 0.0f ? x : 0.2f * x; }

// masked DPP max step
template<int CTRL, int RM>
__device__ __forceinline__ float dpp_maxm(float v) {
    int o = __builtin_amdgcn_update_dpp(__float_as_int(v), __float_as_int(v),
                                        CTRL, RM, 0xF, false);
    return fmaxf(v, __int_as_float(o));
}
__device__ __forceinline__ float wave_max64_sgpr(float v) {
    v = dpp_maxm<0xB1, 0xF>(v);
    v = dpp_maxm<0x4E, 0xF>(v);
    v = dpp_maxm<0x141,0xF>(v);
    v = dpp_maxm<0x140,0xF>(v);
    v = dpp_maxm<0x142,0xA>(v);
    v = dpp_maxm<0x143,0xC>(v);
    return __int_as_float(__builtin_amdgcn_readlane(__float_as_int(v), 63));
}

// masked DPP unsigned-min step
template<int CTRL, int RM>
__device__ __forceinline__ unsigned dpp_minm(unsigned x) {
    unsigned o = (unsigned)__builtin_amdgcn_update_dpp((int)x, (int)x, CTRL, RM, 0xF, false);
    return o < x ? o : x;
}
// pure-VALU wave64 unsigned min -> uniform SGPR value (no ds ops).
__device__ __forceinline__ unsigned wave_minu_sgpr(unsigned x) {
    x = dpp_minm<0xB1, 0xF>(x);
    x = dpp_minm<0x4E, 0xF>(x);
    x = dpp_minm<0x141,0xF>(x);
    x = dpp_minm<0x140,0xF>(x);
    x = dpp_minm<0x142,0xA>(x);
    x = dpp_minm<0x143,0xC>(x);
    return (unsigned)__builtin_amdgcn_readlane((int)x, 63);
}

__device__ __forceinline__ unsigned sortable_(float f) {
    unsigned u = __float_as_uint(f);
    return u ^ ((unsigned)((int)u >> 31) | 0x80000000u);
}

// ---------------------------------------------------------------------------
// prep body (bid in [0,64))
// ---------------------------------------------------------------------------
__device__ __forceinline__ void prep_body(
    const float* bn1, const float* bn2,
    const float* geow, const float* geobn,
    const float* featw, const float* featbn,
    const float* fusew, const float* fusebn,
    const float* gl0w, const float* gl0bn,
    const float* gl1w, const float* gl1bn,
    const float* bnfp, float* ws, int bid)
{
    const int tid = bid * 256 + threadIdx.x;
    const int nt  = 64 * 256;
    float* sc = ws + OFF_SC;
    {
        const float* ps[8]  = {bn1, geobn, featbn, fusebn, gl0bn, gl1bn, bn2, bnfp};
        const int    ch[8]  = {64, 64, 64, 64, 128, 256, 1024, 512};
        const int    so[8]  = {SC_S1, SC_SGEO, SC_SFEAT, SC_SFUSE, SC_SGL0, SC_SGL1, SC_S2, SC_SF};
        const int    to[8]  = {SC_T1, SC_TGEO, SC_TFEAT, SC_TFUSE, SC_TGL0, SC_TGL1, SC_T2, SC_TF};
        for (int g = 0; g < 8; g++) {
            const float* p = ps[g]; int C = ch[g];
            for (int i = tid; i < C; i += nt) {
                float gg = p[i], bb = p[C+i], mm = p[2*C+i], vv = p[3*C+i];
                float s = gg * (1.0f / sqrtf(vv + 1e-5f));
                sc[so[g] + i] = s;
                sc[to[g] + i] = bb - mm * s;
            }
        }
    }
    for (int j = tid; j < 256*64; j += nt) {
        int o = j >> 6, c = j & 63; float v;
        if      (o < 64)  v = geow[o*128 + c];
        else if (o < 128) v = geow[(o-64)*128 + 64 + c];
        else if (o < 192) v = featw[(o-128)*128 + c];
        else              v = featw[(o-192)*128 + 64 + c];
        ws[OFF_WPP + j] = v;
    }
    for (int j = tid; j < 256*64; j += nt) {
        int o = j >> 6, c = j & 63; float v;
        if (o < 128) v = gl0w[o*128 + c];
        else         v = gl0w[(o-128)*128 + 64 + c] - gl0w[(o-128)*128 + c];
        ws[OFF_WPQ0 + j] = v;
    }
    for (int j = tid; j < 512*128; j += nt) {
        int o = j >> 7, c = j & 127; float v;
        if (o < 256) v = gl1w[o*256 + c];
        else         v = gl1w[(o-256)*256 + 128 + c] - gl1w[(o-256)*256 + c];
        ws[OFF_WPQ1 + j] = v;
    }
    for (int j = tid; j < 128*64; j += nt) {
        int c = j >> 6, o = j & 63;
        ws[OFF_WFT + j] = fusew[o*128 + c];
    }
}

// ---------------------------------------------------------------------------
// feat0 body (bid in [0,8192)); self-computes bn1 consts; writes xyz4{x,y,z,gsq}
// ---------------------------------------------------------------------------
__device__ __forceinline__ void feat0_body(
    const float* __restrict__ x, const float* __restrict__ w1,
    const float* __restrict__ bn1,
    float* __restrict__ ft, float* __restrict__ sq,
    float4* __restrict__ xyz4, int bid)
{
    const int t = threadIdx.x, lane = t & 63, w = t >> 6;
    const int pid = bid*4 + w;
    const int b = pid >> 11, n = pid & (N_-1);
    const float* xb = x + (long)b*6*N_ + n;
    float acc = 0.0f;
    #pragma unroll
    for (int c = 0; c < 6; c++) acc += w1[lane*6 + c] * xb[(long)c*N_];
    // bn1 consts computed locally (exact same formula as prep)
    float gg = bn1[lane], bb = bn1[64+lane], mm = bn1[128+lane], vv = bn1[192+lane];
    float s = gg * (1.0f / sqrtf(vv + 1e-5f));
    float tt = bb - mm * s;
    float val = fmaxf(s*acc + tt, 0.0f);
    ft[((long)b*N_ + n)*64 + lane] = val;
    float v2 = val*val;
    #pragma unroll
    for (int sft = 1; sft < 64; sft <<= 1) v2 += __shfl_xor(v2, sft);
    if (lane == 0) {
        sq[b*N_ + n] = v2;
        float rx = xb[0], ry = xb[N_], rz = xb[2*N_];
        float g2 = __fadd_rn(__fadd_rn(__fmul_rn(rx,rx), __fmul_rn(ry,ry)), __fmul_rn(rz,rz));
        xyz4[(long)b*N_ + n] = make_float4(rx, ry, rz, g2);
    }
}

__global__ void __launch_bounds__(256) k_init(
    const float* __restrict__ x, const float* __restrict__ w1,
    const float* bn1, const float* bn2,
    const float* geow, const float* geobn,
    const float* featw, const float* featbn,
    const float* fusew, const float* fusebn,
    const float* gl0w, const float* gl0bn,
    const float* gl1w, const float* gl1bn,
    const float* bnfp, float* ws,
    float* __restrict__ ft, float* __restrict__ sq, float4* __restrict__ xyz4)
{
    if (blockIdx.x < 64u) {
        prep_body(bn1, bn2, geow, geobn, featw, featbn, fusew, fusebn,
                  gl0w, gl0bn, gl1w, gl1bn, bnfp, ws, blockIdx.x);
        return;
    }
    feat0_body(x, w1, bn1, ft, sq, xyz4, blockIdx.x - 64);
}

// ---------------------------------------------------------------------------
// topk_sel4: k smallest (stable first-index ties), index = j*64+lane.
// Top-3 per-lane cache + consumed bitmask; pure-DPP min reduce (SGPR);
// batched index store (lane<KSEL writes keep).
// ---------------------------------------------------------------------------
template<int RPL, int KSEL>
__device__ __forceinline__ void topk_sel4(float (&v)[RPL], int lane, int* __restrict__ out)
{
    unsigned key[RPL];
    #pragma unroll
    for (int j = 0; j < RPL; j++) key[j] = sortable_(v[j]);

    unsigned consumed = 0;
    unsigned m1 = 0xFFFFFFFFu, m2 = 0xFFFFFFFFu, m3 = 0xFFFFFFFFu;
    int s1 = 0, s2 = 0, s3 = 0;
    #pragma unroll
    for (int j = 0; j < RPL; j++) {
        unsigned kk = key[j];
        bool lt1 = kk < m1, lt2 = kk < m2, lt3 = kk < m3;
        unsigned nm3 = lt2 ? m2 : (lt3 ? kk : m3);
        int      ns3 = lt2 ? s2 : (lt3 ? j  : s3);
        unsigned nm2 = lt1 ? m1 : (lt2 ? kk : m2);
        int      ns2 = lt1 ? s1 : (lt2 ? j  : s2);
        m1 = lt1 ? kk : m1;
        s1 = lt1 ? j  : s1;
        m2 = nm2; s2 = ns2; m3 = nm3; s3 = ns3;
    }

    int keep = 0;
    #pragma unroll 1
    for (int k = 0; k < KSEL; k++) {
        unsigned g = wave_minu_sgpr(m1);
        unsigned long long cand = __ballot(m1 == g);
        int gi;
        if (__popcll(cand) > 1) {
            // exact value tie across lanes: min global index (rare, exact)
            int ci = (m1 == g) ? (s1*64 + lane) : 0x7FFFFFFF;
            #pragma unroll
            for (int s = 1; s < 64; s <<= 1) { int o = __shfl_xor(ci, s); ci = o < ci ? o : ci; }
            gi = ci;
        } else {
            int wl = __ffsll((long long)cand) - 1;
            gi = __builtin_amdgcn_readlane(s1, wl) * 64 + wl;
        }
        keep = (lane == k) ? gi : keep;
        if (k + 1 < KSEL) {
            bool win = (m1 == g) && (s1*64 + lane == gi);
            if (win) {
                consumed |= 1u << s1;
                m1 = m2; s1 = s2;
                m2 = m3; s2 = s3;
                m3 = 0xFFFFFFFFu;
            }
            bool need = win && (m1 == 0xFFFFFFFFu);
            if (__any(need)) {
                if (need) {
                    m1 = 0xFFFFFFFFu; m2 = 0xFFFFFFFFu; m3 = 0xFFFFFFFFu;
                    s1 = 0; s2 = 0; s3 = 0;
                    #pragma unroll
                    for (int j = 0; j < RPL; j++) {
                        unsigned kk = ((consumed >> j) & 1u) ? 0xFFFFFFFFu : key[j];
                        bool lt1 = kk < m1, lt2 = kk < m2, lt3 = kk < m3;
                        unsigned nm3 = lt2 ? m2 : (lt3 ? kk : m3);
                        int      ns3 = lt2 ? s2 : (lt3 ? j  : s3);
                        unsigned nm2 = lt1 ? m1 : (lt2 ? kk : m2);
                        int      ns2 = lt1 ? s1 : (lt2 ? j  : s2);
                        m1 = lt1 ? kk : m1;
                        s1 = lt1 ? j  : s1;
                        m2 = nm2; s2 = ns2; m3 = nm3; s3 = ns3;
                    }
                }
            }
        }
    }
    if (lane < KSEL) out[lane] = keep;
}

// ---------------------------------------------------------------------------
// knn over packed xyz4 refs (1 dwordx4/ref, compile-time stride).
// QX4: query from xyz4 (geo self-knn); else from qp (stride-3 float rows).
// ---------------------------------------------------------------------------
template<int RPL, int KSEL, bool QX4>
__device__ __forceinline__ void knn_x4body(
    const float4* __restrict__ xyz4, int NQ,
    const float* __restrict__ qp, long qBatch, int qsN,
    int* __restrict__ out, int bid)
{
    const int t = threadIdx.x, lane = t & 63, w = t >> 6;
    const int bpb = NQ / 4;
    const int b = bid / bpb;
    const int qi = (bid % bpb)*4 + w;
    const float4* rb = xyz4 + (long)b*N_;
    float qx, qy, qz, sumq;
    if constexpr (QX4) {
        float4 q = rb[qi];
        qx = q.x; qy = q.y; qz = q.z; sumq = q.w;
    } else {
        const float* qb = qp + (long)b*qBatch + (long)qi*qsN;
        qx = qb[0]; qy = qb[1]; qz = qb[2];
        sumq = __fadd_rn(__fadd_rn(__fmul_rn(qx,qx), __fmul_rn(qy,qy)), __fmul_rn(qz,qz));
    }
    float v[RPL];
    #pragma unroll
    for (int j = 0; j < RPL; j++) {
        float4 r = rb[j*64 + lane];
        float dot = __fadd_rn(__fadd_rn(__fmul_rn(qx,r.x), __fmul_rn(qy,r.y)), __fmul_rn(qz,r.z));
        v[j] = __fadd_rn(__fsub_rn(sumq, __fmul_rn(2.0f, dot)), r.w);
    }
    topk_sel4<RPL, KSEL>(v, lane, out + ((long)b*NQ + qi)*KSEL);
}

// knn with strided refs (knn2: refs = NX1 stride-3)
template<int RPL, int KSEL>
__device__ __forceinline__ void knn_gbody(
    const float* qp, long qBatch, int qsN, int NQ,
    const float* rp, long rBatch, int rsN,
    int* out, int bid)
{
    const int t = threadIdx.x, lane = t & 63, w = t >> 6;
    const int bpb = NQ / 4;
    const int b = bid / bpb;
    const int qi = (bid % bpb)*4 + w;
    const float* rb = rp + (long)b*rBatch;
    const float* qb = qp + (long)b*qBatch + (long)qi*qsN;
    float qx = qb[0], qy = qb[1], qz = qb[2];
    float sumq = __fadd_rn(__fadd_rn(__fmul_rn(qx,qx), __fmul_rn(qy,qy)), __fmul_rn(qz,qz));
    float v[RPL];
    #pragma unroll
    for (int j = 0; j < RPL; j++) {
        long n = j*64 + lane;
        float rx = rb[n*rsN], ry = rb[n*rsN + 1], rz = rb[n*rsN + 2];
        float dot = __fadd_rn(__fadd_rn(__fmul_rn(qx,rx), __fmul_rn(qy,ry)), __fmul_rn(qz,rz));
        float sumr = __fadd_rn(__fadd_rn(__fmul_rn(rx,rx), __fmul_rn(ry,ry)), __fmul_rn(rz,rz));
        v[j] = __fadd_rn(__fsub_rn(sumq, __fmul_rn(2.0f, dot)), sumr);
    }
    topk_sel4<RPL, KSEL>(v, lane, out + ((long)b*NQ + qi)*KSEL);
}

// ---------------------------------------------------------------------------
// FPS1 segment (unchanged)
// ---------------------------------------------------------------------------
__device__ __forceinline__ void fps1_seg_body(
    const float* __restrict__ x, int b, int i0, int cnt,
    int* __restrict__ fps1, float* __restrict__ nx1,
    float* __restrict__ dl1s, float* __restrict__ st, float* __restrict__ smem)
{
    __builtin_amdgcn_s_setprio(3);
    const int t = threadIdx.x, lane = t & 63, wave = t >> 6;
    const float* pb = x + (long)b*6*N_;

    float4* mrgc   = (float4*)smem;
    int*    mrgi   = (int*)(smem + 32);
    int*    sidxsg = (int*)(smem + 40);
    float*  mxsg   = smem + 296;
    float*  mysg   = smem + 552;
    float*  mzsg   = smem + 808;

    float px[8], py[8], pz[8], dl[8];
    {
        const float4* a4  = (const float4*)(pb + 8*t);
        const float4* b4  = (const float4*)(pb + N_ + 8*t);
        const float4* c4p = (const float4*)(pb + 2*N_ + 8*t);
        float4 a0 = a4[0], a1 = a4[1];
        float4 b0 = b4[0], b1 = b4[1];
        float4 c0 = c4p[0], c1 = c4p[1];
        px[0]=a0.x; px[1]=a0.y; px[2]=a0.z; px[3]=a0.w;
        px[4]=a1.x; px[5]=a1.y; px[6]=a1.z; px[7]=a1.w;
        py[0]=b0.x; py[1]=b0.y; py[2]=b0.z; py[3]=b0.w;
        py[4]=b1.x; py[5]=b1.y; py[6]=b1.z; py[7]=b1.w;
        pz[0]=c0.x; pz[1]=c0.y; pz[2]=c0.z; pz[3]=c0.w;
        pz[4]=c1.x; pz[5]=c1.y; pz[6]=c1.z; pz[7]=c1.w;
    }
    int far; float cx, cy, cz;
    if (i0 == 0) {
        #pragma unroll
        for (int p = 0; p < 8; p++) dl[p] = 1e10f;
        far = 0; cx = pb[0]; cy = pb[N_]; cz = pb[2*N_];
    } else {
        const float4* ds = (const float4*)(dl1s + ((long)b*256 + t)*8);
        float4 d0 = ds[0], d1 = ds[1];
        dl[0]=d0.x; dl[1]=d0.y; dl[2]=d0.z; dl[3]=d0.w;
        dl[4]=d1.x; dl[5]=d1.y; dl[6]=d1.z; dl[7]=d1.w;
        far = __float_as_int(st[b*16+0]);
        cx = st[b*16+1]; cy = st[b*16+2]; cz = st[b*16+3];
    }

    for (int k = 0; k < cnt; k++) {
        if (t == 0) { sidxsg[k] = far; mxsg[k] = cx; mysg[k] = cy; mzsg[k] = cz; }
        float bv = -1.0f; int bp = 0;
        #pragma unroll
        for (int p = 0; p < 8; p++) {
            float dx = __fsub_rn(px[p], cx);
            float dy = __fsub_rn(py[p], cy);
            float dz = __fsub_rn(pz[p], cz);
            float d  = __fadd_rn(__fadd_rn(__fmul_rn(dx,dx), __fmul_rn(dy,dy)), __fmul_rn(dz,dz));
            float nd = fminf(dl[p], d);
            dl[p] = nd;
            if (nd > bv) { bv = nd; bp = p; }
        }
        float wx = px[0], wy = py[0], wz = pz[0];
        #pragma unroll
        for (int p = 1; p < 8; p++) {
            bool c = (bp == p);
            wx = c ? px[p] : wx; wy = c ? py[p] : wy; wz = c ? pz[p] : wz;
        }
        float gm = wave_max64_sgpr(bv);
        unsigned long long cand = __ballot(bv == gm);
        int wl = __ffsll((long long)cand) - 1;
        int   wbp = __builtin_amdgcn_readlane(bp, wl);
        float sxw = __int_as_float(__builtin_amdgcn_readlane(__float_as_int(wx), wl));
        float syw = __int_as_float(__builtin_amdgcn_readlane(__float_as_int(wy), wl));
        float szw = __int_as_float(__builtin_amdgcn_readlane(__float_as_int(wz), wl));
        int par = k & 1;
        if (lane == 0) {
            mrgc[par*4 + wave] = make_float4(sxw, syw, szw, gm);
            mrgi[par*4 + wave] = (((wave << 6) | wl) << 3) + wbp;
        }
        __syncthreads();
        float4 e0 = mrgc[par*4 + 0];
        float fv = e0.w; int fi = mrgi[par*4 + 0];
        float ncx = e0.x, ncy = e0.y, ncz = e0.z;
        #pragma unroll
        for (int w2 = 1; w2 < 4; w2++) {
            float4 e2 = mrgc[par*4 + w2]; int i2 = mrgi[par*4 + w2];
            if (e2.w > fv) { fv = e2.w; fi = i2; ncx = e2.x; ncy = e2.y; ncz = e2.z; }
        }
        far = fi; cx = ncx; cy = ncy; cz = ncz;
    }
    __syncthreads();

    int*   f1o = fps1 + b*NP1;
    float* n1o = nx1 + (long)b*NP1*3;
    for (int s = t; s < cnt; s += 256) {
        f1o[i0+s] = sidxsg[s];
        n1o[(long)(i0+s)*3+0] = mxsg[s];
        n1o[(long)(i0+s)*3+1] = mysg[s];
        n1o[(long)(i0+s)*3+2] = mzsg[s];
    }
    float4* ds = (float4*)(dl1s + ((long)b*256 + t)*8);
    ds[0] = make_float4(dl[0], dl[1], dl[2], dl[3]);
    ds[1] = make_float4(dl[4], dl[5], dl[6], dl[7]);
    if (t == 0) {
        st[b*16+0] = __int_as_float(far);
        st[b*16+1] = cx; st[b*16+2] = cy; st[b*16+3] = cz;
    }
    __builtin_amdgcn_s_setprio(0);
}

// ---------------------------------------------------------------------------
// FPS2 segment (unchanged)
// ---------------------------------------------------------------------------
__device__ __forceinline__ void fps2_seg_body(
    int b, int i0, int cnt,
    const float* __restrict__ nx1, int* __restrict__ fps2, float* __restrict__ nx2,
    float* __restrict__ dl2s, float* __restrict__ st, float* __restrict__ smem)
{
    __builtin_amdgcn_s_setprio(3);
    const int t = threadIdx.x, lane = t & 63, wave = t >> 6;
    float4* mrgc   = (float4*)smem;
    int*    mrgi   = (int*)(smem + 32);
    int*    sidxsg = (int*)(smem + 40);
    float*  mx2    = smem + 168;
    float*  my2    = smem + 680;
    float*  mz2    = smem + 1192;

    const float* n1 = nx1 + (long)b*NP1*3;
    for (int s = t; s < NP1; s += 256) {
        mx2[s] = n1[(long)s*3+0];
        my2[s] = n1[(long)s*3+1];
        mz2[s] = n1[(long)s*3+2];
    }
    __syncthreads();

    const int n0 = t << 1;
    float ax = mx2[n0],   ay = my2[n0],   az = mz2[n0];
    float bx = mx2[n0+1], by = my2[n0+1], bz = mz2[n0+1];
    float dl0, dl1; int far2; float c2x, c2y, c2z;
    if (i0 == 0) {
        dl0 = dl1 = 1e10f; far2 = 0;
        c2x = mx2[0]; c2y = my2[0]; c2z = mz2[0];
    } else {
        dl0 = dl2s[(long)b*512 + n0];
        dl1 = dl2s[(long)b*512 + n0 + 1];
        far2 = __float_as_int(st[b*16+4]);
        c2x = st[b*16+5]; c2y = st[b*16+6]; c2z = st[b*16+7];
    }

    for (int k = 0; k < cnt; k++) {
        if (t == 0) sidxsg[k] = far2;
        float dx = __fsub_rn(ax, c2x), dy = __fsub_rn(ay, c2y), dz = __fsub_rn(az, c2z);
        float d0 = __fadd_rn(__fadd_rn(__fmul_rn(dx,dx), __fmul_rn(dy,dy)), __fmul_rn(dz,dz));
        dx = __fsub_rn(bx, c2x); dy = __fsub_rn(by, c2y); dz = __fsub_rn(bz, c2z);
        float d1 = __fadd_rn(__fadd_rn(__fmul_rn(dx,dx), __fmul_rn(dy,dy)), __fmul_rn(dz,dz));
        dl0 = fminf(dl0, d0);
        dl1 = fminf(dl1, d1);
        float bv = dl0; int bp = 0;
        if (dl1 > bv) { bv = dl1; bp = 1; }
        float wx = bp ? bx : ax, wy = bp ? by : ay, wz = bp ? bz : az;
        float gm = wave_max64_sgpr(bv);
        unsigned long long cand = __ballot(bv == gm);
        int wl = __ffsll((long long)cand) - 1;
        int   wbp = __builtin_amdgcn_readlane(bp, wl);
        float sxw = __int_as_float(__builtin_amdgcn_readlane(__float_as_int(wx), wl));
        float syw = __int_as_float(__builtin_amdgcn_readlane(__float_as_int(wy), wl));
        float szw = __int_as_float(__builtin_amdgcn_readlane(__float_as_int(wz), wl));
        int par = k & 1;
        if (lane == 0) {
            mrgc[par*4 + wave] = make_float4(sxw, syw, szw, gm);
            mrgi[par*4 + wave] = (((wave << 6) | wl) << 1) + wbp;
        }
        __syncthreads();
        float4 e0 = mrgc[par*4 + 0];
        float fv = e0.w; int fi = mrgi[par*4 + 0];
        float ncx = e0.x, ncy = e0.y, ncz = e0.z;
        #pragma unroll
        for (int w2 = 1; w2 < 4; w2++) {
            float4 e2 = mrgc[par*4 + w2]; int i2 = mrgi[par*4 + w2];
            if (e2.w > fv) { fv = e2.w; fi = i2; ncx = e2.x; ncy = e2.y; ncz = e2.z; }
        }
        far2 = fi; c2x = ncx; c2y = ncy; c2z = ncz;
    }
    __syncthreads();

    int*   f2o = fps2 + b*NP2;
    float* n2o = nx2 + (long)b*NP2*3;
    for (int s = t; s < cnt; s += 256) {
        int j = sidxsg[s];
        f2o[i0+s] = j;
        n2o[(long)(i0+s)*3+0] = mx2[j];
        n2o[(long)(i0+s)*3+1] = my2[j];
        n2o[(long)(i0+s)*3+2] = mz2[j];
    }
    dl2s[(long)b*512 + n0]     = dl0;
    dl2s[(long)b*512 + n0 + 1] = dl1;
    if (t == 0) {
        st[b*16+4] = __int_as_float(far2);
        st[b*16+5] = c2x; st[b*16+6] = c2y; st[b*16+7] = c2z;
    }
    __builtin_amdgcn_s_setprio(0);
}

// ---------------------------------------------------------------------------
// distance chunk GEMM body (K=64), swizzled staging
// ---------------------------------------------------------------------------
__device__ __forceinline__ void dist_gemm_body(
    const float* __restrict__ ft, const float* __restrict__ sq,
    float* __restrict__ Dnew, int qbNew, int gi, float* __restrict__ smem)
{
    float* As = smem;
    float* Bs = smem + 4096;
    const int ib = gi & 3;
    const int jb = (gi >> 2) & 31;
    const int b  = gi >> 7;
    const int t  = threadIdx.x;
    const int tx = t & 15, ty = t >> 4;
    const float* Ab = ft + ((long)b*N_ + qbNew + (long)ib*64)*64;
    const float* Bb = ft + ((long)b*N_ + (long)jb*64)*64;
    const float* sqb = sq + (long)b*N_;
    #pragma unroll
    for (int m = 0; m < 4; m++) {
        int li = t + m*256; int r = li >> 4; int c4 = li & 15;
        int cs = r ^ ((c4 & 7) << 2);
        float4 av = *(const float4*)(Ab + (long)r*64 + c4*4);
        As[(c4*4+0)*64 + cs] = av.x; As[(c4*4+1)*64 + cs] = av.y;
        As[(c4*4+2)*64 + cs] = av.z; As[(c4*4+3)*64 + cs] = av.w;
        float4 bv = *(const float4*)(Bb + (long)r*64 + c4*4);
        Bs[(c4*4+0)*64 + cs] = bv.x; Bs[(c4*4+1)*64 + cs] = bv.y;
        Bs[(c4*4+2)*64 + cs] = bv.z; Bs[(c4*4+3)*64 + cs] = bv.w;
    }
    __syncthreads();
    float acc[4][4];
    #pragma unroll
    for (int i = 0; i < 4; i++)
        #pragma unroll
        for (int j = 0; j < 4; j++) acc[i][j] = 0.0f;
    #pragma unroll 4
    for (int k = 0; k < 64; k++) {
        int s4 = ((k >> 2) & 7) << 2;
        float4 a  = *(const float4*)&As[k*64 + ((ty*4) ^ s4)];
        float4 b4 = *(const float4*)&Bs[k*64 + ((tx*4) ^ s4)];
        acc[0][0] += a.x*b4.x; acc[0][1] += a.x*b4.y; acc[0][2] += a.x*b4.z; acc[0][3] += a.x*b4.w;
        acc[1][0] += a.y*b4.x; acc[1][1] += a.y*b4.y; acc[1][2] += a.y*b4.z; acc[1][3] += a.y*b4.w;
        acc[2][0] += a.z*b4.x; acc[2][1] += a.z*b4.y; acc[2][2] += a.z*b4.z; acc[2][3] += a.z*b4.w;
        acc[3][0] += a.w*b4.x; acc[3][1] += a.w*b4.y; acc[3][2] += a.w*b4.z; acc[3][3] += a.w*b4.w;
    }
    const int i0 = ib*64 + ty*4;
    const int j0 = jb*64 + tx*4;
    #pragma unroll
    for (int ii = 0; ii < 4; ii++) {
        float sqq = sqb[qbNew + i0 + ii];
        #pragma unroll
        for (int jj = 0; jj < 4; jj++) {
            int r = j0 + jj;
            Dnew[((long)b*CHQ + i0 + ii)*N_ + r] = (sqq - 2.0f*acc[ii][jj]) + sqb[r];
        }
    }
}

// ---------------------------------------------------------------------------
// generic K=64 projection GEMM body (swizzled staging)
// ---------------------------------------------------------------------------
__device__ __forceinline__ void proj64_body(
    int gi, int nIB, int nJB,
    const float* __restrict__ A, long aBatch, int aRow,
    const float* __restrict__ Bw,
    float* __restrict__ C, long cBatch, int cRow, int cCol0,
    int act, const float* __restrict__ sv, const float* __restrict__ tv,
    float* __restrict__ smem)
{
    float* As = smem;
    float* Bs = smem + 4096;
    const int ib = gi % nIB;
    const int jb = (gi / nIB) % nJB;
    const int b  = gi / (nIB*nJB);
    const int t  = threadIdx.x;
    const int tx = t & 15, ty = t >> 4;
    const float* Ab = A + (long)b*aBatch + (long)(ib*64)*aRow;
    #pragma unroll
    for (int m = 0; m < 4; m++) {
        int li = t + m*256; int r = li >> 4; int c4 = li & 15;
        int cs = r ^ ((c4 & 7) << 2);
        float4 av = *(const float4*)(Ab + (long)r*aRow + c4*4);
        As[(c4*4+0)*64 + cs] = av.x; As[(c4*4+1)*64 + cs] = av.y;
        As[(c4*4+2)*64 + cs] = av.z; As[(c4*4+3)*64 + cs] = av.w;
        float4 bv = *(const float4*)(Bw + (long)(jb*64 + r)*64 + c4*4);
        Bs[(c4*4+0)*64 + cs] = bv.x; Bs[(c4*4+1)*64 + cs] = bv.y;
        Bs[(c4*4+2)*64 + cs] = bv.z; Bs[(c4*4+3)*64 + cs] = bv.w;
    }
    __syncthreads();
    float acc[4][4];
    #pragma unroll
    for (int i = 0; i < 4; i++)
        #pragma unroll
        for (int j = 0; j < 4; j++) acc[i][j] = 0.0f;
    #pragma unroll 4
    for (int k = 0; k < 64; k++) {
        int s4 = ((k >> 2) & 7) << 2;
        float4 a  = *(const float4*)&As[k*64 + ((ty*4) ^ s4)];
        float4 b4 = *(const float4*)&Bs[k*64 + ((tx*4) ^ s4)];
        acc[0][0] += a.x*b4.x; acc[0][1] += a.x*b4.y; acc[0][2] += a.x*b4.z; acc[0][3] += a.x*b4.w;
        acc[1][0] += a.y*b4.x; acc[1][1] += a.y*b4.y; acc[1][2] += a.y*b4.z; acc[1][3] += a.y*b4.w;
        acc[2][0] += a.z*b4.x; acc[2][1] += a.z*b4.y; acc[2][2] += a.z*b4.z; acc[2][3] += a.z*b4.w;
        acc[3][0] += a.w*b4.x; acc[3][1] += a.w*b4.y; acc[3][2] += a.w*b4.z; acc[3][3] += a.w*b4.w;
    }
    const int i0 = ib*64 + ty*4;
    const int j0 = jb*64 + tx*4;
    #pragma unroll
    for (int ii = 0; ii < 4; ii++)
        #pragma unroll
        for (int jj = 0; jj < 4; jj++) {
            int j = j0 + jj;
            float vv = acc[ii][jj];
            if (act == 1) vv = fmaxf(sv[j]*vv + tv[j], 0.0f);
            C[(long)b*cBatch + (long)(i0+ii)*cRow + cCol0 + j] = vv;
        }
}

// ---------------------------------------------------------------------------
// select body
// ---------------------------------------------------------------------------
__device__ __forceinline__ void sel_body(
    const float* __restrict__ Dold, int qbOld, int* __restrict__ idxf, int bid)
{
    const int t = threadIdx.x, lane = t & 63, w = t >> 6;
    const int r = bid*4 + w;
    const int b = r >> 8, qi = r & (CHQ-1);
    const float* row = Dold + ((long)b*CHQ + qi) * N_;
    float v[32];
    #pragma unroll
    for (int j = 0; j < 32; j++) v[j] = row[j*64 + lane];
    topk_sel4<32, KG>(v, lane, idxf + ((long)b*N_ + qbOld + qi)*KG);
}

// ---------------------------------------------------------------------------
// edgefuse body (smem: wt 8192 + fused 512)
// ---------------------------------------------------------------------------
__device__ __forceinline__ void edgefuse_body(
    const float* __restrict__ P, const int* __restrict__ idxg, const int* __restrict__ idxf,
    const float* __restrict__ wft, const float* __restrict__ sc,
    float* __restrict__ outf, int bid, float* __restrict__ smem)
{
    float* wt = smem;
    float* fused = smem + 8192;
    const int t = threadIdx.x, lane = t & 63, w = t >> 6;
    for (int i = t; i < 128*64; i += 256) wt[i] = wft[i];
    const int pid = bid*4 + w;
    const int b = pid >> 11, n = pid & (N_-1);
    const float* Prow = P + ((long)b*N_ + n)*256;
    const int* ig  = idxg + ((long)b*N_ + n)*KG;
    const int* ifx = idxf + ((long)b*N_ + n)*KG;
    float gmax = -FLT_MAX, hmax = -FLT_MAX;
    for (int k = 0; k < KG; k++) {
        int idg = ig[k];
        gmax = fmaxf(gmax, P[((long)b*N_ + idg)*256 + lane]);
        int idf = ifx[k];
        hmax = fmaxf(hmax, P[((long)b*N_ + idf)*256 + 128 + lane]);
    }
    float glin = gmax - Prow[lane]       + Prow[64 + lane];
    float hlin = hmax - Prow[128 + lane] + Prow[192 + lane];
    float gv = lrelu_(sc[SC_SGEO + lane]*glin + sc[SC_TGEO + lane]);
    float hv = lrelu_(sc[SC_SFEAT + lane]*hlin + sc[SC_TFEAT + lane]);
    fused[w*128 + lane]      = gv;
    fused[w*128 + 64 + lane] = hv;
    __syncthreads();
    float acc = 0.0f;
    #pragma unroll 8
    for (int c4 = 0; c4 < 32; c4++) {
        float4 f = *(const float4*)&fused[w*128 + c4*4];
        acc += f.x * wt[(c4*4+0)*64 + lane];
        acc += f.y * wt[(c4*4+1)*64 + lane];
        acc += f.z * wt[(c4*4+2)*64 + lane];
        acc += f.w * wt[(c4*4+3)*64 + lane];
    }
    float ov = lrelu_(sc[SC_SFUSE + lane]*acc + sc[SC_TFUSE + lane]);
    outf[((long)b*N_ + n)*64 + lane] = ov;
}

// ---------------------------------------------------------------------------
// gathermax body
// ---------------------------------------------------------------------------
template<int QN, int ROWW, int CO, int MROWS, int SO>
__device__ __forceinline__ void gathermax_body(
    const float* __restrict__ Q, const int* __restrict__ knn, const int* __restrict__ fpsi,
    const float* __restrict__ sv, const float* __restrict__ tv,
    float* __restrict__ outp, int outRow, int bid)
{
    const int t = threadIdx.x, lane = t & 63, w = t >> 6;
    const int pid = bid*4 + w;
    const int b = pid / SO, s = pid % SO;
    const int* ix = knn + ((long)b*SO + s)*NSAMP;
    float mx[QN];
    #pragma unroll
    for (int q = 0; q < QN; q++) mx[q] = -FLT_MAX;
    for (int k = 0; k < NSAMP; k++) {
        int id = ix[k];
        const float* r = Q + ((long)b*MROWS + id)*ROWW;
        #pragma unroll
        for (int q = 0; q < QN; q++) mx[q] = fmaxf(mx[q], r[lane + 64*q]);
    }
    int crow = fpsi[b*SO + s];
    const float* cr = Q + ((long)b*MROWS + crow)*ROWW + CO;
    #pragma unroll
    for (int q = 0; q < QN; q++) {
        int o = lane + 64*q;
        float lin = mx[q] + cr[o];
        float val = fmaxf(sv[o]*lin + tv[o], 0.0f);
        outp[((long)b*SO + s)*outRow + o] = val;
    }
}

// ---------------------------------------------------------------------------
// d1: FPS1(0,256) + geo-knn (xyz4) + dist gemm chunk0
// ---------------------------------------------------------------------------
__global__ void __launch_bounds__(256, 4) k_geo0(
    const float* __restrict__ x, const float4* __restrict__ xyz4,
    int* __restrict__ idxg,
    int* __restrict__ fps1, float* __restrict__ nx1,
    float* __restrict__ dl1s, float* __restrict__ st,
    const float* __restrict__ ft, const float* __restrict__ sq,
    float* __restrict__ D0)
{
    __shared__ float smem[8192];
    if (blockIdx.x < (unsigned)B_) {
        fps1_seg_body(x, blockIdx.x, 0, 256, fps1, nx1, dl1s, st, smem);
        return;
    }
    if (blockIdx.x < (unsigned)(B_ + 8192)) {
        knn_x4body<32, KG, true>(xyz4, N_, nullptr, 0, 0, idxg, blockIdx.x - B_);
        return;
    }
    dist_gemm_body(ft, sq, D0, 0, blockIdx.x - (B_ + 8192), smem);
}

// ---------------------------------------------------------------------------
// chain: FPS1 segment + sel(ci-1) + gemm(ci)
// ---------------------------------------------------------------------------
__global__ void __launch_bounds__(256, 4) k_chain(
    const float* __restrict__ x, const float* __restrict__ ft, const float* __restrict__ sq,
    float* __restrict__ Dnew, int qbNew,
    const float* __restrict__ Dold, int qbOld,
    int* __restrict__ idxf,
    int* __restrict__ fps1, float* __restrict__ nx1,
    float* __restrict__ dl1s, float* __restrict__ st, int i0)
{
    __shared__ float smem[8192];
    if (blockIdx.x < 16u) {
        fps1_seg_body(x, blockIdx.x, i0, 32, fps1, nx1, dl1s, st, smem);
        return;
    }
    if (blockIdx.x < 1040u) {
        sel_body(Dold, qbOld, idxf, blockIdx.x - 16);
        return;
    }
    dist_gemm_body(ft, sq, Dnew, qbNew, blockIdx.x - 1040, smem);
}

// ---------------------------------------------------------------------------
// d9: FPS1(480,32) + sel7 + P projection
// ---------------------------------------------------------------------------
__global__ void __launch_bounds__(256, 4) k_tail9(
    const float* __restrict__ x, const float* __restrict__ ft,
    const float* __restrict__ Dold, int qbOld, int* __restrict__ idxf,
    int* __restrict__ fps1, float* __restrict__ nx1,
    float* __restrict__ dl1s, float* __restrict__ st,
    const float* __restrict__ wpp, float* __restrict__ big)
{
    __shared__ float smem[8192];
    if (blockIdx.x < 16u) {
        fps1_seg_body(x, blockIdx.x, 480, 32, fps1, nx1, dl1s, st, smem);
        return;
    }
    if (blockIdx.x < 1040u) {
        sel_body(Dold, qbOld, idxf, blockIdx.x - 16);
        return;
    }
    proj64_body(blockIdx.x - 1040, 32, 4, ft, (long)N_*64, 64, wpp,
                big, (long)N_*256, 256, 0, 0, nullptr, nullptr, smem);
}

// ---------------------------------------------------------------------------
// d10: FPS2(0,128) + edgefuse + x_skip projection
// ---------------------------------------------------------------------------
__global__ void __launch_bounds__(256, 4) k_tail10(
    const float* __restrict__ nx1, int* __restrict__ fps2, float* __restrict__ nx2,
    float* __restrict__ dl2s, float* __restrict__ st,
    const float* __restrict__ P, const int* __restrict__ idxg, const int* __restrict__ idxf,
    const float* __restrict__ wft, const float* __restrict__ sc, float* __restrict__ outf,
    const float* __restrict__ ft, const float* __restrict__ w2, float* __restrict__ V)
{
    __shared__ float smem[8704];
    if (blockIdx.x < 16u) {
        fps2_seg_body(blockIdx.x, 0, 128, nx1, fps2, nx2, dl2s, st, smem);
        return;
    }
    if (blockIdx.x < (unsigned)(16 + 8192)) {
        edgefuse_body(P, idxg, idxf, wft, sc, outf, blockIdx.x - 16, smem);
        return;
    }
    proj64_body(blockIdx.x - (16 + 8192), 4, 16, ft, (long)N_*64, 512, w2,
                V, (long)NP2*1280, 1280, 256, 1, sc + SC_S2, sc + SC_T2, smem);
}

// ---------------------------------------------------------------------------
// d11: FPS2(128,128) + knn1 (xyz4 refs) + Q0 projection
// ---------------------------------------------------------------------------
__global__ void __launch_bounds__(256, 4) k_tail11(
    const float* __restrict__ nx1, int* __restrict__ fps2, float* __restrict__ nx2,
    float* __restrict__ dl2s, float* __restrict__ st,
    const float4* __restrict__ xyz4, int* __restrict__ idx1,
    const float* __restrict__ outf, const float* __restrict__ wpq0, float* __restrict__ big)
{
    __shared__ float smem[8192];
    if (blockIdx.x < 16u) {
        fps2_seg_body(blockIdx.x, 128, 128, nx1, fps2, nx2, dl2s, st, smem);
        return;
    }
    if (blockIdx.x < (unsigned)(16 + 2048)) {
        knn_x4body<32, 32, false>(xyz4, NP1, nx1, (long)NP1*3, 3, idx1, blockIdx.x - 16);
        return;
    }
    proj64_body(blockIdx.x - (16 + 2048), 32, 4, outf, (long)N_*64, 64, wpq0,
                big, (long)N_*256, 256, 0, 0, nullptr, nullptr, smem);
}

// ---------------------------------------------------------------------------
// d12: gathermax0 + knn2
// ---------------------------------------------------------------------------
__global__ void __launch_bounds__(256, 4) k_gm0knn2(
    const float* __restrict__ big, const int* __restrict__ idx1, const int* __restrict__ fps1,
    const float* __restrict__ sc, float* __restrict__ f0t,
    const float* __restrict__ nx2, const float* __restrict__ nx1, int* __restrict__ idx2)
{
    if (blockIdx.x < 2048u) {
        gathermax_body<2,256,128,2048,512>(big, idx1, fps1,
            sc + SC_SGL0, sc + SC_TGL0, f0t, 128, blockIdx.x);
        return;
    }
    knn_gbody<8,32>(nx2, (long)NP2*3, 3, NP2,
                    nx1, (long)NP1*3, 3, idx2, blockIdx.x - 2048);
}

// ---------------------------------------------------------------------------
// generic GEMM (Q1 projection K=128, final K=1280), swizzled staging
// ---------------------------------------------------------------------------
__global__ void __launch_bounds__(256) k_gemm(
    const float* __restrict__ A, long aBatch, int aRow,
    const float* __restrict__ Bw, long bBatch, int K,
    float* __restrict__ C, long cBatch, int cRow, int cCol0,
    int act, const float* __restrict__ sv, const float* __restrict__ tv,
    int epi)
{
    __shared__ float As[4096];
    __shared__ float Bs[4096];
    const int b  = blockIdx.z;
    const int ib = blockIdx.x * 64;
    const int jb = blockIdx.y * 64;
    const int t  = threadIdx.x;
    const int tx = t & 15, ty = t >> 4;
    const float* Ab = A + (long)b * aBatch;
    const float* Bb = Bw + (long)b * bBatch;
    float acc[4][4];
    #pragma unroll
    for (int i = 0; i < 4; i++)
        #pragma unroll
        for (int j = 0; j < 4; j++) acc[i][j] = 0.0f;

    for (int kb = 0; kb < K; kb += 64) {
        #pragma unroll
        for (int m = 0; m < 4; m++) {
            int li = t + m*256; int r = li >> 4; int c4 = li & 15;
            int cs = r ^ ((c4 & 7) << 2);
            float4 av = *(const float4*)(Ab + (long)(ib + r)*aRow + kb + c4*4);
            As[(c4*4+0)*64 + cs] = av.x; As[(c4*4+1)*64 + cs] = av.y;
            As[(c4*4+2)*64 + cs] = av.z; As[(c4*4+3)*64 + cs] = av.w;
            float4 bv = *(const float4*)(Bb + (long)(jb + r)*K + kb + c4*4);
            Bs[(c4*4+0)*64 + cs] = bv.x; Bs[(c4*4+1)*64 + cs] = bv.y;
            Bs[(c4*4+2)*64 + cs] = bv.z; Bs[(c4*4+3)*64 + cs] = bv.w;
        }
        __syncthreads();
        #pragma unroll 4
        for (int k = 0; k < 64; k++) {
            int s4 = ((k >> 2) & 7) << 2;
            float4 a  = *(const float4*)&As[k*64 + ((ty*4) ^ s4)];
            float4 b4 = *(const float4*)&Bs[k*64 + ((tx*4) ^ s4)];
            acc[0][0] += a.x*b4.x; acc[0][1] += a.x*b4.y; acc[0][2] += a.x*b4.z; acc[0][3] += a.x*b4.w;
            acc[1][0] += a.y*b4.x; acc[1][1] += a.y*b4.y; acc[1][2] += a.y*b4.z; acc[1][3] += a.y*b4.w;
            acc[2][0] += a.z*b4.x; acc[2][1] += a.z*b4.y; acc[2][2] += a.z*b4.z; acc[2][3] += a.z*b4.w;
            acc[3][0] += a.w*b4.x; acc[3][1] += a.w*b4.y; acc[3][2] += a.w*b4.z; acc[3][3] += a.w*b4.w;
        }
        __syncthreads();
    }

    const int i0 = ib + ty*4;
    const int j0 = jb + tx*4;
    if (epi == 2) {
        #pragma unroll
        for (int ii = 0; ii < 4; ii++)
            #pragma unroll
            for (int jj = 0; jj < 4; jj++) {
                int j = j0 + jj;
                float vv = lrelu_(sv[j]*acc[ii][jj] + tv[j]);
                C[(long)b*cBatch + (long)j*cRow + (i0+ii)] = vv;
            }
    } else {
        #pragma unroll
        for (int ii = 0; ii < 4; ii++)
            #pragma unroll
            for (int jj = 0; jj < 4; jj++) {
                int j = j0 + jj;
                float vv = acc[ii][jj];
                if (act == 1) vv = fmaxf(sv[j]*vv + tv[j], 0.0f);
                else if (act == 2) vv = lrelu_(sv[j]*vv + tv[j]);
                C[(long)b*cBatch + (long)(i0+ii)*cRow + cCol0 + j] = vv;
            }
    }
}

// ---------------------------------------------------------------------------
// standalone gathermax (d14)
// ---------------------------------------------------------------------------
template<int QN, int ROWW, int CO, int MROWS, int SO>
__global__ void __launch_bounds__(256) k_gathermax(
    const float* __restrict__ Q, const int* __restrict__ knn, const int* __restrict__ fpsi,
    const float* __restrict__ sv, const float* __restrict__ tv,
    float* __restrict__ outp, int outRow)
{
    gathermax_body<QN,ROWW,CO,MROWS,SO>(Q, knn, fpsi, sv, tv, outp, outRow, blockIdx.x);
}

// ---------------------------------------------------------------------------
extern "C" void kernel_launch(void* const* d_in, const int* in_sizes, int n_in,
                              void* d_out, int out_size, void* d_ws, size_t ws_size,
                              hipStream_t stream)
{
    const float* x      = (const float*)d_in[0];
    const float* w1     = (const float*)d_in[1];
    const float* bn1    = (const float*)d_in[2];
    const float* w2     = (const float*)d_in[3];
    const float* bn2    = (const float*)d_in[4];
    const float* geow   = (const float*)d_in[5];
    const float* geobn  = (const float*)d_in[6];
    const float* featw  = (const float*)d_in[7];
    const float* featbn = (const float*)d_in[8];
    const float* fusew  = (const float*)d_in[9];
    const float* fusebn = (const float*)d_in[10];
    const float* gl0w   = (const float*)d_in[11];
    const float* gl0bn  = (const float*)d_in[12];
    const float* gl1w   = (const float*)d_in[13];
    const float* gl1bn  = (const float*)d_in[14];
    const float* wf     = (const float*)d_in[15];
    const float* bnfp   = (const float*)d_in[16];

    float* ws  = (float*)d_ws;
    float* out = (float*)d_out;

    float* FT   = ws + OFF_FT;
    float* SQ   = ws + OFF_SQ;
    float* BIG  = ws + OFF_BIG;
    int*   IDXG = (int*)(ws + OFF_IDXG);
    int*   IDXF = (int*)(ws + OFF_IDXF);
    float* OUTF = ws + OFF_OUTF;
    int*   FPS1 = (int*)(ws + OFF_FPS1);
    float* NX1  = ws + OFF_NX1;
    int*   IDX1 = (int*)(ws + OFF_IDX1);
    float* F0T  = ws + OFF_F0T;
    int*   FPS2 = (int*)(ws + OFF_FPS2);
    float* NX2  = ws + OFF_NX2;
    int*   IDX2 = (int*)(ws + OFF_IDX2);
    float* Q1B  = ws + OFF_Q1;
    float* V    = ws + OFF_V;
    float* WPP  = ws + OFF_WPP;
    float* WPQ0 = ws + OFF_WPQ0;
    float* WPQ1 = ws + OFF_WPQ1;
    float* WFT  = ws + OFF_WFT;
    float* SC   = ws + OFF_SC;
    float* DL1  = ws + OFF_DL1;
    float* DL2  = ws + OFF_DL2;
    float* ST   = ws + OFF_ST;
    float4* XYZ4 = (float4*)(ws + OFF_XYZ4);

    // d0: prep + feat0 (+xyz4/gsq packing) in one dispatch
    hipLaunchKernelGGL(k_init, dim3(64 + B_*N_/4), dim3(256), 0, stream,
        x, w1, bn1, bn2, geow, geobn, featw, featbn, fusew, fusebn,
        gl0w, gl0bn, gl1w, gl1bn, bnfp, ws, FT, SQ, XYZ4);

    // d1: FPS1 first 256 iters + geo-knn + dist gemm chunk0 -> BIG
    hipLaunchKernelGGL(k_geo0, dim3(B_ + 8192 + 2048), dim3(256), 0, stream,
        x, XYZ4, IDXG, FPS1, NX1, DL1, ST, FT, SQ, BIG);

    // d2..d8: {FPS1 seg (32) + sel(ci-1) + gemm(ci)}
    float* bufs[2] = { BIG, Q1B };
    for (int ci = 1; ci < 8; ci++) {
        hipLaunchKernelGGL(k_chain, dim3(16 + 1024 + 2048), dim3(256), 0, stream,
            x, FT, SQ,
            bufs[ci & 1], ci*CHQ,
            bufs[(ci - 1) & 1], (ci - 1)*CHQ,
            IDXF, FPS1, NX1, DL1, ST, 256 + 32*(ci - 1));
    }

    // d9: FPS1 last 32 + sel7 + P projection -> BIG
    hipLaunchKernelGGL(k_tail9, dim3(16 + 1024 + 2048), dim3(256), 0, stream,
        x, FT, bufs[1], 7*CHQ, IDXF, FPS1, NX1, DL1, ST, WPP, BIG);

    // d10: FPS2 seg0 + edgefuse + x_skip
    hipLaunchKernelGGL(k_tail10, dim3(16 + 8192 + 1024), dim3(256), 0, stream,
        NX1, FPS2, NX2, DL2, ST,
        BIG, IDXG, IDXF, WFT, SC, OUTF,
        FT, w2, V);

    // d11: FPS2 seg1 + knn1 + Q0 projection -> BIG
    hipLaunchKernelGGL(k_tail11, dim3(16 + 2048 + 2048), dim3(256), 0, stream,
        NX1, FPS2, NX2, DL2, ST,
        XYZ4, IDX1,
        OUTF, WPQ0, BIG);

    // d12: gathermax0 + knn2
    hipLaunchKernelGGL(k_gm0knn2, dim3(2048 + 1024), dim3(256), 0, stream,
        BIG, IDX1, FPS1, SC, F0T, NX2, NX1, IDX2);

    // d13: Q1 projection (K=128)
    hipLaunchKernelGGL(k_gemm, dim3(NP1/64, 512/64, B_), dim3(256), 0, stream,
        F0T, (long)NP1*128, 128, WPQ1, (long)0, 128,
        Q1B, (long)NP1*512, 512, 0, 0, nullptr, nullptr, 0);

    // d14: gathermax1
    hipLaunchKernelGGL((k_gathermax<4,512,256,512,256>), dim3(B_*NP2/4), dim3(256), 0, stream,
        Q1B, IDX2, FPS2, SC + SC_SGL1, SC + SC_TGL1, V, 1280);

    // d15: final (B,512,256) = lrelu(bnf(wf . V^T)), transposed store
    hipLaunchKernelGGL(k_gemm, dim3(NP2/64, 512/64, B_), dim3(256), 0, stream,
        V, (long)NP2*1280, 1280, wf, (long)0, 1280,
        out, (long)512*256, 256, 0, 2, SC + SC_SF, SC + SC_TF, 2);

    (void)in_sizes; (void)n_in; (void)out_size; (void)ws_size;
}